// Round 10
// baseline (1243.743 us; speedup 1.0000x reference)
//
#include <hip/hip_runtime.h>
#include <math.h>

constexpr int TS = 8;      // samples per block (LDS 74.5KB -> 2 blocks/CU)
constexpr int NT = 256;    // threads per block (4 waves)
constexpr int NW = NT/64;  // 4 waves
constexpr int SSTRIDE = 776;   // bf16 per sample, HID0 state (768 + 8 pad)
constexpr int H1S = 1544;      // bf16 per sample, HID1 transient (1536 + 8 pad)
constexpr int BUF = TS*SSTRIDE;
// HID0 per-sample layout: l0 @0 (64: [u]), l1 @64 (3x64: [i][u]),
// l2 @256 (5x64), l1b @576 (3x64)
// HID1 layout: l0 @0 (128), l1 @128 (3x128), l2 @512 (5x128), l1b @1152 (3x128)
//
// R9 state: fused TP (15 barriers) + KFENCE = 786us steady, VGPR=128, ZERO
// spill (WRITE 384B). Counters: VALU 23.5%, MFMA 9%, ~67% stall -- intra-phase
// latency that same-block waves cannot hide (barrier-synced).
// REGISTER MODEL (fits R1-R9 exactly): effective footprint = 2 x VGPR_Count
// (AGPR mirror on unified file); compiler cap = 512/minWavesPerSIMD/2.
// R4/R5 co-residency failures were 2xVGPR > budget, NOT LDS/concept.
// R10: two INDEPENDENT barrier domains per CU -- NT=256, TS=8,
// launch_bounds(256,2) -> cap 128 (R9 proves kernel fits in 128 spill-free);
// 2 blocks = 2 waves/SIMD x 2x128 = 512 = budget; LDS 74,496x2 fits.
// Cost: MFMA M-rows + TP lanes half-wasted (2x instr on 9%/23%-busy pipes).
// Sample reads masked (l16&7); stores guarded (quad<2 / l16<8 / lane<8).

typedef __attribute__((ext_vector_type(8))) short bf16x8;
typedef __attribute__((ext_vector_type(4))) float f32x4;
typedef __attribute__((ext_vector_type(4))) unsigned short u16x4;

#define KFENCE() asm volatile("" ::: "memory")

__device__ inline f32x4 mfma16(bf16x8 a, bf16x8 b, f32x4 c){
  return __builtin_amdgcn_mfma_f32_16x16x32_bf16(a, b, c, 0, 0, 0);
}
__device__ inline unsigned short f2b(float f){
  union { float f; unsigned u; } v; v.f = f;
  return (unsigned short)((v.u + 0x7fffu + ((v.u >> 16) & 1u)) >> 16);
}
__device__ inline float b2f(unsigned short h){
  union { unsigned u; float f; } v; v.u = ((unsigned)h) << 16; return v.f;
}
__device__ inline void store_hl(unsigned short* ph, unsigned short* pl, int idx, float v){
  unsigned short h = f2b(v);
  ph[idx] = h;
  pl[idx] = f2b(v - b2f(h));
}
#define LDFRAG(p) (*(const bf16x8*)(p))

// ws bf16 weight offsets (elements, base = ws+4096B). lo plane at +W_TOT.
constexpr int OFF_L2W0 = 0;        // 64x128 (WT[o][k])
constexpr int OFF_L2W1 = 8192;     // 128x256
constexpr int OFF_L2W2 = 40960;    // 64x128
constexpr int OFF_LW0  = 49152;    // 11 x 64x64
constexpr int OFF_LW1  = 94208;    // 11 x 128x128
constexpr int OFF_LW2  = 274432;   // 11 x 64x64
constexpr int OFF_TPW  = 319488;   // 3x14 x 64x64 ([u][v])
constexpr int OFF_TP4W = 491520;   // 17 x 64x64
constexpr int W_TOT    = 561152;

// ============================================================================
// Clebsch-Gordan init (element-parallel fp64; verified R2/R3)
// offsets: 0:(0,0,0)@0 1:(0,1,1)@1 2:(1,0,1)@10 3:(0,2,2)@19 4:(2,0,2)@44
// 5:(1,1,0)@69 6:(1,1,1)@78 7:(1,1,2)@105 8:(2,1,2)@150 9:(1,2,2)@225
// 10:(2,2,0)@300 11:(2,2,1)@325 12:(2,2,2)@400 ; total 525 floats
// ============================================================================
__device__ inline double dfact(int n){ double r=1.0; for(int i=2;i<=n;i++) r*=(double)i; return r; }
struct dcplx { double x, y; };
__device__ inline dcplx cmul(dcplx a, dcplx b){ return {a.x*b.x-a.y*b.y, a.x*b.y+a.y*b.x}; }

__device__ dcplx Uent(int l, int r, int c){
  double re=0.0, im=0.0;
  double s = 1.0/sqrt(2.0);
  if (r==l && c==l) re = 1.0;
  else if (c>l){ int m=c-l; double sgn=(m&1)?-1.0:1.0;
    if (r==l-m) re = s; else if (r==l+m) re = sgn*s;
  } else if (c<l){ int m=l-c; double sgn=(m&1)?-1.0:1.0;
    if (r==l-m) im = s; else if (r==l+m) im = -sgn*s;
  }
  int lm=l&3; double pr,pi;
  if(lm==0){pr=1;pi=0;} else if(lm==1){pr=0;pi=-1;} else if(lm==2){pr=-1;pi=0;} else {pr=0;pi=1;}
  return { re*pr-im*pi, re*pi+im*pr };
}

__device__ double cg_complex_entry(int l1,int l2,int l3,int m1,int m2){
  int m3=m1+m2;
  if (m3<-l3 || m3>l3) return 0.0;
  double pref = sqrt((double)(2*l3+1)*dfact(l3+l1-l2)*dfact(l3-l1+l2)*dfact(l1+l2-l3)/dfact(l1+l2+l3+1));
  pref *= sqrt(dfact(l3+m3)*dfact(l3-m3)*dfact(l1-m1)*dfact(l1+m1)*dfact(l2-m2)*dfact(l2+m2));
  double s=0.0;
  for(int k=0;k<=l1+l2-l3;k++){
    int a2=l1-m1-k, a3=l2+m2-k, a4=l3-l2+m1+k, a5=l3-l1-m2+k;
    if(a2<0||a3<0||a4<0||a5<0) continue;
    double t=1.0/(dfact(k)*dfact(l1+l2-l3-k)*dfact(a2)*dfact(a3)*dfact(a4)*dfact(a5));
    s += (k&1)? -t : t;
  }
  return pref*s;
}

__global__ void cg_init_kernel(float* cg){
  __shared__ double sKr[525], sKi[525];
  __shared__ double sScale[13];
  __shared__ int    sSel[13];
  const int L1[13]={0,0,1,0,2,1,1,1,2,1,2,2,2};
  const int L2[13]={0,1,0,2,0,1,1,1,1,2,2,2,2};
  const int L3[13]={0,1,1,2,2,0,1,2,2,2,0,1,2};
  const int OFF[14]={0,1,10,19,44,69,78,105,150,225,300,325,400,525};
  const int tid = threadIdx.x;
  int combo=-1, l1=0,l2=0,l3=0;
  if (tid < 525){
    combo=12;
    for(int i=0;i<12;i++) if (tid < OFF[i+1]) { combo=i; break; }
    l1=L1[combo]; l2=L2[combo]; l3=L3[combo];
    int d2=2*l2+1, d3=2*l3+1;
    int e = tid - OFF[combo];
    int a = e/(d2*d3), b=(e/d3)%d2, cc=e%d3;
    double kr=0.0, ki=0.0;
    for(int m=0;m<2*l1+1;m++) for(int n=0;n<d2;n++){
      int m3 = (m-l1)+(n-l2);
      if (m3<-l3||m3>l3) continue;
      double cv = cg_complex_entry(l1,l2,l3,m-l1,n-l2);
      if (cv==0.0) continue;
      dcplx u1=Uent(l1,m,a), u2=Uent(l2,n,b), u3=Uent(l3,m3+l3,cc);
      u3.y = -u3.y;
      dcplx t = cmul(cmul(u1,u2),u3);
      kr += t.x*cv; ki += t.y*cv;
    }
    sKr[tid]=kr; sKi[tid]=ki;
  }
  __syncthreads();
  if (tid < 13){
    int sz = OFF[tid+1]-OFF[tid];
    double nr=0,ni=0;
    for(int i=0;i<sz;i++){ double r=sKr[OFF[tid]+i], im=sKi[OFF[tid]+i]; nr+=r*r; ni+=im*im; }
    int sel = (nr>=ni)? 0 : 1;
    sSel[tid]=sel;
    sScale[tid] = sqrt((double)(2*L3[tid]+1))/sqrt(sel? ni : nr);
  }
  __syncthreads();
  if (tid < 525){
    double v = sSel[combo]? sKi[tid] : sKr[tid];
    cg[tid] = (float)(v*sScale[combo]);
  }
}

// ============================================================================
// Weight prep: fp32 -> bf16 hi/lo planes. Linear weights transposed WT[o][k];
// TP weights [u][v].
// ============================================================================
__global__ void prep_kernel(const float* __restrict__ l2W0, const float* __restrict__ l2W1,
                            const float* __restrict__ l2W2, const float* __restrict__ LW0,
                            const float* __restrict__ LW1, const float* __restrict__ LW2,
                            const float* __restrict__ tpw, const float* __restrict__ tp4w,
                            unsigned short* __restrict__ wb){
  int i = blockIdx.x*256 + threadIdx.x;
  if (i >= W_TOT) return;
  float v;
  if (i < 8192){ int o=i>>7, k=i&127; v = l2W0[k*64+o]; }
  else if (i < 40960){ int j=i-8192; int o=j>>8, k=j&255; v = l2W1[k*128+o]; }
  else if (i < 49152){ int j=i-40960; int o=j>>7, k=j&127; v = l2W2[k*64+o]; }
  else if (i < 94208){ int j=i-49152; int li=j>>12, r=j&4095, o=r>>6, k=r&63; v = LW0[li*4096+k*64+o]; }
  else if (i < 274432){ int j=i-94208; int li=j>>14, r=j&16383, o=r>>7, k=r&127; v = LW1[li*16384+k*128+o]; }
  else if (i < 319488){ int j=i-274432; int li=j>>12, r=j&4095, o=r>>6, k=r&63; v = LW2[li*4096+k*64+o]; }
  else if (i < 491520){ v = tpw[i-319488]; }
  else { v = tp4w[i-491520]; }
  unsigned short h = f2b(v);
  wb[i] = h;
  wb[W_TOT + i] = f2b(v - b2f(h));
}

// ============================================================================
// MFMA linear HID0->HID0 (hi/lo). Jobs: 0..3 l0 | 4..11 l1 | 12..15 l2.
// NW=4: 4 jobs/wave (1 l0, 2 l1, 1 l2). TS=8: A rows masked (l16&7);
// output rows >=8 discarded (quad<2).
// ============================================================================
__device__ void linL_mfma(const unsigned short* __restrict__ wb, int o0, int o1, int o2,
                          const float* __restrict__ b0,
                          const unsigned short* sh, const unsigned short* sl,
                          unsigned short* dh, unsigned short* dl, int wave, int lane)
{
  const float rs128 = 0.08838834764831845f;
  int l16 = lane & 15, quad = lane >> 4;
  int abase = (l16 & 7) * SSTRIDE;
  for (int job = wave; job < 16; job += NW){
    if (job < 4){                 // l0: K=64, /8 + bias
      int col = job*16 + l16;
      f32x4 a0 = {0,0,0,0}, a1 = {0,0,0,0};
      #pragma unroll
      for (int ks=0; ks<2; ks++){
        int so = abase + ks*32 + quad*8;
        bf16x8 xh = LDFRAG(sh+so), xl = LDFRAG(sl+so);
        int wo = o0 + col*64 + ks*32 + quad*8;
        bf16x8 wh = LDFRAG(wb+wo), wl = LDFRAG(wb+W_TOT+wo);
        a0 = mfma16(xh,wh,a0); a1 = mfma16(xh,wl,a1); a1 = mfma16(xl,wh,a1);
      }
      float bias = b0[col];
      if (quad < 2){
        #pragma unroll
        for (int r=0;r<4;r++)
          store_hl(dh,dl,(quad*4+r)*SSTRIDE + col, (a0[r]+a1[r])*0.125f + bias);
      }
    } else if (job < 12){         // l1: K=128 (l1|l1b), /sqrt(128)
      int nt = job-4; int col = nt*16 + l16;
      #pragma unroll
      for (int i=0;i<3;i++){
        f32x4 a0 = {0,0,0,0}, a1 = {0,0,0,0};
        #pragma unroll
        for (int ks=0; ks<4; ks++){
          int ka = ks*32 + quad*8;
          int so = abase + ((ka < 64) ? (64 + i*64 + ka) : (576 + i*64 + ka - 64));
          bf16x8 xh = LDFRAG(sh+so), xl = LDFRAG(sl+so);
          int wo = o1 + col*128 + ka;
          bf16x8 wh = LDFRAG(wb+wo), wl = LDFRAG(wb+W_TOT+wo);
          a0 = mfma16(xh,wh,a0); a1 = mfma16(xh,wl,a1); a1 = mfma16(xl,wh,a1);
        }
        int dof = (col < 64) ? (64 + i*64 + col) : (576 + i*64 + col - 64);
        if (quad < 2){
          #pragma unroll
          for (int r=0;r<4;r++)
            store_hl(dh,dl,(quad*4+r)*SSTRIDE + dof, (a0[r]+a1[r])*rs128);
        }
      }
    } else {                      // l2: K=64, /8
      int nt = job-12; int col = nt*16 + l16;
      #pragma unroll
      for (int i=0;i<5;i++){
        f32x4 a0 = {0,0,0,0}, a1 = {0,0,0,0};
        #pragma unroll
        for (int ks=0; ks<2; ks++){
          int so = abase + 256 + i*64 + ks*32 + quad*8;
          bf16x8 xh = LDFRAG(sh+so), xl = LDFRAG(sl+so);
          int wo = o2 + col*64 + ks*32 + quad*8;
          bf16x8 wh = LDFRAG(wb+wo), wl = LDFRAG(wb+W_TOT+wo);
          a0 = mfma16(xh,wh,a0); a1 = mfma16(xh,wl,a1); a1 = mfma16(xl,wh,a1);
        }
        if (quad < 2){
          #pragma unroll
          for (int r=0;r<4;r++)
            store_hl(dh,dl,(quad*4+r)*SSTRIDE + 256 + i*64 + col, (a0[r]+a1[r])*0.125f);
        }
      }
    }
  }
}

// lin2: HID1 -> HID0 (K=128/256/128), hi/lo
__device__ void lin2_mfma(const unsigned short* __restrict__ wb,
                          const float* __restrict__ b0,
                          const unsigned short* h1h, const unsigned short* h1l,
                          unsigned short* dh, unsigned short* dl, int wave, int lane)
{
  const float rs128 = 0.08838834764831845f;
  int l16 = lane & 15, quad = lane >> 4;
  int abase = (l16 & 7) * H1S;
  for (int job = wave; job < 16; job += NW){
    if (job < 4){                 // l0: K=128
      int col = job*16 + l16;
      f32x4 a0 = {0,0,0,0}, a1 = {0,0,0,0};
      #pragma unroll
      for (int ks=0; ks<4; ks++){
        int so = abase + ks*32 + quad*8;
        bf16x8 xh = LDFRAG(h1h+so), xl = LDFRAG(h1l+so);
        int wo = OFF_L2W0 + col*128 + ks*32 + quad*8;
        bf16x8 wh = LDFRAG(wb+wo), wl = LDFRAG(wb+W_TOT+wo);
        a0 = mfma16(xh,wh,a0); a1 = mfma16(xh,wl,a1); a1 = mfma16(xl,wh,a1);
      }
      float bias = b0[col];
      if (quad < 2){
        #pragma unroll
        for (int r=0;r<4;r++)
          store_hl(dh,dl,(quad*4+r)*SSTRIDE + col, (a0[r]+a1[r])*rs128 + bias);
      }
    } else if (job < 12){         // l1: K=256, /16
      int nt = job-4; int col = nt*16 + l16;
      #pragma unroll
      for (int i=0;i<3;i++){
        f32x4 a0 = {0,0,0,0}, a1 = {0,0,0,0};
        #pragma unroll
        for (int ks=0; ks<8; ks++){
          int ka = ks*32 + quad*8;
          int so = abase + ((ka < 128) ? (128 + i*128 + ka) : (1152 + i*128 + ka - 128));
          bf16x8 xh = LDFRAG(h1h+so), xl = LDFRAG(h1l+so);
          int wo = OFF_L2W1 + col*256 + ka;
          bf16x8 wh = LDFRAG(wb+wo), wl = LDFRAG(wb+W_TOT+wo);
          a0 = mfma16(xh,wh,a0); a1 = mfma16(xh,wl,a1); a1 = mfma16(xl,wh,a1);
        }
        int dof = (col < 64) ? (64 + i*64 + col) : (576 + i*64 + col - 64);
        if (quad < 2){
          #pragma unroll
          for (int r=0;r<4;r++)
            store_hl(dh,dl,(quad*4+r)*SSTRIDE + dof, (a0[r]+a1[r])*0.0625f);
        }
      }
    } else {                      // l2: K=128
      int nt = job-12; int col = nt*16 + l16;
      #pragma unroll
      for (int i=0;i<5;i++){
        f32x4 a0 = {0,0,0,0}, a1 = {0,0,0,0};
        #pragma unroll
        for (int ks=0; ks<4; ks++){
          int so = abase + 512 + i*128 + ks*32 + quad*8;
          bf16x8 xh = LDFRAG(h1h+so), xl = LDFRAG(h1l+so);
          int wo = OFF_L2W2 + col*128 + ks*32 + quad*8;
          bf16x8 wh = LDFRAG(wb+wo), wl = LDFRAG(wb+W_TOT+wo);
          a0 = mfma16(xh,wh,a0); a1 = mfma16(xh,wl,a1); a1 = mfma16(xl,wh,a1);
        }
        if (quad < 2){
          #pragma unroll
          for (int r=0;r<4;r++)
            store_hl(dh,dl,(quad*4+r)*SSTRIDE + 256 + i*64 + col, (a0[r]+a1[r])*rs128);
        }
      }
    }
  }
}

// ============================================================================
// Fused TP path: stage b-fragment in regs via MFMA, contract immediately.
// Wave's mt picks the u-block; lane l -> sample n = l16&7 (TS=8 masked),
// u = mt*16 + quad*4 + r. x1v loaded as u16x4 (one ds_read_b64 per plane).
// Callers put a KFENCE between paths to stop LICM hoisting all x1v loads.
// ============================================================================
template<int D1,int D2,int D3,int O1,int O2,int CGO>
__device__ __forceinline__ void fused_path(
    const unsigned short* __restrict__ wb, int wo,
    const unsigned short* s1h, const unsigned short* s1l,
    const unsigned short* s2h, const unsigned short* s2l,
    const float* __restrict__ cgp,
    float (&tk)[4][D3], int mt, int lane)
{
  int l16 = lane & 15, quad = lane >> 4;
  int sbase = (l16 & 7) * SSTRIDE;
  float x1v[D1][4];
  #pragma unroll
  for (int i=0;i<D1;i++){
    int o = sbase + O1 + i*64 + mt*16 + quad*4;
    u16x4 xh4 = *(const u16x4*)(s1h + o);
    u16x4 xl4 = *(const u16x4*)(s1l + o);
    #pragma unroll
    for (int r=0;r<4;r++) x1v[i][r] = b2f(xh4[r]) + b2f(xl4[r]);
  }
  #pragma unroll
  for (int j=0;j<D2;j++){
    f32x4 a0 = {0,0,0,0}, a1 = {0,0,0,0};
    #pragma unroll
    for (int ks=0; ks<2; ks++){
      int wofs = wo + (mt*16 + l16)*64 + ks*32 + quad*8;
      bf16x8 wh = LDFRAG(wb + wofs);
      bf16x8 wl = LDFRAG(wb + W_TOT + wofs);
      int sofs = sbase + O2 + j*64 + ks*32 + quad*8;
      bf16x8 xh = LDFRAG(s2h + sofs);
      bf16x8 xl = LDFRAG(s2l + sofs);
      a0 = mfma16(wh,xh,a0); a1 = mfma16(wh,xl,a1); a1 = mfma16(wl,xh,a1);
    }
    #pragma unroll
    for (int r=0;r<4;r++){
      float bu = a0[r] + a1[r];
      #pragma unroll
      for (int i=0;i<D1;i++){
        float pr = x1v[i][r]*bu;
        #pragma unroll
        for (int k=0;k<D3;k++) tk[r][k] += pr*cgp[CGO + (i*D2 + j)*D3 + k];
      }
    }
  }
}

// FC variant: output is summed over u, so fold the r-sum immediately: tk[k].
template<int D1,int D2,int D3,int O1,int O2,int CGO>
__device__ __forceinline__ void fused_path_fc(
    const unsigned short* __restrict__ wb, int wo,
    const unsigned short* s1h, const unsigned short* s1l,
    const unsigned short* s2h, const unsigned short* s2l,
    const float* __restrict__ cgp,
    float (&tk)[D3], int mt, int lane)
{
  int l16 = lane & 15, quad = lane >> 4;
  int sbase = (l16 & 7) * SSTRIDE;
  float x1v[D1][4];
  #pragma unroll
  for (int i=0;i<D1;i++){
    int o = sbase + O1 + i*64 + mt*16 + quad*4;
    u16x4 xh4 = *(const u16x4*)(s1h + o);
    u16x4 xl4 = *(const u16x4*)(s1l + o);
    #pragma unroll
    for (int r=0;r<4;r++) x1v[i][r] = b2f(xh4[r]) + b2f(xl4[r]);
  }
  #pragma unroll
  for (int j=0;j<D2;j++){
    f32x4 a0 = {0,0,0,0}, a1 = {0,0,0,0};
    #pragma unroll
    for (int ks=0; ks<2; ks++){
      int wofs = wo + (mt*16 + l16)*64 + ks*32 + quad*8;
      bf16x8 wh = LDFRAG(wb + wofs);
      bf16x8 wl = LDFRAG(wb + W_TOT + wofs);
      int sofs = sbase + O2 + j*64 + ks*32 + quad*8;
      bf16x8 xh = LDFRAG(s2h + sofs);
      bf16x8 xl = LDFRAG(s2l + sofs);
      a0 = mfma16(wh,xh,a0); a1 = mfma16(wh,xl,a1); a1 = mfma16(wl,xh,a1);
    }
    float bu[4];
    #pragma unroll
    for (int r=0;r<4;r++) bu[r] = a0[r] + a1[r];
    #pragma unroll
    for (int i=0;i<D1;i++){
      float pij = x1v[i][0]*bu[0] + x1v[i][1]*bu[1] + x1v[i][2]*bu[2] + x1v[i][3]*bu[3];
      #pragma unroll
      for (int k=0;k<D3;k++) tk[k] += pij*cgp[CGO + (i*D2 + j)*D3 + k];
    }
  }
}

// pack 4 consecutive u-values into one b64 store per plane
__device__ inline void store4_hl(unsigned short* ph, unsigned short* pl, int idx,
                                 float v0, float v1, float v2, float v3){
  u16x4 vh, vl;
  float v[4] = {v0,v1,v2,v3};
  #pragma unroll
  for (int r=0;r<4;r++){
    unsigned short h = f2b(v[r]);
    vh[r] = h;
    vl[r] = f2b(v[r] - b2f(h));
  }
  *(u16x4*)(ph + idx) = vh;
  *(u16x4*)(pl + idx) = vl;
}

// uvu TP, one barrier-free phase. NW=4: wave = mt; each wave does group A
// (l0+l2) then group B (l1+l1b) sequentially. Stores guarded l16<8 (TS=8;
// lanes 8-15 are sample duplicates). KFENCE caps live regs per path.
__device__ void fused_tp_uvu(const unsigned short* __restrict__ wb, int two,
    const unsigned short* ah, const unsigned short* al,
    const unsigned short* bh, const unsigned short* bl,
    unsigned short* dh, unsigned short* dl,
    const float* __restrict__ cgp, int wave, int lane)
{
  const float f192 = 0.07216878364870323f;  // 1/sqrt(192)
  const float f256 = 0.0625f;               // 1/sqrt(256)
  int mt = wave & 3;
  int l16 = lane & 15, quad = lane >> 4;
  int u0 = mt*16 + quad*4;
  bool wr = (l16 < 8);
  int srow = (l16 & 7) * SSTRIDE;
  { // out l0 @0 (fan 192): paths 0,5,10
    float tk0[4][1] = {};
    fused_path<1,1,1,  0,  0,  0>(wb,two+ 0*4096, ah,al,bh,bl,cgp,tk0,mt,lane);
    KFENCE();
    fused_path<3,3,1, 64, 64, 69>(wb,two+ 5*4096, ah,al,bh,bl,cgp,tk0,mt,lane);
    KFENCE();
    fused_path<5,5,1,256,256,300>(wb,two+10*4096, ah,al,bh,bl,cgp,tk0,mt,lane);
    if (wr)
      store4_hl(dh,dl, srow + u0,
                tk0[0][0]*f192, tk0[1][0]*f192, tk0[2][0]*f192, tk0[3][0]*f192);
    KFENCE();
  }
  { // out l2 @256 (fan 256): paths 2,8,9,13
    float tk2[4][5] = {};
    fused_path<1,5,5,  0,256, 19>(wb,two+ 2*4096, ah,al,bh,bl,cgp,tk2,mt,lane);
    KFENCE();
    fused_path<5,1,5,256,  0, 44>(wb,two+ 8*4096, ah,al,bh,bl,cgp,tk2,mt,lane);
    KFENCE();
    fused_path<5,3,5,256, 64,150>(wb,two+ 9*4096, ah,al,bh,bl,cgp,tk2,mt,lane);
    KFENCE();
    fused_path<5,3,5,256,576,150>(wb,two+13*4096, ah,al,bh,bl,cgp,tk2,mt,lane);
    if (wr){
      #pragma unroll
      for (int k=0;k<5;k++)
        store4_hl(dh,dl, srow + 256 + k*64 + u0,
                  tk2[0][k]*f256, tk2[1][k]*f256, tk2[2][k]*f256, tk2[3][k]*f256);
    }
    KFENCE();
  }
  { // out l1 @64 (fan 256): paths 1,4,6,11
    float tkA[4][3] = {};
    fused_path<1,3,3,  0, 64,  1>(wb,two+ 1*4096, ah,al,bh,bl,cgp,tkA,mt,lane);
    KFENCE();
    fused_path<3,1,3, 64,  0, 10>(wb,two+ 4*4096, ah,al,bh,bl,cgp,tkA,mt,lane);
    KFENCE();
    fused_path<3,3,3, 64, 64, 78>(wb,two+ 6*4096, ah,al,bh,bl,cgp,tkA,mt,lane);
    KFENCE();
    fused_path<5,5,3,256,256,325>(wb,two+11*4096, ah,al,bh,bl,cgp,tkA,mt,lane);
    if (wr){
      #pragma unroll
      for (int k=0;k<3;k++)
        store4_hl(dh,dl, srow +  64 + k*64 + u0,
                  tkA[0][k]*f256, tkA[1][k]*f256, tkA[2][k]*f256, tkA[3][k]*f256);
    }
    KFENCE();
  }
  { // out l1b @576 (fan 192): paths 3,7,12
    float tkB[4][3] = {};
    fused_path<1,3,3,  0,576,  1>(wb,two+ 3*4096, ah,al,bh,bl,cgp,tkB,mt,lane);
    KFENCE();
    fused_path<3,3,3, 64, 64, 78>(wb,two+ 7*4096, ah,al,bh,bl,cgp,tkB,mt,lane);
    KFENCE();
    fused_path<5,5,3,256,256,325>(wb,two+12*4096, ah,al,bh,bl,cgp,tkB,mt,lane);
    if (wr){
      #pragma unroll
      for (int k=0;k<3;k++)
        store4_hl(dh,dl, srow + 576 + k*64 + u0,
                  tkB[0][k]*f192, tkB[1][k]*f192, tkB[2][k]*f192, tkB[3][k]*f192);
    }
  }
}

// FC TP: NW=4 -> each wave (mt) runs ALL 17 paths sequentially (0e group then
// 2e group). Quad-sum via shfl_xor; atomics guarded lane<8 (samples 0-7).
__device__ void fused_tp_fc(const unsigned short* __restrict__ wb,
    const unsigned short* ah, const unsigned short* al,
    const unsigned short* bh, const unsigned short* bl,
    float* s_out, const float* __restrict__ cgp, int wave, int lane)
{
  int mt = wave & 3;
  { // 0e partials: fc paths 0..5
    float t0[1] = {};
    fused_path_fc<1,1,1,  0,  0,  0>(wb,OFF_TP4W+ 0*4096, ah,al,bh,bl,cgp,t0,mt,lane);
    KFENCE();
    fused_path_fc<3,3,1, 64, 64, 69>(wb,OFF_TP4W+ 1*4096, ah,al,bh,bl,cgp,t0,mt,lane);
    KFENCE();
    fused_path_fc<3,3,1, 64,576, 69>(wb,OFF_TP4W+ 2*4096, ah,al,bh,bl,cgp,t0,mt,lane);
    KFENCE();
    fused_path_fc<5,5,1,256,256,300>(wb,OFF_TP4W+ 3*4096, ah,al,bh,bl,cgp,t0,mt,lane);
    KFENCE();
    fused_path_fc<3,3,1,576, 64, 69>(wb,OFF_TP4W+ 4*4096, ah,al,bh,bl,cgp,t0,mt,lane);
    KFENCE();
    fused_path_fc<3,3,1,576,576, 69>(wb,OFF_TP4W+ 5*4096, ah,al,bh,bl,cgp,t0,mt,lane);
    float v0 = t0[0];
    v0 += __shfl_xor(v0, 16, 64);
    v0 += __shfl_xor(v0, 32, 64);
    if (lane < 8) atomicAdd(&s_out[lane*6 + 0], v0);
  }
  KFENCE();
  { // 2e partials: fc paths 6..16
    float t2[5] = {};
    fused_path_fc<1,5,5,  0,256, 19>(wb,OFF_TP4W+ 6*4096, ah,al,bh,bl,cgp,t2,mt,lane);
    KFENCE();
    fused_path_fc<3,3,5, 64, 64,105>(wb,OFF_TP4W+ 7*4096, ah,al,bh,bl,cgp,t2,mt,lane);
    KFENCE();
    fused_path_fc<3,5,5, 64,256,225>(wb,OFF_TP4W+ 8*4096, ah,al,bh,bl,cgp,t2,mt,lane);
    KFENCE();
    fused_path_fc<3,3,5, 64,576,105>(wb,OFF_TP4W+ 9*4096, ah,al,bh,bl,cgp,t2,mt,lane);
    KFENCE();
    fused_path_fc<5,1,5,256,  0, 44>(wb,OFF_TP4W+10*4096, ah,al,bh,bl,cgp,t2,mt,lane);
    KFENCE();
    fused_path_fc<5,3,5,256, 64,150>(wb,OFF_TP4W+11*4096, ah,al,bh,bl,cgp,t2,mt,lane);
    KFENCE();
    fused_path_fc<5,5,5,256,256,400>(wb,OFF_TP4W+12*4096, ah,al,bh,bl,cgp,t2,mt,lane);
    KFENCE();
    fused_path_fc<5,3,5,256,576,150>(wb,OFF_TP4W+13*4096, ah,al,bh,bl,cgp,t2,mt,lane);
    KFENCE();
    fused_path_fc<3,3,5,576, 64,105>(wb,OFF_TP4W+14*4096, ah,al,bh,bl,cgp,t2,mt,lane);
    KFENCE();
    fused_path_fc<3,5,5,576,256,225>(wb,OFF_TP4W+15*4096, ah,al,bh,bl,cgp,t2,mt,lane);
    KFENCE();
    fused_path_fc<3,3,5,576,576,105>(wb,OFF_TP4W+16*4096, ah,al,bh,bl,cgp,t2,mt,lane);
    #pragma unroll
    for (int k=0;k<5;k++){
      float v = t2[k];
      v += __shfl_xor(v, 16, 64);
      v += __shfl_xor(v, 32, 64);
      if (lane < 8) atomicAdd(&s_out[lane*6 + 1 + k], v);
    }
  }
}

// ============================================================================
// 15 barriers. __launch_bounds__(256,2): cap = 512/2/2 = 128 arch VGPRs
// (R9 proves the kernel fits 128 spill-free). 2 blocks/CU = 2 waves/SIMD x
// 2x128 = 512 = budget; LDS 74,496x2 = 148,992 <= 163,840. Two independent
// barrier domains per CU overlap each other's intra-phase stalls.
// ============================================================================
__global__ __launch_bounds__(NT, 2) void deeprst_main(
    const float* __restrict__ x,
    const float* __restrict__ l1W0, const float* __restrict__ l1W1,
    const float* __restrict__ l1W2, const float* __restrict__ l1b0,
    const float* __restrict__ l2b0, const float* __restrict__ Lb0,
    const unsigned short* __restrict__ wb, const float* __restrict__ cgp,
    float* __restrict__ out)
{
  __shared__ unsigned short sth[3*BUF];   // 37248 B hi plane
  __shared__ unsigned short stl[3*BUF];   // 37248 B lo plane

  const int tid  = threadIdx.x;
  const int lane = tid & 63;
  const int wave = tid >> 6;
  const int n0   = blockIdx.x * TS;
  const float rs8 = 0.3535533905932738f;

  // ---- lin1 (scalar fp32 -> hi/lo), h1 in buffers 0+1 of both planes ----
  for (int idx=tid; idx<TS*128; idx+=NT){
    int n=idx>>7, o=idx&127;
    const float* xp = x + (n0+n)*80;
    float acc=0.f;
    #pragma unroll
    for (int v=0;v<16;v++) acc += xp[v]*l1W0[v*128+o];
    store_hl(sth,stl, n*H1S + o, acc*0.25f + l1b0[o]);
  }
  for (int idx=tid; idx<TS*768; idx+=NT){
    int o=idx&255, i=(idx>>8)%3, n=idx/768;
    const float* xp = x + (n0+n)*80 + 16;
    float acc=0.f;
    #pragma unroll
    for (int v=0;v<8;v++) acc += xp[v*3+i]*l1W1[v*256+o];
    int du = (o<128)? (128 + i*128 + o) : (1152 + i*128 + o-128);
    store_hl(sth,stl, n*H1S + du, acc*rs8);
  }
  for (int idx=tid; idx<TS*640; idx+=NT){
    int o=idx&127, i=(idx>>7)%5, n=idx/640;
    const float* xp = x + (n0+n)*80 + 40;
    float acc=0.f;
    #pragma unroll
    for (int v=0;v<8;v++) acc += xp[v*5+i]*l1W2[v*128+o];
    store_hl(sth,stl, n*H1S + 512 + i*128 + o, acc*rs8);
  }
  __syncthreads();

  // ---- lin2 (MFMA hi/lo): h1 -> buffer 2 ----
  lin2_mfma(wb, l2b0, sth, stl, sth+2*BUF, stl+2*BUF, wave, lane);
  __syncthreads();

  // ---- 3 rounds: split -> fused tp_uvu -> linear (3 barriers/round) ----
  int ih = 2, i0 = 0, i1 = 1;
  for (int r=0;r<3;r++){
    unsigned short *hh=sth+ih*BUF, *hl=stl+ih*BUF;
    unsigned short *ah=sth+i0*BUF, *al=stl+i0*BUF;
    unsigned short *bh=sth+i1*BUF, *bl=stl+i1*BUF;
    linL_mfma(wb, OFF_LW0+(3*r  )*4096, OFF_LW1+(3*r  )*16384, OFF_LW2+(3*r  )*4096,
              Lb0+(3*r  )*64, hh, hl, ah, al, wave, lane);
    linL_mfma(wb, OFF_LW0+(3*r+1)*4096, OFF_LW1+(3*r+1)*16384, OFF_LW2+(3*r+1)*4096,
              Lb0+(3*r+1)*64, hh, hl, bh, bl, wave, lane);
    __syncthreads();   // lin writes -> TP reads
    fused_tp_uvu(wb, OFF_TPW + r*14*4096, ah, al, bh, bl, hh, hl, cgp, wave, lane);
    __syncthreads();   // TP writes h -> linC reads h
    linL_mfma(wb, OFF_LW0+(3*r+2)*4096, OFF_LW1+(3*r+2)*16384, OFF_LW2+(3*r+2)*4096,
              Lb0+(3*r+2)*64, hh, hl, ah, al, wave, lane);
    __syncthreads();   // linC writes a -> next round reads
    int nh=i0; i0=i1; i1=ih; ih=nh;
  }

  // ---- split4 + fully-connected TP ----
  unsigned short *hh=sth+ih*BUF, *hl=stl+ih*BUF;
  unsigned short *ah=sth+i0*BUF, *al=stl+i0*BUF;
  unsigned short *bh=sth+i1*BUF, *bl=stl+i1*BUF;
  linL_mfma(wb, OFF_LW0+ 9*4096, OFF_LW1+ 9*16384, OFF_LW2+ 9*4096, Lb0+ 9*64, hh, hl, ah, al, wave, lane);
  linL_mfma(wb, OFF_LW0+10*4096, OFF_LW1+10*16384, OFF_LW2+10*4096, Lb0+10*64, hh, hl, bh, bl, wave, lane);
  __syncthreads();   // lin reads of h done -> safe to reuse h as s_out

  float* s_out = (float*)hh;   // h buffer dead after split4 linears
  if (tid < TS*6) s_out[tid] = 0.f;
  __syncthreads();   // zero visible before atomics

  fused_tp_fc(wb, ah, al, bh, bl, s_out, cgp, wave, lane);
  __syncthreads();   // atomics done -> read s_out

  if (tid < TS*6){
    int n=tid/6, k=tid%6;
    float sc = (k==0)? (1.0f/sqrtf(24576.0f)) : (1.0f/sqrtf(45056.0f));
    out[(n0+n)*6+k] = s_out[tid]*sc;
  }
}

// ============================================================================
extern "C" void kernel_launch(void* const* d_in, const int* in_sizes, int n_in,
                              void* d_out, int out_size, void* d_ws, size_t ws_size,
                              hipStream_t stream)
{
  (void)n_in; (void)out_size; (void)ws_size;
  const float* x    = (const float*)d_in[0];
  const float* l1W0 = (const float*)d_in[1];
  const float* l1W1 = (const float*)d_in[2];
  const float* l1W2 = (const float*)d_in[3];
  const float* l1b0 = (const float*)d_in[4];
  const float* l2W0 = (const float*)d_in[5];
  const float* l2W1 = (const float*)d_in[6];
  const float* l2W2 = (const float*)d_in[7];
  const float* l2b0 = (const float*)d_in[8];
  const float* LW0  = (const float*)d_in[9];
  const float* LW1  = (const float*)d_in[10];
  const float* LW2  = (const float*)d_in[11];
  const float* Lb0  = (const float*)d_in[12];
  const float* tpw  = (const float*)d_in[13];
  const float* tp4w = (const float*)d_in[14];

  float* cg = (float*)d_ws;                                    // 525 f32 @ ws+0
  unsigned short* wb = (unsigned short*)((char*)d_ws + 4096);  // hi + lo planes
  const int n = in_sizes[0]/80;

  cg_init_kernel<<<1, 576, 0, stream>>>(cg);
  prep_kernel<<<(W_TOT+255)/256, 256, 0, stream>>>(l2W0,l2W1,l2W2,LW0,LW1,LW2,tpw,tp4w,wb);
  deeprst_main<<<n/TS, NT, 0, stream>>>(x,l1W0,l1W1,l1W2,l1b0,l2b0,Lb0,wb,cg,(float*)d_out);
}

// Round 11
// 886.480 us; speedup vs baseline: 1.4030x; 1.4030x over previous
//
#include <hip/hip_runtime.h>
#include <math.h>

constexpr int TS = 16;     // samples per block
constexpr int NT = 512;    // threads per block (8 waves)
constexpr int SSTRIDE = 776;   // bf16 per sample, HID0 state (768 + 8 pad)
constexpr int H1S = 1544;      // bf16 per sample, HID1 transient (1536 + 8 pad)
constexpr int BUF = TS*SSTRIDE;
// HID0 per-sample layout: l0 @0 (64: [u]), l1 @64 (3x64: [i][u]),
// l2 @256 (5x64), l1b @576 (3x64)
// HID1 layout: l0 @0 (128), l1 @128 (3x128), l2 @512 (5x128), l1b @1152 (3x128)
//
// R9 (best, 786us): fused TP, 15 barriers, VGPR=128, zero spill; VALU 23.5%,
// MFMA 9%, ~67% stall. R10 proved co-residency overlap (2 blocks/CU) can
// never pay: freeing room requires TS=8 which doubles per-sample work (MFMA
// M=16 geometry) -- 2x work vs 1.27x issue gain. TLP door closed.
// R11 (this): attack the issue count + intra-phase ILP instead.
// (a) Packed f32x2 contraction: r-pairs {0,1},{2,3} -> v_pk_fma_f32; per
//     (i,j) cost 4+4*D3 -> 2+2*D3 instr. uvu path bit-identical arithmetic.
// (b) KFENCE regions widened 1 path -> 2 paths: live set ~100 regs < 128 cap,
//     and each path's LDS loads hide under its neighbor's VALU tail.

typedef __attribute__((ext_vector_type(8))) short bf16x8;
typedef __attribute__((ext_vector_type(4))) float f32x4;
typedef __attribute__((ext_vector_type(2))) float f32x2;
typedef __attribute__((ext_vector_type(4))) unsigned short u16x4;

#define KFENCE() asm volatile("" ::: "memory")

__device__ inline f32x4 mfma16(bf16x8 a, bf16x8 b, f32x4 c){
  return __builtin_amdgcn_mfma_f32_16x16x32_bf16(a, b, c, 0, 0, 0);
}
__device__ inline unsigned short f2b(float f){
  union { float f; unsigned u; } v; v.f = f;
  return (unsigned short)((v.u + 0x7fffu + ((v.u >> 16) & 1u)) >> 16);
}
__device__ inline float b2f(unsigned short h){
  union { unsigned u; float f; } v; v.u = ((unsigned)h) << 16; return v.f;
}
__device__ inline void store_hl(unsigned short* ph, unsigned short* pl, int idx, float v){
  unsigned short h = f2b(v);
  ph[idx] = h;
  pl[idx] = f2b(v - b2f(h));
}
#define LDFRAG(p) (*(const bf16x8*)(p))

// ws bf16 weight offsets (elements, base = ws+4096B). lo plane at +W_TOT.
constexpr int OFF_L2W0 = 0;        // 64x128 (WT[o][k])
constexpr int OFF_L2W1 = 8192;     // 128x256
constexpr int OFF_L2W2 = 40960;    // 64x128
constexpr int OFF_LW0  = 49152;    // 11 x 64x64
constexpr int OFF_LW1  = 94208;    // 11 x 128x128
constexpr int OFF_LW2  = 274432;   // 11 x 64x64
constexpr int OFF_TPW  = 319488;   // 3x14 x 64x64 ([u][v])
constexpr int OFF_TP4W = 491520;   // 17 x 64x64
constexpr int W_TOT    = 561152;

// ============================================================================
// Clebsch-Gordan init (element-parallel fp64; verified R2/R3)
// offsets: 0:(0,0,0)@0 1:(0,1,1)@1 2:(1,0,1)@10 3:(0,2,2)@19 4:(2,0,2)@44
// 5:(1,1,0)@69 6:(1,1,1)@78 7:(1,1,2)@105 8:(2,1,2)@150 9:(1,2,2)@225
// 10:(2,2,0)@300 11:(2,2,1)@325 12:(2,2,2)@400 ; total 525 floats
// ============================================================================
__device__ inline double dfact(int n){ double r=1.0; for(int i=2;i<=n;i++) r*=(double)i; return r; }
struct dcplx { double x, y; };
__device__ inline dcplx cmul(dcplx a, dcplx b){ return {a.x*b.x-a.y*b.y, a.x*b.y+a.y*b.x}; }

__device__ dcplx Uent(int l, int r, int c){
  double re=0.0, im=0.0;
  double s = 1.0/sqrt(2.0);
  if (r==l && c==l) re = 1.0;
  else if (c>l){ int m=c-l; double sgn=(m&1)?-1.0:1.0;
    if (r==l-m) re = s; else if (r==l+m) re = sgn*s;
  } else if (c<l){ int m=l-c; double sgn=(m&1)?-1.0:1.0;
    if (r==l-m) im = s; else if (r==l+m) im = -sgn*s;
  }
  int lm=l&3; double pr,pi;
  if(lm==0){pr=1;pi=0;} else if(lm==1){pr=0;pi=-1;} else if(lm==2){pr=-1;pi=0;} else {pr=0;pi=1;}
  return { re*pr-im*pi, re*pi+im*pr };
}

__device__ double cg_complex_entry(int l1,int l2,int l3,int m1,int m2){
  int m3=m1+m2;
  if (m3<-l3 || m3>l3) return 0.0;
  double pref = sqrt((double)(2*l3+1)*dfact(l3+l1-l2)*dfact(l3-l1+l2)*dfact(l1+l2-l3)/dfact(l1+l2+l3+1));
  pref *= sqrt(dfact(l3+m3)*dfact(l3-m3)*dfact(l1-m1)*dfact(l1+m1)*dfact(l2-m2)*dfact(l2+m2));
  double s=0.0;
  for(int k=0;k<=l1+l2-l3;k++){
    int a2=l1-m1-k, a3=l2+m2-k, a4=l3-l2+m1+k, a5=l3-l1-m2+k;
    if(a2<0||a3<0||a4<0||a5<0) continue;
    double t=1.0/(dfact(k)*dfact(l1+l2-l3-k)*dfact(a2)*dfact(a3)*dfact(a4)*dfact(a5));
    s += (k&1)? -t : t;
  }
  return pref*s;
}

__global__ void cg_init_kernel(float* cg){
  __shared__ double sKr[525], sKi[525];
  __shared__ double sScale[13];
  __shared__ int    sSel[13];
  const int L1[13]={0,0,1,0,2,1,1,1,2,1,2,2,2};
  const int L2[13]={0,1,0,2,0,1,1,1,1,2,2,2,2};
  const int L3[13]={0,1,1,2,2,0,1,2,2,2,0,1,2};
  const int OFF[14]={0,1,10,19,44,69,78,105,150,225,300,325,400,525};
  const int tid = threadIdx.x;
  int combo=-1, l1=0,l2=0,l3=0;
  if (tid < 525){
    combo=12;
    for(int i=0;i<12;i++) if (tid < OFF[i+1]) { combo=i; break; }
    l1=L1[combo]; l2=L2[combo]; l3=L3[combo];
    int d2=2*l2+1, d3=2*l3+1;
    int e = tid - OFF[combo];
    int a = e/(d2*d3), b=(e/d3)%d2, cc=e%d3;
    double kr=0.0, ki=0.0;
    for(int m=0;m<2*l1+1;m++) for(int n=0;n<d2;n++){
      int m3 = (m-l1)+(n-l2);
      if (m3<-l3||m3>l3) continue;
      double cv = cg_complex_entry(l1,l2,l3,m-l1,n-l2);
      if (cv==0.0) continue;
      dcplx u1=Uent(l1,m,a), u2=Uent(l2,n,b), u3=Uent(l3,m3+l3,cc);
      u3.y = -u3.y;
      dcplx t = cmul(cmul(u1,u2),u3);
      kr += t.x*cv; ki += t.y*cv;
    }
    sKr[tid]=kr; sKi[tid]=ki;
  }
  __syncthreads();
  if (tid < 13){
    int sz = OFF[tid+1]-OFF[tid];
    double nr=0,ni=0;
    for(int i=0;i<sz;i++){ double r=sKr[OFF[tid]+i], im=sKi[OFF[tid]+i]; nr+=r*r; ni+=im*im; }
    int sel = (nr>=ni)? 0 : 1;
    sSel[tid]=sel;
    sScale[tid] = sqrt((double)(2*L3[tid]+1))/sqrt(sel? ni : nr);
  }
  __syncthreads();
  if (tid < 525){
    double v = sSel[combo]? sKi[tid] : sKr[tid];
    cg[tid] = (float)(v*sScale[combo]);
  }
}

// ============================================================================
// Weight prep: fp32 -> bf16 hi/lo planes. Linear weights transposed WT[o][k];
// TP weights [u][v].
// ============================================================================
__global__ void prep_kernel(const float* __restrict__ l2W0, const float* __restrict__ l2W1,
                            const float* __restrict__ l2W2, const float* __restrict__ LW0,
                            const float* __restrict__ LW1, const float* __restrict__ LW2,
                            const float* __restrict__ tpw, const float* __restrict__ tp4w,
                            unsigned short* __restrict__ wb){
  int i = blockIdx.x*256 + threadIdx.x;
  if (i >= W_TOT) return;
  float v;
  if (i < 8192){ int o=i>>7, k=i&127; v = l2W0[k*64+o]; }
  else if (i < 40960){ int j=i-8192; int o=j>>8, k=j&255; v = l2W1[k*128+o]; }
  else if (i < 49152){ int j=i-40960; int o=j>>7, k=j&127; v = l2W2[k*64+o]; }
  else if (i < 94208){ int j=i-49152; int li=j>>12, r=j&4095, o=r>>6, k=r&63; v = LW0[li*4096+k*64+o]; }
  else if (i < 274432){ int j=i-94208; int li=j>>14, r=j&16383, o=r>>7, k=r&127; v = LW1[li*16384+k*128+o]; }
  else if (i < 319488){ int j=i-274432; int li=j>>12, r=j&4095, o=r>>6, k=r&63; v = LW2[li*4096+k*64+o]; }
  else if (i < 491520){ v = tpw[i-319488]; }
  else { v = tp4w[i-491520]; }
  unsigned short h = f2b(v);
  wb[i] = h;
  wb[W_TOT + i] = f2b(v - b2f(h));
}

// ============================================================================
// MFMA linear HID0->HID0 (hi/lo). Jobs: 0..3 l0 | 4..11 l1 | 12..15 l2.
// 8 waves, 2 jobs/wave (R0-verified).
// ============================================================================
__device__ void linL_mfma(const unsigned short* __restrict__ wb, int o0, int o1, int o2,
                          const float* __restrict__ b0,
                          const unsigned short* sh, const unsigned short* sl,
                          unsigned short* dh, unsigned short* dl, int wave, int lane)
{
  const float rs128 = 0.08838834764831845f;
  int l16 = lane & 15, quad = lane >> 4;
  int abase = l16 * SSTRIDE;
  for (int job = wave; job < 16; job += 8){
    if (job < 4){                 // l0: K=64, /8 + bias
      int col = job*16 + l16;
      f32x4 a0 = {0,0,0,0}, a1 = {0,0,0,0};
      #pragma unroll
      for (int ks=0; ks<2; ks++){
        int so = abase + ks*32 + quad*8;
        bf16x8 xh = LDFRAG(sh+so), xl = LDFRAG(sl+so);
        int wo = o0 + col*64 + ks*32 + quad*8;
        bf16x8 wh = LDFRAG(wb+wo), wl = LDFRAG(wb+W_TOT+wo);
        a0 = mfma16(xh,wh,a0); a1 = mfma16(xh,wl,a1); a1 = mfma16(xl,wh,a1);
      }
      float bias = b0[col];
      #pragma unroll
      for (int r=0;r<4;r++)
        store_hl(dh,dl,(quad*4+r)*SSTRIDE + col, (a0[r]+a1[r])*0.125f + bias);
    } else if (job < 12){         // l1: K=128 (l1|l1b), /sqrt(128)
      int nt = job-4; int col = nt*16 + l16;
      #pragma unroll
      for (int i=0;i<3;i++){
        f32x4 a0 = {0,0,0,0}, a1 = {0,0,0,0};
        #pragma unroll
        for (int ks=0; ks<4; ks++){
          int ka = ks*32 + quad*8;
          int so = abase + ((ka < 64) ? (64 + i*64 + ka) : (576 + i*64 + ka - 64));
          bf16x8 xh = LDFRAG(sh+so), xl = LDFRAG(sl+so);
          int wo = o1 + col*128 + ka;
          bf16x8 wh = LDFRAG(wb+wo), wl = LDFRAG(wb+W_TOT+wo);
          a0 = mfma16(xh,wh,a0); a1 = mfma16(xh,wl,a1); a1 = mfma16(xl,wh,a1);
        }
        int dof = (col < 64) ? (64 + i*64 + col) : (576 + i*64 + col - 64);
        #pragma unroll
        for (int r=0;r<4;r++)
          store_hl(dh,dl,(quad*4+r)*SSTRIDE + dof, (a0[r]+a1[r])*rs128);
      }
    } else {                      // l2: K=64, /8
      int nt = job-12; int col = nt*16 + l16;
      #pragma unroll
      for (int i=0;i<5;i++){
        f32x4 a0 = {0,0,0,0}, a1 = {0,0,0,0};
        #pragma unroll
        for (int ks=0; ks<2; ks++){
          int so = abase + 256 + i*64 + ks*32 + quad*8;
          bf16x8 xh = LDFRAG(sh+so), xl = LDFRAG(sl+so);
          int wo = o2 + col*64 + ks*32 + quad*8;
          bf16x8 wh = LDFRAG(wb+wo), wl = LDFRAG(wb+W_TOT+wo);
          a0 = mfma16(xh,wh,a0); a1 = mfma16(xh,wl,a1); a1 = mfma16(xl,wh,a1);
        }
        #pragma unroll
        for (int r=0;r<4;r++)
          store_hl(dh,dl,(quad*4+r)*SSTRIDE + 256 + i*64 + col, (a0[r]+a1[r])*0.125f);
      }
    }
  }
}

// lin2: HID1 -> HID0 (K=128/256/128), hi/lo
__device__ void lin2_mfma(const unsigned short* __restrict__ wb,
                          const float* __restrict__ b0,
                          const unsigned short* h1h, const unsigned short* h1l,
                          unsigned short* dh, unsigned short* dl, int wave, int lane)
{
  const float rs128 = 0.08838834764831845f;
  int l16 = lane & 15, quad = lane >> 4;
  int abase = l16 * H1S;
  for (int job = wave; job < 16; job += 8){
    if (job < 4){                 // l0: K=128
      int col = job*16 + l16;
      f32x4 a0 = {0,0,0,0}, a1 = {0,0,0,0};
      #pragma unroll
      for (int ks=0; ks<4; ks++){
        int so = abase + ks*32 + quad*8;
        bf16x8 xh = LDFRAG(h1h+so), xl = LDFRAG(h1l+so);
        int wo = OFF_L2W0 + col*128 + ks*32 + quad*8;
        bf16x8 wh = LDFRAG(wb+wo), wl = LDFRAG(wb+W_TOT+wo);
        a0 = mfma16(xh,wh,a0); a1 = mfma16(xh,wl,a1); a1 = mfma16(xl,wh,a1);
      }
      float bias = b0[col];
      #pragma unroll
      for (int r=0;r<4;r++)
        store_hl(dh,dl,(quad*4+r)*SSTRIDE + col, (a0[r]+a1[r])*rs128 + bias);
    } else if (job < 12){         // l1: K=256, /16
      int nt = job-4; int col = nt*16 + l16;
      #pragma unroll
      for (int i=0;i<3;i++){
        f32x4 a0 = {0,0,0,0}, a1 = {0,0,0,0};
        #pragma unroll
        for (int ks=0; ks<8; ks++){
          int ka = ks*32 + quad*8;
          int so = abase + ((ka < 128) ? (128 + i*128 + ka) : (1152 + i*128 + ka - 128));
          bf16x8 xh = LDFRAG(h1h+so), xl = LDFRAG(h1l+so);
          int wo = OFF_L2W1 + col*256 + ka;
          bf16x8 wh = LDFRAG(wb+wo), wl = LDFRAG(wb+W_TOT+wo);
          a0 = mfma16(xh,wh,a0); a1 = mfma16(xh,wl,a1); a1 = mfma16(xl,wh,a1);
        }
        int dof = (col < 64) ? (64 + i*64 + col) : (576 + i*64 + col - 64);
        #pragma unroll
        for (int r=0;r<4;r++)
          store_hl(dh,dl,(quad*4+r)*SSTRIDE + dof, (a0[r]+a1[r])*0.0625f);
      }
    } else {                      // l2: K=128
      int nt = job-12; int col = nt*16 + l16;
      #pragma unroll
      for (int i=0;i<5;i++){
        f32x4 a0 = {0,0,0,0}, a1 = {0,0,0,0};
        #pragma unroll
        for (int ks=0; ks<4; ks++){
          int so = abase + 512 + i*128 + ks*32 + quad*8;
          bf16x8 xh = LDFRAG(h1h+so), xl = LDFRAG(h1l+so);
          int wo = OFF_L2W2 + col*128 + ks*32 + quad*8;
          bf16x8 wh = LDFRAG(wb+wo), wl = LDFRAG(wb+W_TOT+wo);
          a0 = mfma16(xh,wh,a0); a1 = mfma16(xh,wl,a1); a1 = mfma16(xl,wh,a1);
        }
        #pragma unroll
        for (int r=0;r<4;r++)
          store_hl(dh,dl,(quad*4+r)*SSTRIDE + 256 + i*64 + col, (a0[r]+a1[r])*rs128);
      }
    }
  }
}

// ============================================================================
// Fused TP path: stage b-fragment in regs via MFMA, contract immediately.
// Wave's fixed mt picks the u-block; lane l -> sample n=l&15,
// u = mt*16 + quad*4 + r. PACKED contraction: r-pairs {0,1} and {2,3} live in
// f32x2 (v_pk_fma_f32); per (i,j) cost 2+2*D3 instr (was 4+4*D3).
// tk[h][k] holds (r=2h, r=2h+1). Callers fence every TWO paths.
// ============================================================================
template<int D1,int D2,int D3,int O1,int O2,int CGO>
__device__ __forceinline__ void fused_path(
    const unsigned short* __restrict__ wb, int wo,
    const unsigned short* s1h, const unsigned short* s1l,
    const unsigned short* s2h, const unsigned short* s2l,
    const float* __restrict__ cgp,
    f32x2 (&tk)[2][D3], int mt, int lane)
{
  int l16 = lane & 15, quad = lane >> 4;
  f32x2 x1v[D1][2];
  #pragma unroll
  for (int i=0;i<D1;i++){
    int o = l16*SSTRIDE + O1 + i*64 + mt*16 + quad*4;
    u16x4 xh4 = *(const u16x4*)(s1h + o);
    u16x4 xl4 = *(const u16x4*)(s1l + o);
    #pragma unroll
    for (int h=0;h<2;h++){
      f32x2 v;
      v[0] = b2f(xh4[2*h  ]) + b2f(xl4[2*h  ]);
      v[1] = b2f(xh4[2*h+1]) + b2f(xl4[2*h+1]);
      x1v[i][h] = v;
    }
  }
  #pragma unroll
  for (int j=0;j<D2;j++){
    f32x4 a0 = {0,0,0,0}, a1 = {0,0,0,0};
    #pragma unroll
    for (int ks=0; ks<2; ks++){
      int wofs = wo + (mt*16 + l16)*64 + ks*32 + quad*8;
      bf16x8 wh = LDFRAG(wb + wofs);
      bf16x8 wl = LDFRAG(wb + W_TOT + wofs);
      int sofs = l16*SSTRIDE + O2 + j*64 + ks*32 + quad*8;
      bf16x8 xh = LDFRAG(s2h + sofs);
      bf16x8 xl = LDFRAG(s2l + sofs);
      a0 = mfma16(wh,xh,a0); a1 = mfma16(wh,xl,a1); a1 = mfma16(wl,xh,a1);
    }
    f32x2 bu0, bu1;
    bu0[0] = a0[0]+a1[0]; bu0[1] = a0[1]+a1[1];
    bu1[0] = a0[2]+a1[2]; bu1[1] = a0[3]+a1[3];
    #pragma unroll
    for (int i=0;i<D1;i++){
      f32x2 pr0 = x1v[i][0]*bu0;
      f32x2 pr1 = x1v[i][1]*bu1;
      #pragma unroll
      for (int k=0;k<D3;k++){
        float c = cgp[CGO + (i*D2 + j)*D3 + k];
        f32x2 cc = {c, c};
        tk[0][k] += pr0*cc;
        tk[1][k] += pr1*cc;
      }
    }
  }
}

// FC variant: output summed over u. Packed: tk2[k] accumulates r-pairs;
// caller folds tk[k][0]+tk[k][1] before the lane reduce.
template<int D1,int D2,int D3,int O1,int O2,int CGO>
__device__ __forceinline__ void fused_path_fc(
    const unsigned short* __restrict__ wb, int wo,
    const unsigned short* s1h, const unsigned short* s1l,
    const unsigned short* s2h, const unsigned short* s2l,
    const float* __restrict__ cgp,
    f32x2 (&tk)[D3], int mt, int lane)
{
  int l16 = lane & 15, quad = lane >> 4;
  f32x2 x1v[D1][2];
  #pragma unroll
  for (int i=0;i<D1;i++){
    int o = l16*SSTRIDE + O1 + i*64 + mt*16 + quad*4;
    u16x4 xh4 = *(const u16x4*)(s1h + o);
    u16x4 xl4 = *(const u16x4*)(s1l + o);
    #pragma unroll
    for (int h=0;h<2;h++){
      f32x2 v;
      v[0] = b2f(xh4[2*h  ]) + b2f(xl4[2*h  ]);
      v[1] = b2f(xh4[2*h+1]) + b2f(xl4[2*h+1]);
      x1v[i][h] = v;
    }
  }
  #pragma unroll
  for (int j=0;j<D2;j++){
    f32x4 a0 = {0,0,0,0}, a1 = {0,0,0,0};
    #pragma unroll
    for (int ks=0; ks<2; ks++){
      int wofs = wo + (mt*16 + l16)*64 + ks*32 + quad*8;
      bf16x8 wh = LDFRAG(wb + wofs);
      bf16x8 wl = LDFRAG(wb + W_TOT + wofs);
      int sofs = l16*SSTRIDE + O2 + j*64 + ks*32 + quad*8;
      bf16x8 xh = LDFRAG(s2h + sofs);
      bf16x8 xl = LDFRAG(s2l + sofs);
      a0 = mfma16(wh,xh,a0); a1 = mfma16(wh,xl,a1); a1 = mfma16(wl,xh,a1);
    }
    f32x2 bu0, bu1;
    bu0[0] = a0[0]+a1[0]; bu0[1] = a0[1]+a1[1];
    bu1[0] = a0[2]+a1[2]; bu1[1] = a0[3]+a1[3];
    #pragma unroll
    for (int i=0;i<D1;i++){
      f32x2 pr = x1v[i][0]*bu0;
      pr += x1v[i][1]*bu1;
      #pragma unroll
      for (int k=0;k<D3;k++){
        float c = cgp[CGO + (i*D2 + j)*D3 + k];
        f32x2 cc = {c, c};
        tk[k] += pr*cc;
      }
    }
  }
}

// pack 4 consecutive u-values into one b64 store per plane
__device__ inline void store4_hl(unsigned short* ph, unsigned short* pl, int idx,
                                 float v0, float v1, float v2, float v3){
  u16x4 vh, vl;
  float v[4] = {v0,v1,v2,v3};
  #pragma unroll
  for (int r=0;r<4;r++){
    unsigned short h = f2b(v[r]);
    vh[r] = h;
    vl[r] = f2b(v[r] - b2f(h));
  }
  *(u16x4*)(ph + idx) = vh;
  *(u16x4*)(pl + idx) = vl;
}

// uvu TP, one barrier-free phase. Waves 0-3 (mt=w): out l0 + l2;
// waves 4-7 (mt=w-4): out l1 + l1b. KFENCE every 2 paths (2-path live set
// ~100 regs < 128 cap; cross-path ILP within each region).
__device__ void fused_tp_uvu(const unsigned short* __restrict__ wb, int two,
    const unsigned short* ah, const unsigned short* al,
    const unsigned short* bh, const unsigned short* bl,
    unsigned short* dh, unsigned short* dl,
    const float* __restrict__ cgp, int wave, int lane)
{
  const float f192 = 0.07216878364870323f;  // 1/sqrt(192)
  const float f256 = 0.0625f;               // 1/sqrt(256)
  int mt = wave & 3;
  int l16 = lane & 15, quad = lane >> 4;
  int u0 = mt*16 + quad*4;
  if (wave < 4){
    { // out l0 @0 (fan 192): paths 0,5,10
      f32x2 tk0[2][1] = {};
      fused_path<1,1,1,  0,  0,  0>(wb,two+ 0*4096, ah,al,bh,bl,cgp,tk0,mt,lane);
      fused_path<3,3,1, 64, 64, 69>(wb,two+ 5*4096, ah,al,bh,bl,cgp,tk0,mt,lane);
      KFENCE();
      fused_path<5,5,1,256,256,300>(wb,two+10*4096, ah,al,bh,bl,cgp,tk0,mt,lane);
      store4_hl(dh,dl, l16*SSTRIDE + u0,
                tk0[0][0][0]*f192, tk0[0][0][1]*f192, tk0[1][0][0]*f192, tk0[1][0][1]*f192);
      KFENCE();
    }
    { // out l2 @256 (fan 256): paths 2,8,9,13
      f32x2 tk2[2][5] = {};
      fused_path<1,5,5,  0,256, 19>(wb,two+ 2*4096, ah,al,bh,bl,cgp,tk2,mt,lane);
      fused_path<5,1,5,256,  0, 44>(wb,two+ 8*4096, ah,al,bh,bl,cgp,tk2,mt,lane);
      KFENCE();
      fused_path<5,3,5,256, 64,150>(wb,two+ 9*4096, ah,al,bh,bl,cgp,tk2,mt,lane);
      fused_path<5,3,5,256,576,150>(wb,two+13*4096, ah,al,bh,bl,cgp,tk2,mt,lane);
      #pragma unroll
      for (int k=0;k<5;k++)
        store4_hl(dh,dl, l16*SSTRIDE + 256 + k*64 + u0,
                  tk2[0][k][0]*f256, tk2[0][k][1]*f256, tk2[1][k][0]*f256, tk2[1][k][1]*f256);
    }
  } else {
    { // out l1 @64 (fan 256): paths 1,4,6,11
      f32x2 tkA[2][3] = {};
      fused_path<1,3,3,  0, 64,  1>(wb,two+ 1*4096, ah,al,bh,bl,cgp,tkA,mt,lane);
      fused_path<3,1,3, 64,  0, 10>(wb,two+ 4*4096, ah,al,bh,bl,cgp,tkA,mt,lane);
      KFENCE();
      fused_path<3,3,3, 64, 64, 78>(wb,two+ 6*4096, ah,al,bh,bl,cgp,tkA,mt,lane);
      fused_path<5,5,3,256,256,325>(wb,two+11*4096, ah,al,bh,bl,cgp,tkA,mt,lane);
      #pragma unroll
      for (int k=0;k<3;k++)
        store4_hl(dh,dl, l16*SSTRIDE +  64 + k*64 + u0,
                  tkA[0][k][0]*f256, tkA[0][k][1]*f256, tkA[1][k][0]*f256, tkA[1][k][1]*f256);
      KFENCE();
    }
    { // out l1b @576 (fan 192): paths 3,7,12
      f32x2 tkB[2][3] = {};
      fused_path<1,3,3,  0,576,  1>(wb,two+ 3*4096, ah,al,bh,bl,cgp,tkB,mt,lane);
      fused_path<3,3,3, 64, 64, 78>(wb,two+ 7*4096, ah,al,bh,bl,cgp,tkB,mt,lane);
      KFENCE();
      fused_path<5,5,3,256,256,325>(wb,two+12*4096, ah,al,bh,bl,cgp,tkB,mt,lane);
      #pragma unroll
      for (int k=0;k<3;k++)
        store4_hl(dh,dl, l16*SSTRIDE + 576 + k*64 + u0,
                  tkB[0][k][0]*f192, tkB[0][k][1]*f192, tkB[1][k][0]*f192, tkB[1][k][1]*f192);
    }
  }
}

// FC TP: output sums over u via atomicAdd; 0e group completes before the 2e
// group. KFENCE every 2 paths. Fold f32x2 pairs before the lane reduce.
__device__ void fused_tp_fc(const unsigned short* __restrict__ wb,
    const unsigned short* ah, const unsigned short* al,
    const unsigned short* bh, const unsigned short* bl,
    float* s_out, const float* __restrict__ cgp, int wave, int lane)
{
  int mt = wave & 3, half = wave >> 2;
  int l16 = lane & 15;
  { // 0e partials
    f32x2 t0[1] = {};
    if (half == 0){
      fused_path_fc<1,1,1,  0,  0,  0>(wb,OFF_TP4W+ 0*4096, ah,al,bh,bl,cgp,t0,mt,lane);
      fused_path_fc<3,3,1, 64, 64, 69>(wb,OFF_TP4W+ 1*4096, ah,al,bh,bl,cgp,t0,mt,lane);
      KFENCE();
      fused_path_fc<3,3,1, 64,576, 69>(wb,OFF_TP4W+ 2*4096, ah,al,bh,bl,cgp,t0,mt,lane);
    } else {
      fused_path_fc<5,5,1,256,256,300>(wb,OFF_TP4W+ 3*4096, ah,al,bh,bl,cgp,t0,mt,lane);
      fused_path_fc<3,3,1,576, 64, 69>(wb,OFF_TP4W+ 4*4096, ah,al,bh,bl,cgp,t0,mt,lane);
      KFENCE();
      fused_path_fc<3,3,1,576,576, 69>(wb,OFF_TP4W+ 5*4096, ah,al,bh,bl,cgp,t0,mt,lane);
    }
    float v0 = t0[0][0] + t0[0][1];
    v0 += __shfl_xor(v0, 16, 64);
    v0 += __shfl_xor(v0, 32, 64);
    if (lane < 16) atomicAdd(&s_out[l16*6 + 0], v0);
  }
  KFENCE();
  { // 2e partials
    f32x2 t2[5] = {};
    if (half == 0){
      fused_path_fc<3,5,5, 64,256,225>(wb,OFF_TP4W+ 8*4096, ah,al,bh,bl,cgp,t2,mt,lane);
      fused_path_fc<5,3,5,256, 64,150>(wb,OFF_TP4W+11*4096, ah,al,bh,bl,cgp,t2,mt,lane);
      KFENCE();
      fused_path_fc<5,5,5,256,256,400>(wb,OFF_TP4W+12*4096, ah,al,bh,bl,cgp,t2,mt,lane);
      fused_path_fc<5,3,5,256,576,150>(wb,OFF_TP4W+13*4096, ah,al,bh,bl,cgp,t2,mt,lane);
    } else {
      fused_path_fc<1,5,5,  0,256, 19>(wb,OFF_TP4W+ 6*4096, ah,al,bh,bl,cgp,t2,mt,lane);
      fused_path_fc<3,3,5, 64, 64,105>(wb,OFF_TP4W+ 7*4096, ah,al,bh,bl,cgp,t2,mt,lane);
      KFENCE();
      fused_path_fc<3,3,5, 64,576,105>(wb,OFF_TP4W+ 9*4096, ah,al,bh,bl,cgp,t2,mt,lane);
      fused_path_fc<5,1,5,256,  0, 44>(wb,OFF_TP4W+10*4096, ah,al,bh,bl,cgp,t2,mt,lane);
      KFENCE();
      fused_path_fc<3,3,5,576, 64,105>(wb,OFF_TP4W+14*4096, ah,al,bh,bl,cgp,t2,mt,lane);
      fused_path_fc<3,5,5,576,256,225>(wb,OFF_TP4W+15*4096, ah,al,bh,bl,cgp,t2,mt,lane);
      KFENCE();
      fused_path_fc<3,3,5,576,576,105>(wb,OFF_TP4W+16*4096, ah,al,bh,bl,cgp,t2,mt,lane);
    }
    #pragma unroll
    for (int k=0;k<5;k++){
      float v = t2[k][0] + t2[k][1];
      v += __shfl_xor(v, 16, 64);
      v += __shfl_xor(v, 32, 64);
      if (lane < 16) atomicAdd(&s_out[l16*6 + 1 + k], v);
    }
  }
}

// ============================================================================
// 15 barriers total. VGPR arch-cap at 8 waves/CU is 128 (backend halves the
// unified budget for AGPRs); 2-path KFENCE regions keep live pressure under
// it while restoring cross-path ILP.
// ============================================================================
__global__ __launch_bounds__(NT) void deeprst_main(
    const float* __restrict__ x,
    const float* __restrict__ l1W0, const float* __restrict__ l1W1,
    const float* __restrict__ l1W2, const float* __restrict__ l1b0,
    const float* __restrict__ l2b0, const float* __restrict__ Lb0,
    const unsigned short* __restrict__ wb, const float* __restrict__ cgp,
    float* __restrict__ out)
{
  __shared__ unsigned short sth[3*BUF];   // 74496 B hi plane
  __shared__ unsigned short stl[3*BUF];   // 74496 B lo plane

  const int tid  = threadIdx.x;
  const int lane = tid & 63;
  const int wave = tid >> 6;
  const int n0   = blockIdx.x * TS;
  const float rs8 = 0.3535533905932738f;

  // ---- lin1 (scalar fp32 -> hi/lo), h1 in buffers 0+1 of both planes ----
  for (int idx=tid; idx<TS*128; idx+=NT){
    int n=idx>>7, o=idx&127;
    const float* xp = x + (n0+n)*80;
    float acc=0.f;
    #pragma unroll
    for (int v=0;v<16;v++) acc += xp[v]*l1W0[v*128+o];
    store_hl(sth,stl, n*H1S + o, acc*0.25f + l1b0[o]);
  }
  for (int idx=tid; idx<TS*768; idx+=NT){
    int o=idx&255, i=(idx>>8)%3, n=idx/768;
    const float* xp = x + (n0+n)*80 + 16;
    float acc=0.f;
    #pragma unroll
    for (int v=0;v<8;v++) acc += xp[v*3+i]*l1W1[v*256+o];
    int du = (o<128)? (128 + i*128 + o) : (1152 + i*128 + o-128);
    store_hl(sth,stl, n*H1S + du, acc*rs8);
  }
  for (int idx=tid; idx<TS*640; idx+=NT){
    int o=idx&127, i=(idx>>7)%5, n=idx/640;
    const float* xp = x + (n0+n)*80 + 40;
    float acc=0.f;
    #pragma unroll
    for (int v=0;v<8;v++) acc += xp[v*5+i]*l1W2[v*128+o];
    store_hl(sth,stl, n*H1S + 512 + i*128 + o, acc*rs8);
  }
  __syncthreads();

  // ---- lin2 (MFMA hi/lo): h1 -> buffer 2 ----
  lin2_mfma(wb, l2b0, sth, stl, sth+2*BUF, stl+2*BUF, wave, lane);
  __syncthreads();

  // ---- 3 rounds: split -> fused tp_uvu -> linear (3 barriers/round) ----
  int ih = 2, i0 = 0, i1 = 1;
  for (int r=0;r<3;r++){
    unsigned short *hh=sth+ih*BUF, *hl=stl+ih*BUF;
    unsigned short *ah=sth+i0*BUF, *al=stl+i0*BUF;
    unsigned short *bh=sth+i1*BUF, *bl=stl+i1*BUF;
    linL_mfma(wb, OFF_LW0+(3*r  )*4096, OFF_LW1+(3*r  )*16384, OFF_LW2+(3*r  )*4096,
              Lb0+(3*r  )*64, hh, hl, ah, al, wave, lane);
    linL_mfma(wb, OFF_LW0+(3*r+1)*4096, OFF_LW1+(3*r+1)*16384, OFF_LW2+(3*r+1)*4096,
              Lb0+(3*r+1)*64, hh, hl, bh, bl, wave, lane);
    __syncthreads();   // lin writes -> TP reads
    fused_tp_uvu(wb, OFF_TPW + r*14*4096, ah, al, bh, bl, hh, hl, cgp, wave, lane);
    __syncthreads();   // TP writes h -> linC reads h
    linL_mfma(wb, OFF_LW0+(3*r+2)*4096, OFF_LW1+(3*r+2)*16384, OFF_LW2+(3*r+2)*4096,
              Lb0+(3*r+2)*64, hh, hl, ah, al, wave, lane);
    __syncthreads();   // linC writes a -> next round reads
    int nh=i0; i0=i1; i1=ih; ih=nh;
  }

  // ---- split4 + fully-connected TP ----
  unsigned short *hh=sth+ih*BUF, *hl=stl+ih*BUF;
  unsigned short *ah=sth+i0*BUF, *al=stl+i0*BUF;
  unsigned short *bh=sth+i1*BUF, *bl=stl+i1*BUF;
  linL_mfma(wb, OFF_LW0+ 9*4096, OFF_LW1+ 9*16384, OFF_LW2+ 9*4096, Lb0+ 9*64, hh, hl, ah, al, wave, lane);
  linL_mfma(wb, OFF_LW0+10*4096, OFF_LW1+10*16384, OFF_LW2+10*4096, Lb0+10*64, hh, hl, bh, bl, wave, lane);
  __syncthreads();   // lin reads of h done -> safe to reuse h as s_out

  float* s_out = (float*)hh;   // h buffer dead after split4 linears
  if (tid < TS*6) s_out[tid] = 0.f;
  __syncthreads();   // zero visible before atomics

  fused_tp_fc(wb, ah, al, bh, bl, s_out, cgp, wave, lane);
  __syncthreads();   // atomics done -> read s_out

  if (tid < TS*6){
    int n=tid/6, k=tid%6;
    float sc = (k==0)? (1.0f/sqrtf(24576.0f)) : (1.0f/sqrtf(45056.0f));
    out[(n0+n)*6+k] = s_out[tid]*sc;
  }
}

// ============================================================================
extern "C" void kernel_launch(void* const* d_in, const int* in_sizes, int n_in,
                              void* d_out, int out_size, void* d_ws, size_t ws_size,
                              hipStream_t stream)
{
  (void)n_in; (void)out_size; (void)ws_size;
  const float* x    = (const float*)d_in[0];
  const float* l1W0 = (const float*)d_in[1];
  const float* l1W1 = (const float*)d_in[2];
  const float* l1W2 = (const float*)d_in[3];
  const float* l1b0 = (const float*)d_in[4];
  const float* l2W0 = (const float*)d_in[5];
  const float* l2W1 = (const float*)d_in[6];
  const float* l2W2 = (const float*)d_in[7];
  const float* l2b0 = (const float*)d_in[8];
  const float* LW0  = (const float*)d_in[9];
  const float* LW1  = (const float*)d_in[10];
  const float* LW2  = (const float*)d_in[11];
  const float* Lb0  = (const float*)d_in[12];
  const float* tpw  = (const float*)d_in[13];
  const float* tp4w = (const float*)d_in[14];

  float* cg = (float*)d_ws;                                    // 525 f32 @ ws+0
  unsigned short* wb = (unsigned short*)((char*)d_ws + 4096);  // hi + lo planes
  const int n = in_sizes[0]/80;

  cg_init_kernel<<<1, 576, 0, stream>>>(cg);
  prep_kernel<<<(W_TOT+255)/256, 256, 0, stream>>>(l2W0,l2W1,l2W2,LW0,LW1,LW2,tpw,tp4w,wb);
  deeprst_main<<<n/TS, NT, 0, stream>>>(x,l1W0,l1W1,l1W2,l1b0,l2b0,Lb0,wb,cg,(float*)d_out);
}

// Round 12
// 815.363 us; speedup vs baseline: 1.5254x; 1.0872x over previous
//
#include <hip/hip_runtime.h>
#include <math.h>

constexpr int TS = 16;     // samples per block
constexpr int NT = 768;    // threads per block (12 waves = 3 waves/SIMD)
constexpr int NW = NT/64;  // 12 waves
constexpr int SSTRIDE = 776;   // bf16 per sample, HID0 state (768 + 8 pad)
constexpr int H1S = 1544;      // bf16 per sample, HID1 transient (1536 + 8 pad)
constexpr int BUF = TS*SSTRIDE;
// HID0 per-sample layout: l0 @0 (64: [u]), l1 @64 (3x64: [i][u]),
// l2 @256 (5x64), l1b @576 (3x64)
// HID1 layout: l0 @0 (128), l1 @128 (3x128), l2 @512 (5x128), l1b @1152 (3x128)
//
// R11: packed f32x2 contraction dropped VGPR 128->88 but dur 786->822 --
// kernel is LATENCY-bound (VALU 22%, MFMA 9%, ~67% dependency stall at
// 2 waves/SIMD), not issue-bound. The VGPR drop unlocks 3 waves/SIMD:
// cap = 512/3/2 = 85 ~ 88 needed. R3's NT=768 failure was in the 165-barrier
// drain regime; at 15 barriers the stall is intra-phase latency, which more
// waves/SIMD directly hides. R12: NT=768 with true 12-way partitions:
// - linears: waves 0-3 {l0+l2} (36 MFMA), waves 4-11 one l1 (36 MFMA).
// - TP uvu: 3 groups x 4 mt by OUTPUT irrep (disjoint LDS, no merge):
//   w0-3 l2 (~480 VALU), w4-7 l1 (~320), w8-11 l1b+l0 (~436); crit 620->480.
// - FC: 3 path-groups (~580/616/624); atomics make any split valid.

typedef __attribute__((ext_vector_type(8))) short bf16x8;
typedef __attribute__((ext_vector_type(4))) float f32x4;
typedef __attribute__((ext_vector_type(2))) float f32x2;
typedef __attribute__((ext_vector_type(4))) unsigned short u16x4;

#define KFENCE() asm volatile("" ::: "memory")

__device__ inline f32x4 mfma16(bf16x8 a, bf16x8 b, f32x4 c){
  return __builtin_amdgcn_mfma_f32_16x16x32_bf16(a, b, c, 0, 0, 0);
}
__device__ inline unsigned short f2b(float f){
  union { float f; unsigned u; } v; v.f = f;
  return (unsigned short)((v.u + 0x7fffu + ((v.u >> 16) & 1u)) >> 16);
}
__device__ inline float b2f(unsigned short h){
  union { unsigned u; float f; } v; v.u = ((unsigned)h) << 16; return v.f;
}
__device__ inline void store_hl(unsigned short* ph, unsigned short* pl, int idx, float v){
  unsigned short h = f2b(v);
  ph[idx] = h;
  pl[idx] = f2b(v - b2f(h));
}
#define LDFRAG(p) (*(const bf16x8*)(p))

// ws bf16 weight offsets (elements, base = ws+4096B). lo plane at +W_TOT.
constexpr int OFF_L2W0 = 0;        // 64x128 (WT[o][k])
constexpr int OFF_L2W1 = 8192;     // 128x256
constexpr int OFF_L2W2 = 40960;    // 64x128
constexpr int OFF_LW0  = 49152;    // 11 x 64x64
constexpr int OFF_LW1  = 94208;    // 11 x 128x128
constexpr int OFF_LW2  = 274432;   // 11 x 64x64
constexpr int OFF_TPW  = 319488;   // 3x14 x 64x64 ([u][v])
constexpr int OFF_TP4W = 491520;   // 17 x 64x64
constexpr int W_TOT    = 561152;

// ============================================================================
// Clebsch-Gordan init (element-parallel fp64; verified R2/R3)
// offsets: 0:(0,0,0)@0 1:(0,1,1)@1 2:(1,0,1)@10 3:(0,2,2)@19 4:(2,0,2)@44
// 5:(1,1,0)@69 6:(1,1,1)@78 7:(1,1,2)@105 8:(2,1,2)@150 9:(1,2,2)@225
// 10:(2,2,0)@300 11:(2,2,1)@325 12:(2,2,2)@400 ; total 525 floats
// ============================================================================
__device__ inline double dfact(int n){ double r=1.0; for(int i=2;i<=n;i++) r*=(double)i; return r; }
struct dcplx { double x, y; };
__device__ inline dcplx cmul(dcplx a, dcplx b){ return {a.x*b.x-a.y*b.y, a.x*b.y+a.y*b.x}; }

__device__ dcplx Uent(int l, int r, int c){
  double re=0.0, im=0.0;
  double s = 1.0/sqrt(2.0);
  if (r==l && c==l) re = 1.0;
  else if (c>l){ int m=c-l; double sgn=(m&1)?-1.0:1.0;
    if (r==l-m) re = s; else if (r==l+m) re = sgn*s;
  } else if (c<l){ int m=l-c; double sgn=(m&1)?-1.0:1.0;
    if (r==l-m) im = s; else if (r==l+m) im = -sgn*s;
  }
  int lm=l&3; double pr,pi;
  if(lm==0){pr=1;pi=0;} else if(lm==1){pr=0;pi=-1;} else if(lm==2){pr=-1;pi=0;} else {pr=0;pi=1;}
  return { re*pr-im*pi, re*pi+im*pr };
}

__device__ double cg_complex_entry(int l1,int l2,int l3,int m1,int m2){
  int m3=m1+m2;
  if (m3<-l3 || m3>l3) return 0.0;
  double pref = sqrt((double)(2*l3+1)*dfact(l3+l1-l2)*dfact(l3-l1+l2)*dfact(l1+l2-l3)/dfact(l1+l2+l3+1));
  pref *= sqrt(dfact(l3+m3)*dfact(l3-m3)*dfact(l1-m1)*dfact(l1+m1)*dfact(l2-m2)*dfact(l2+m2));
  double s=0.0;
  for(int k=0;k<=l1+l2-l3;k++){
    int a2=l1-m1-k, a3=l2+m2-k, a4=l3-l2+m1+k, a5=l3-l1-m2+k;
    if(a2<0||a3<0||a4<0||a5<0) continue;
    double t=1.0/(dfact(k)*dfact(l1+l2-l3-k)*dfact(a2)*dfact(a3)*dfact(a4)*dfact(a5));
    s += (k&1)? -t : t;
  }
  return pref*s;
}

__global__ void cg_init_kernel(float* cg){
  __shared__ double sKr[525], sKi[525];
  __shared__ double sScale[13];
  __shared__ int    sSel[13];
  const int L1[13]={0,0,1,0,2,1,1,1,2,1,2,2,2};
  const int L2[13]={0,1,0,2,0,1,1,1,1,2,2,2,2};
  const int L3[13]={0,1,1,2,2,0,1,2,2,2,0,1,2};
  const int OFF[14]={0,1,10,19,44,69,78,105,150,225,300,325,400,525};
  const int tid = threadIdx.x;
  int combo=-1, l1=0,l2=0,l3=0;
  if (tid < 525){
    combo=12;
    for(int i=0;i<12;i++) if (tid < OFF[i+1]) { combo=i; break; }
    l1=L1[combo]; l2=L2[combo]; l3=L3[combo];
    int d2=2*l2+1, d3=2*l3+1;
    int e = tid - OFF[combo];
    int a = e/(d2*d3), b=(e/d3)%d2, cc=e%d3;
    double kr=0.0, ki=0.0;
    for(int m=0;m<2*l1+1;m++) for(int n=0;n<d2;n++){
      int m3 = (m-l1)+(n-l2);
      if (m3<-l3||m3>l3) continue;
      double cv = cg_complex_entry(l1,l2,l3,m-l1,n-l2);
      if (cv==0.0) continue;
      dcplx u1=Uent(l1,m,a), u2=Uent(l2,n,b), u3=Uent(l3,m3+l3,cc);
      u3.y = -u3.y;
      dcplx t = cmul(cmul(u1,u2),u3);
      kr += t.x*cv; ki += t.y*cv;
    }
    sKr[tid]=kr; sKi[tid]=ki;
  }
  __syncthreads();
  if (tid < 13){
    int sz = OFF[tid+1]-OFF[tid];
    double nr=0,ni=0;
    for(int i=0;i<sz;i++){ double r=sKr[OFF[tid]+i], im=sKi[OFF[tid]+i]; nr+=r*r; ni+=im*im; }
    int sel = (nr>=ni)? 0 : 1;
    sSel[tid]=sel;
    sScale[tid] = sqrt((double)(2*L3[tid]+1))/sqrt(sel? ni : nr);
  }
  __syncthreads();
  if (tid < 525){
    double v = sSel[combo]? sKi[tid] : sKr[tid];
    cg[tid] = (float)(v*sScale[combo]);
  }
}

// ============================================================================
// Weight prep: fp32 -> bf16 hi/lo planes. Linear weights transposed WT[o][k];
// TP weights [u][v].
// ============================================================================
__global__ void prep_kernel(const float* __restrict__ l2W0, const float* __restrict__ l2W1,
                            const float* __restrict__ l2W2, const float* __restrict__ LW0,
                            const float* __restrict__ LW1, const float* __restrict__ LW2,
                            const float* __restrict__ tpw, const float* __restrict__ tp4w,
                            unsigned short* __restrict__ wb){
  int i = blockIdx.x*256 + threadIdx.x;
  if (i >= W_TOT) return;
  float v;
  if (i < 8192){ int o=i>>7, k=i&127; v = l2W0[k*64+o]; }
  else if (i < 40960){ int j=i-8192; int o=j>>8, k=j&255; v = l2W1[k*128+o]; }
  else if (i < 49152){ int j=i-40960; int o=j>>7, k=j&127; v = l2W2[k*64+o]; }
  else if (i < 94208){ int j=i-49152; int li=j>>12, r=j&4095, o=r>>6, k=r&63; v = LW0[li*4096+k*64+o]; }
  else if (i < 274432){ int j=i-94208; int li=j>>14, r=j&16383, o=r>>7, k=r&127; v = LW1[li*16384+k*128+o]; }
  else if (i < 319488){ int j=i-274432; int li=j>>12, r=j&4095, o=r>>6, k=r&63; v = LW2[li*4096+k*64+o]; }
  else if (i < 491520){ v = tpw[i-319488]; }
  else { v = tp4w[i-491520]; }
  unsigned short h = f2b(v);
  wb[i] = h;
  wb[W_TOT + i] = f2b(v - b2f(h));
}

// ============================================================================
// MFMA linear HID0->HID0 (hi/lo). Jobs: 0..3 l0 | 4..11 l1 | 12..15 l2.
// NW=12: waves 0-3 do {l0, l2} (36 MFMA), waves 4-11 one l1 (36 MFMA).
// ============================================================================
__device__ void linL_mfma(const unsigned short* __restrict__ wb, int o0, int o1, int o2,
                          const float* __restrict__ b0,
                          const unsigned short* sh, const unsigned short* sl,
                          unsigned short* dh, unsigned short* dl, int wave, int lane)
{
  const float rs128 = 0.08838834764831845f;
  int l16 = lane & 15, quad = lane >> 4;
  int abase = l16 * SSTRIDE;
  for (int job = wave; job < 16; job += NW){
    if (job < 4){                 // l0: K=64, /8 + bias
      int col = job*16 + l16;
      f32x4 a0 = {0,0,0,0}, a1 = {0,0,0,0};
      #pragma unroll
      for (int ks=0; ks<2; ks++){
        int so = abase + ks*32 + quad*8;
        bf16x8 xh = LDFRAG(sh+so), xl = LDFRAG(sl+so);
        int wo = o0 + col*64 + ks*32 + quad*8;
        bf16x8 wh = LDFRAG(wb+wo), wl = LDFRAG(wb+W_TOT+wo);
        a0 = mfma16(xh,wh,a0); a1 = mfma16(xh,wl,a1); a1 = mfma16(xl,wh,a1);
      }
      float bias = b0[col];
      #pragma unroll
      for (int r=0;r<4;r++)
        store_hl(dh,dl,(quad*4+r)*SSTRIDE + col, (a0[r]+a1[r])*0.125f + bias);
    } else if (job < 12){         // l1: K=128 (l1|l1b), /sqrt(128)
      int nt = job-4; int col = nt*16 + l16;
      #pragma unroll
      for (int i=0;i<3;i++){
        f32x4 a0 = {0,0,0,0}, a1 = {0,0,0,0};
        #pragma unroll
        for (int ks=0; ks<4; ks++){
          int ka = ks*32 + quad*8;
          int so = abase + ((ka < 64) ? (64 + i*64 + ka) : (576 + i*64 + ka - 64));
          bf16x8 xh = LDFRAG(sh+so), xl = LDFRAG(sl+so);
          int wo = o1 + col*128 + ka;
          bf16x8 wh = LDFRAG(wb+wo), wl = LDFRAG(wb+W_TOT+wo);
          a0 = mfma16(xh,wh,a0); a1 = mfma16(xh,wl,a1); a1 = mfma16(xl,wh,a1);
        }
        int dof = (col < 64) ? (64 + i*64 + col) : (576 + i*64 + col - 64);
        #pragma unroll
        for (int r=0;r<4;r++)
          store_hl(dh,dl,(quad*4+r)*SSTRIDE + dof, (a0[r]+a1[r])*rs128);
      }
    } else {                      // l2: K=64, /8
      int nt = job-12; int col = nt*16 + l16;
      #pragma unroll
      for (int i=0;i<5;i++){
        f32x4 a0 = {0,0,0,0}, a1 = {0,0,0,0};
        #pragma unroll
        for (int ks=0; ks<2; ks++){
          int so = abase + 256 + i*64 + ks*32 + quad*8;
          bf16x8 xh = LDFRAG(sh+so), xl = LDFRAG(sl+so);
          int wo = o2 + col*64 + ks*32 + quad*8;
          bf16x8 wh = LDFRAG(wb+wo), wl = LDFRAG(wb+W_TOT+wo);
          a0 = mfma16(xh,wh,a0); a1 = mfma16(xh,wl,a1); a1 = mfma16(xl,wh,a1);
        }
        #pragma unroll
        for (int r=0;r<4;r++)
          store_hl(dh,dl,(quad*4+r)*SSTRIDE + 256 + i*64 + col, (a0[r]+a1[r])*0.125f);
      }
    }
  }
}

// lin2: HID1 -> HID0 (K=128/256/128), hi/lo
__device__ void lin2_mfma(const unsigned short* __restrict__ wb,
                          const float* __restrict__ b0,
                          const unsigned short* h1h, const unsigned short* h1l,
                          unsigned short* dh, unsigned short* dl, int wave, int lane)
{
  const float rs128 = 0.08838834764831845f;
  int l16 = lane & 15, quad = lane >> 4;
  int abase = l16 * H1S;
  for (int job = wave; job < 16; job += NW){
    if (job < 4){                 // l0: K=128
      int col = job*16 + l16;
      f32x4 a0 = {0,0,0,0}, a1 = {0,0,0,0};
      #pragma unroll
      for (int ks=0; ks<4; ks++){
        int so = abase + ks*32 + quad*8;
        bf16x8 xh = LDFRAG(h1h+so), xl = LDFRAG(h1l+so);
        int wo = OFF_L2W0 + col*128 + ks*32 + quad*8;
        bf16x8 wh = LDFRAG(wb+wo), wl = LDFRAG(wb+W_TOT+wo);
        a0 = mfma16(xh,wh,a0); a1 = mfma16(xh,wl,a1); a1 = mfma16(xl,wh,a1);
      }
      float bias = b0[col];
      #pragma unroll
      for (int r=0;r<4;r++)
        store_hl(dh,dl,(quad*4+r)*SSTRIDE + col, (a0[r]+a1[r])*rs128 + bias);
    } else if (job < 12){         // l1: K=256, /16
      int nt = job-4; int col = nt*16 + l16;
      #pragma unroll
      for (int i=0;i<3;i++){
        f32x4 a0 = {0,0,0,0}, a1 = {0,0,0,0};
        #pragma unroll
        for (int ks=0; ks<8; ks++){
          int ka = ks*32 + quad*8;
          int so = abase + ((ka < 128) ? (128 + i*128 + ka) : (1152 + i*128 + ka - 128));
          bf16x8 xh = LDFRAG(h1h+so), xl = LDFRAG(h1l+so);
          int wo = OFF_L2W1 + col*256 + ka;
          bf16x8 wh = LDFRAG(wb+wo), wl = LDFRAG(wb+W_TOT+wo);
          a0 = mfma16(xh,wh,a0); a1 = mfma16(xh,wl,a1); a1 = mfma16(xl,wh,a1);
        }
        int dof = (col < 64) ? (64 + i*64 + col) : (576 + i*64 + col - 64);
        #pragma unroll
        for (int r=0;r<4;r++)
          store_hl(dh,dl,(quad*4+r)*SSTRIDE + dof, (a0[r]+a1[r])*0.0625f);
      }
    } else {                      // l2: K=128
      int nt = job-12; int col = nt*16 + l16;
      #pragma unroll
      for (int i=0;i<5;i++){
        f32x4 a0 = {0,0,0,0}, a1 = {0,0,0,0};
        #pragma unroll
        for (int ks=0; ks<4; ks++){
          int so = abase + 512 + i*128 + ks*32 + quad*8;
          bf16x8 xh = LDFRAG(h1h+so), xl = LDFRAG(h1l+so);
          int wo = OFF_L2W2 + col*128 + ks*32 + quad*8;
          bf16x8 wh = LDFRAG(wb+wo), wl = LDFRAG(wb+W_TOT+wo);
          a0 = mfma16(xh,wh,a0); a1 = mfma16(xh,wl,a1); a1 = mfma16(xl,wh,a1);
        }
        #pragma unroll
        for (int r=0;r<4;r++)
          store_hl(dh,dl,(quad*4+r)*SSTRIDE + 256 + i*64 + col, (a0[r]+a1[r])*rs128);
      }
    }
  }
}

// ============================================================================
// Fused TP path: stage b-fragment in regs via MFMA, contract immediately.
// Wave's fixed mt picks the u-block; lane l -> sample n=l&15,
// u = mt*16 + quad*4 + r. PACKED contraction (f32x2, r-pairs {0,1},{2,3}).
// ============================================================================
template<int D1,int D2,int D3,int O1,int O2,int CGO>
__device__ __forceinline__ void fused_path(
    const unsigned short* __restrict__ wb, int wo,
    const unsigned short* s1h, const unsigned short* s1l,
    const unsigned short* s2h, const unsigned short* s2l,
    const float* __restrict__ cgp,
    f32x2 (&tk)[2][D3], int mt, int lane)
{
  int l16 = lane & 15, quad = lane >> 4;
  f32x2 x1v[D1][2];
  #pragma unroll
  for (int i=0;i<D1;i++){
    int o = l16*SSTRIDE + O1 + i*64 + mt*16 + quad*4;
    u16x4 xh4 = *(const u16x4*)(s1h + o);
    u16x4 xl4 = *(const u16x4*)(s1l + o);
    #pragma unroll
    for (int h=0;h<2;h++){
      f32x2 v;
      v[0] = b2f(xh4[2*h  ]) + b2f(xl4[2*h  ]);
      v[1] = b2f(xh4[2*h+1]) + b2f(xl4[2*h+1]);
      x1v[i][h] = v;
    }
  }
  #pragma unroll
  for (int j=0;j<D2;j++){
    f32x4 a0 = {0,0,0,0}, a1 = {0,0,0,0};
    #pragma unroll
    for (int ks=0; ks<2; ks++){
      int wofs = wo + (mt*16 + l16)*64 + ks*32 + quad*8;
      bf16x8 wh = LDFRAG(wb + wofs);
      bf16x8 wl = LDFRAG(wb + W_TOT + wofs);
      int sofs = l16*SSTRIDE + O2 + j*64 + ks*32 + quad*8;
      bf16x8 xh = LDFRAG(s2h + sofs);
      bf16x8 xl = LDFRAG(s2l + sofs);
      a0 = mfma16(wh,xh,a0); a1 = mfma16(wh,xl,a1); a1 = mfma16(wl,xh,a1);
    }
    f32x2 bu0, bu1;
    bu0[0] = a0[0]+a1[0]; bu0[1] = a0[1]+a1[1];
    bu1[0] = a0[2]+a1[2]; bu1[1] = a0[3]+a1[3];
    #pragma unroll
    for (int i=0;i<D1;i++){
      f32x2 pr0 = x1v[i][0]*bu0;
      f32x2 pr1 = x1v[i][1]*bu1;
      #pragma unroll
      for (int k=0;k<D3;k++){
        float c = cgp[CGO + (i*D2 + j)*D3 + k];
        f32x2 cc = {c, c};
        tk[0][k] += pr0*cc;
        tk[1][k] += pr1*cc;
      }
    }
  }
}

// FC variant: output summed over u; r-pairs folded into tk[k] (f32x2).
template<int D1,int D2,int D3,int O1,int O2,int CGO>
__device__ __forceinline__ void fused_path_fc(
    const unsigned short* __restrict__ wb, int wo,
    const unsigned short* s1h, const unsigned short* s1l,
    const unsigned short* s2h, const unsigned short* s2l,
    const float* __restrict__ cgp,
    f32x2 (&tk)[D3], int mt, int lane)
{
  int l16 = lane & 15, quad = lane >> 4;
  f32x2 x1v[D1][2];
  #pragma unroll
  for (int i=0;i<D1;i++){
    int o = l16*SSTRIDE + O1 + i*64 + mt*16 + quad*4;
    u16x4 xh4 = *(const u16x4*)(s1h + o);
    u16x4 xl4 = *(const u16x4*)(s1l + o);
    #pragma unroll
    for (int h=0;h<2;h++){
      f32x2 v;
      v[0] = b2f(xh4[2*h  ]) + b2f(xl4[2*h  ]);
      v[1] = b2f(xh4[2*h+1]) + b2f(xl4[2*h+1]);
      x1v[i][h] = v;
    }
  }
  #pragma unroll
  for (int j=0;j<D2;j++){
    f32x4 a0 = {0,0,0,0}, a1 = {0,0,0,0};
    #pragma unroll
    for (int ks=0; ks<2; ks++){
      int wofs = wo + (mt*16 + l16)*64 + ks*32 + quad*8;
      bf16x8 wh = LDFRAG(wb + wofs);
      bf16x8 wl = LDFRAG(wb + W_TOT + wofs);
      int sofs = l16*SSTRIDE + O2 + j*64 + ks*32 + quad*8;
      bf16x8 xh = LDFRAG(s2h + sofs);
      bf16x8 xl = LDFRAG(s2l + sofs);
      a0 = mfma16(wh,xh,a0); a1 = mfma16(wh,xl,a1); a1 = mfma16(wl,xh,a1);
    }
    f32x2 bu0, bu1;
    bu0[0] = a0[0]+a1[0]; bu0[1] = a0[1]+a1[1];
    bu1[0] = a0[2]+a1[2]; bu1[1] = a0[3]+a1[3];
    #pragma unroll
    for (int i=0;i<D1;i++){
      f32x2 pr = x1v[i][0]*bu0;
      pr += x1v[i][1]*bu1;
      #pragma unroll
      for (int k=0;k<D3;k++){
        float c = cgp[CGO + (i*D2 + j)*D3 + k];
        f32x2 cc = {c, c};
        tk[k] += pr*cc;
      }
    }
  }
}

// pack 4 consecutive u-values into one b64 store per plane
__device__ inline void store4_hl(unsigned short* ph, unsigned short* pl, int idx,
                                 float v0, float v1, float v2, float v3){
  u16x4 vh, vl;
  float v[4] = {v0,v1,v2,v3};
  #pragma unroll
  for (int r=0;r<4;r++){
    unsigned short h = f2b(v[r]);
    vh[r] = h;
    vl[r] = f2b(v[r] - b2f(h));
  }
  *(u16x4*)(ph + idx) = vh;
  *(u16x4*)(pl + idx) = vl;
}

// uvu TP, one barrier-free phase. 12 waves = 3 output-groups x 4 mt
// (disjoint LDS ranges, no merging): w0-3 l2, w4-7 l1, w8-11 l1b+l0.
// KFENCE every ~2 paths keeps live regs under the 85-reg cap.
__device__ void fused_tp_uvu(const unsigned short* __restrict__ wb, int two,
    const unsigned short* ah, const unsigned short* al,
    const unsigned short* bh, const unsigned short* bl,
    unsigned short* dh, unsigned short* dl,
    const float* __restrict__ cgp, int wave, int lane)
{
  const float f192 = 0.07216878364870323f;  // 1/sqrt(192)
  const float f256 = 0.0625f;               // 1/sqrt(256)
  int mt = wave & 3, grp = wave >> 2;
  int l16 = lane & 15, quad = lane >> 4;
  int u0 = mt*16 + quad*4;
  if (grp == 0){
    // out l2 @256 (fan 256): paths 2,8,9,13  (~480 VALU)
    f32x2 tk2[2][5] = {};
    fused_path<1,5,5,  0,256, 19>(wb,two+ 2*4096, ah,al,bh,bl,cgp,tk2,mt,lane);
    fused_path<5,1,5,256,  0, 44>(wb,two+ 8*4096, ah,al,bh,bl,cgp,tk2,mt,lane);
    KFENCE();
    fused_path<5,3,5,256, 64,150>(wb,two+ 9*4096, ah,al,bh,bl,cgp,tk2,mt,lane);
    fused_path<5,3,5,256,576,150>(wb,two+13*4096, ah,al,bh,bl,cgp,tk2,mt,lane);
    #pragma unroll
    for (int k=0;k<5;k++)
      store4_hl(dh,dl, l16*SSTRIDE + 256 + k*64 + u0,
                tk2[0][k][0]*f256, tk2[0][k][1]*f256, tk2[1][k][0]*f256, tk2[1][k][1]*f256);
  } else if (grp == 1){
    // out l1 @64 (fan 256): paths 1,4,6,11  (~320 VALU)
    f32x2 tkA[2][3] = {};
    fused_path<1,3,3,  0, 64,  1>(wb,two+ 1*4096, ah,al,bh,bl,cgp,tkA,mt,lane);
    fused_path<3,1,3, 64,  0, 10>(wb,two+ 4*4096, ah,al,bh,bl,cgp,tkA,mt,lane);
    KFENCE();
    fused_path<3,3,3, 64, 64, 78>(wb,two+ 6*4096, ah,al,bh,bl,cgp,tkA,mt,lane);
    fused_path<5,5,3,256,256,325>(wb,two+11*4096, ah,al,bh,bl,cgp,tkA,mt,lane);
    #pragma unroll
    for (int k=0;k<3;k++)
      store4_hl(dh,dl, l16*SSTRIDE +  64 + k*64 + u0,
                tkA[0][k][0]*f256, tkA[0][k][1]*f256, tkA[1][k][0]*f256, tkA[1][k][1]*f256);
  } else {
    // out l1b @576 (fan 192): paths 3,7,12, then l0 @0 (fan 192): 0,5,10 (~436)
    {
      f32x2 tkB[2][3] = {};
      fused_path<1,3,3,  0,576,  1>(wb,two+ 3*4096, ah,al,bh,bl,cgp,tkB,mt,lane);
      fused_path<3,3,3, 64, 64, 78>(wb,two+ 7*4096, ah,al,bh,bl,cgp,tkB,mt,lane);
      KFENCE();
      fused_path<5,5,3,256,256,325>(wb,two+12*4096, ah,al,bh,bl,cgp,tkB,mt,lane);
      #pragma unroll
      for (int k=0;k<3;k++)
        store4_hl(dh,dl, l16*SSTRIDE + 576 + k*64 + u0,
                  tkB[0][k][0]*f192, tkB[0][k][1]*f192, tkB[1][k][0]*f192, tkB[1][k][1]*f192);
      KFENCE();
    }
    {
      f32x2 tk0[2][1] = {};
      fused_path<1,1,1,  0,  0,  0>(wb,two+ 0*4096, ah,al,bh,bl,cgp,tk0,mt,lane);
      fused_path<3,3,1, 64, 64, 69>(wb,two+ 5*4096, ah,al,bh,bl,cgp,tk0,mt,lane);
      KFENCE();
      fused_path<5,5,1,256,256,300>(wb,two+10*4096, ah,al,bh,bl,cgp,tk0,mt,lane);
      store4_hl(dh,dl, l16*SSTRIDE + u0,
                tk0[0][0][0]*f192, tk0[0][0][1]*f192, tk0[1][0][0]*f192, tk0[1][0][1]*f192);
    }
  }
}

// FC TP: 3 path-groups x 4 mt (atomicAdd makes any partition valid):
// g0 {p12,p8,p3}=~580, g1 {p11,p13,p7,p9,p0,p1}=~616,
// g2 {p6,p10,p14,p15,p16,p2,p4,p5}=~624. Zero-contribution atomics harmless.
__device__ void fused_tp_fc(const unsigned short* __restrict__ wb,
    const unsigned short* ah, const unsigned short* al,
    const unsigned short* bh, const unsigned short* bl,
    float* s_out, const float* __restrict__ cgp, int wave, int lane)
{
  int mt = wave & 3, grp = wave >> 2;
  int l16 = lane & 15;
  f32x2 t0[1] = {};
  f32x2 t2[5] = {};
  if (grp == 0){
    fused_path_fc<5,5,5,256,256,400>(wb,OFF_TP4W+12*4096, ah,al,bh,bl,cgp,t2,mt,lane);
    KFENCE();
    fused_path_fc<3,5,5, 64,256,225>(wb,OFF_TP4W+ 8*4096, ah,al,bh,bl,cgp,t2,mt,lane);
    KFENCE();
    fused_path_fc<5,5,1,256,256,300>(wb,OFF_TP4W+ 3*4096, ah,al,bh,bl,cgp,t0,mt,lane);
  } else if (grp == 1){
    fused_path_fc<5,3,5,256, 64,150>(wb,OFF_TP4W+11*4096, ah,al,bh,bl,cgp,t2,mt,lane);
    fused_path_fc<5,3,5,256,576,150>(wb,OFF_TP4W+13*4096, ah,al,bh,bl,cgp,t2,mt,lane);
    KFENCE();
    fused_path_fc<3,3,5, 64, 64,105>(wb,OFF_TP4W+ 7*4096, ah,al,bh,bl,cgp,t2,mt,lane);
    fused_path_fc<3,3,5, 64,576,105>(wb,OFF_TP4W+ 9*4096, ah,al,bh,bl,cgp,t2,mt,lane);
    KFENCE();
    fused_path_fc<1,1,1,  0,  0,  0>(wb,OFF_TP4W+ 0*4096, ah,al,bh,bl,cgp,t0,mt,lane);
    fused_path_fc<3,3,1, 64, 64, 69>(wb,OFF_TP4W+ 1*4096, ah,al,bh,bl,cgp,t0,mt,lane);
  } else {
    fused_path_fc<1,5,5,  0,256, 19>(wb,OFF_TP4W+ 6*4096, ah,al,bh,bl,cgp,t2,mt,lane);
    fused_path_fc<5,1,5,256,  0, 44>(wb,OFF_TP4W+10*4096, ah,al,bh,bl,cgp,t2,mt,lane);
    KFENCE();
    fused_path_fc<3,3,5,576, 64,105>(wb,OFF_TP4W+14*4096, ah,al,bh,bl,cgp,t2,mt,lane);
    fused_path_fc<3,5,5,576,256,225>(wb,OFF_TP4W+15*4096, ah,al,bh,bl,cgp,t2,mt,lane);
    KFENCE();
    fused_path_fc<3,3,5,576,576,105>(wb,OFF_TP4W+16*4096, ah,al,bh,bl,cgp,t2,mt,lane);
    fused_path_fc<3,3,1, 64,576, 69>(wb,OFF_TP4W+ 2*4096, ah,al,bh,bl,cgp,t0,mt,lane);
    KFENCE();
    fused_path_fc<3,3,1,576, 64, 69>(wb,OFF_TP4W+ 4*4096, ah,al,bh,bl,cgp,t0,mt,lane);
    fused_path_fc<3,3,1,576,576, 69>(wb,OFF_TP4W+ 5*4096, ah,al,bh,bl,cgp,t0,mt,lane);
  }
  float v0 = t0[0][0] + t0[0][1];
  v0 += __shfl_xor(v0, 16, 64);
  v0 += __shfl_xor(v0, 32, 64);
  if (lane < 16) atomicAdd(&s_out[l16*6 + 0], v0);
  #pragma unroll
  for (int k=0;k<5;k++){
    float v = t2[k][0] + t2[k][1];
    v += __shfl_xor(v, 16, 64);
    v += __shfl_xor(v, 32, 64);
    if (lane < 16) atomicAdd(&s_out[l16*6 + 1 + k], v);
  }
}

// ============================================================================
// 15 barriers. NT=768 -> 12 waves -> 3 waves/SIMD: VGPR cap = 512/3/2 = 85
// (packed body measured 88 at the 128 cap -- expected to squeeze to 85
// spill-free). 1.5x latency hiding on the ~67% dependency stall.
// ============================================================================
__global__ __launch_bounds__(NT) void deeprst_main(
    const float* __restrict__ x,
    const float* __restrict__ l1W0, const float* __restrict__ l1W1,
    const float* __restrict__ l1W2, const float* __restrict__ l1b0,
    const float* __restrict__ l2b0, const float* __restrict__ Lb0,
    const unsigned short* __restrict__ wb, const float* __restrict__ cgp,
    float* __restrict__ out)
{
  __shared__ unsigned short sth[3*BUF];   // 74496 B hi plane
  __shared__ unsigned short stl[3*BUF];   // 74496 B lo plane

  const int tid  = threadIdx.x;
  const int lane = tid & 63;
  const int wave = tid >> 6;
  const int n0   = blockIdx.x * TS;
  const float rs8 = 0.3535533905932738f;

  // ---- lin1 (scalar fp32 -> hi/lo), h1 in buffers 0+1 of both planes ----
  for (int idx=tid; idx<TS*128; idx+=NT){
    int n=idx>>7, o=idx&127;
    const float* xp = x + (n0+n)*80;
    float acc=0.f;
    #pragma unroll
    for (int v=0;v<16;v++) acc += xp[v]*l1W0[v*128+o];
    store_hl(sth,stl, n*H1S + o, acc*0.25f + l1b0[o]);
  }
  for (int idx=tid; idx<TS*768; idx+=NT){
    int o=idx&255, i=(idx>>8)%3, n=idx/768;
    const float* xp = x + (n0+n)*80 + 16;
    float acc=0.f;
    #pragma unroll
    for (int v=0;v<8;v++) acc += xp[v*3+i]*l1W1[v*256+o];
    int du = (o<128)? (128 + i*128 + o) : (1152 + i*128 + o-128);
    store_hl(sth,stl, n*H1S + du, acc*rs8);
  }
  for (int idx=tid; idx<TS*640; idx+=NT){
    int o=idx&127, i=(idx>>7)%5, n=idx/640;
    const float* xp = x + (n0+n)*80 + 40;
    float acc=0.f;
    #pragma unroll
    for (int v=0;v<8;v++) acc += xp[v*5+i]*l1W2[v*128+o];
    store_hl(sth,stl, n*H1S + 512 + i*128 + o, acc*rs8);
  }
  __syncthreads();

  // ---- lin2 (MFMA hi/lo): h1 -> buffer 2 ----
  lin2_mfma(wb, l2b0, sth, stl, sth+2*BUF, stl+2*BUF, wave, lane);
  __syncthreads();

  // ---- 3 rounds: split -> fused tp_uvu -> linear (3 barriers/round) ----
  int ih = 2, i0 = 0, i1 = 1;
  for (int r=0;r<3;r++){
    unsigned short *hh=sth+ih*BUF, *hl=stl+ih*BUF;
    unsigned short *ah=sth+i0*BUF, *al=stl+i0*BUF;
    unsigned short *bh=sth+i1*BUF, *bl=stl+i1*BUF;
    linL_mfma(wb, OFF_LW0+(3*r  )*4096, OFF_LW1+(3*r  )*16384, OFF_LW2+(3*r  )*4096,
              Lb0+(3*r  )*64, hh, hl, ah, al, wave, lane);
    linL_mfma(wb, OFF_LW0+(3*r+1)*4096, OFF_LW1+(3*r+1)*16384, OFF_LW2+(3*r+1)*4096,
              Lb0+(3*r+1)*64, hh, hl, bh, bl, wave, lane);
    __syncthreads();   // lin writes -> TP reads
    fused_tp_uvu(wb, OFF_TPW + r*14*4096, ah, al, bh, bl, hh, hl, cgp, wave, lane);
    __syncthreads();   // TP writes h -> linC reads h
    linL_mfma(wb, OFF_LW0+(3*r+2)*4096, OFF_LW1+(3*r+2)*16384, OFF_LW2+(3*r+2)*4096,
              Lb0+(3*r+2)*64, hh, hl, ah, al, wave, lane);
    __syncthreads();   // linC writes a -> next round reads
    int nh=i0; i0=i1; i1=ih; ih=nh;
  }

  // ---- split4 + fully-connected TP ----
  unsigned short *hh=sth+ih*BUF, *hl=stl+ih*BUF;
  unsigned short *ah=sth+i0*BUF, *al=stl+i0*BUF;
  unsigned short *bh=sth+i1*BUF, *bl=stl+i1*BUF;
  linL_mfma(wb, OFF_LW0+ 9*4096, OFF_LW1+ 9*16384, OFF_LW2+ 9*4096, Lb0+ 9*64, hh, hl, ah, al, wave, lane);
  linL_mfma(wb, OFF_LW0+10*4096, OFF_LW1+10*16384, OFF_LW2+10*4096, Lb0+10*64, hh, hl, bh, bl, wave, lane);
  __syncthreads();   // lin reads of h done -> safe to reuse h as s_out

  float* s_out = (float*)hh;   // h buffer dead after split4 linears
  if (tid < TS*6) s_out[tid] = 0.f;
  __syncthreads();   // zero visible before atomics

  fused_tp_fc(wb, ah, al, bh, bl, s_out, cgp, wave, lane);
  __syncthreads();   // atomics done -> read s_out

  if (tid < TS*6){
    int n=tid/6, k=tid%6;
    float sc = (k==0)? (1.0f/sqrtf(24576.0f)) : (1.0f/sqrtf(45056.0f));
    out[(n0+n)*6+k] = s_out[tid]*sc;
  }
}

// ============================================================================
extern "C" void kernel_launch(void* const* d_in, const int* in_sizes, int n_in,
                              void* d_out, int out_size, void* d_ws, size_t ws_size,
                              hipStream_t stream)
{
  (void)n_in; (void)out_size; (void)ws_size;
  const float* x    = (const float*)d_in[0];
  const float* l1W0 = (const float*)d_in[1];
  const float* l1W1 = (const float*)d_in[2];
  const float* l1W2 = (const float*)d_in[3];
  const float* l1b0 = (const float*)d_in[4];
  const float* l2W0 = (const float*)d_in[5];
  const float* l2W1 = (const float*)d_in[6];
  const float* l2W2 = (const float*)d_in[7];
  const float* l2b0 = (const float*)d_in[8];
  const float* LW0  = (const float*)d_in[9];
  const float* LW1  = (const float*)d_in[10];
  const float* LW2  = (const float*)d_in[11];
  const float* Lb0  = (const float*)d_in[12];
  const float* tpw  = (const float*)d_in[13];
  const float* tp4w = (const float*)d_in[14];

  float* cg = (float*)d_ws;                                    // 525 f32 @ ws+0
  unsigned short* wb = (unsigned short*)((char*)d_ws + 4096);  // hi + lo planes
  const int n = in_sizes[0]/80;

  cg_init_kernel<<<1, 576, 0, stream>>>(cg);
  prep_kernel<<<(W_TOT+255)/256, 256, 0, stream>>>(l2W0,l2W1,l2W2,LW0,LW1,LW2,tpw,tp4w,wb);
  deeprst_main<<<n/TS, NT, 0, stream>>>(x,l1W0,l1W1,l1W2,l1b0,l2b0,Lb0,wb,cg,(float*)d_out);
}

// Round 13
// 760.056 us; speedup vs baseline: 1.6364x; 1.0728x over previous
//
#include <hip/hip_runtime.h>
#include <math.h>

constexpr int TS = 16;     // samples per block
constexpr int NT = 768;    // threads per block (12 waves = 3 waves/SIMD)
constexpr int NW = NT/64;  // 12 waves
constexpr int SSTRIDE = 776;   // bf16 per sample, HID0 state (768 + 8 pad)
constexpr int H1S = 1544;      // bf16 per sample, HID1 transient (1536 + 8 pad)
constexpr int BUF = TS*SSTRIDE;
// HID0 per-sample layout: l0 @0 (64: [u]), l1 @64 (3x64: [i][u]),
// l2 @256 (5x64), l1b @576 (3x64)
// HID1 layout: l0 @0 (128), l1 @128 (3x128), l2 @512 (5x128), l1b @1152 (3x128)
//
// R12 (757us): NT=768, 3 waves/SIMD, VGPR=84, no spill, occ 36%. Counter
// audit: SQ_LDS_BANK_CONFLICT 3.36e7 ~ 131K cyc/CU ~ 29% of block time.
// Culprit: linear-layer scalar u16 stores at (quad*4+r)*SSTRIDE+col -- the
// sample-row stride (388 dw = 4 mod 32) collapses quad to banks {0,16}
// (8 banks total, 4-way + sub-dword serialization). TP stores are clean
// because fused_path uses SWAPPED operands mfma(w,x): lane owns 4
// CONTIGUOUS features of one sample -> packed b64 stores.
// R13: swap the linears to mfma(w,x) too. Operand address streams are
// bit-identical (both fragment layouts use lane=row/col, quad=k-chunk;
// both orders already verified in this codebase). Only the C-layout flips:
// store4_hl per (job,i) instead of 8 scalar u16 ops. Same MFMA count, same
// products. Bias becomes a float4 load.

typedef __attribute__((ext_vector_type(8))) short bf16x8;
typedef __attribute__((ext_vector_type(4))) float f32x4;
typedef __attribute__((ext_vector_type(2))) float f32x2;
typedef __attribute__((ext_vector_type(4))) unsigned short u16x4;

#define KFENCE() asm volatile("" ::: "memory")

__device__ inline f32x4 mfma16(bf16x8 a, bf16x8 b, f32x4 c){
  return __builtin_amdgcn_mfma_f32_16x16x32_bf16(a, b, c, 0, 0, 0);
}
__device__ inline unsigned short f2b(float f){
  union { float f; unsigned u; } v; v.f = f;
  return (unsigned short)((v.u + 0x7fffu + ((v.u >> 16) & 1u)) >> 16);
}
__device__ inline float b2f(unsigned short h){
  union { unsigned u; float f; } v; v.u = ((unsigned)h) << 16; return v.f;
}
__device__ inline void store_hl(unsigned short* ph, unsigned short* pl, int idx, float v){
  unsigned short h = f2b(v);
  ph[idx] = h;
  pl[idx] = f2b(v - b2f(h));
}
#define LDFRAG(p) (*(const bf16x8*)(p))

// ws bf16 weight offsets (elements, base = ws+4096B). lo plane at +W_TOT.
constexpr int OFF_L2W0 = 0;        // 64x128 (WT[o][k])
constexpr int OFF_L2W1 = 8192;     // 128x256
constexpr int OFF_L2W2 = 40960;    // 64x128
constexpr int OFF_LW0  = 49152;    // 11 x 64x64
constexpr int OFF_LW1  = 94208;    // 11 x 128x128
constexpr int OFF_LW2  = 274432;   // 11 x 64x64
constexpr int OFF_TPW  = 319488;   // 3x14 x 64x64 ([u][v])
constexpr int OFF_TP4W = 491520;   // 17 x 64x64
constexpr int W_TOT    = 561152;

// ============================================================================
// Clebsch-Gordan init (element-parallel fp64; verified R2/R3)
// offsets: 0:(0,0,0)@0 1:(0,1,1)@1 2:(1,0,1)@10 3:(0,2,2)@19 4:(2,0,2)@44
// 5:(1,1,0)@69 6:(1,1,1)@78 7:(1,1,2)@105 8:(2,1,2)@150 9:(1,2,2)@225
// 10:(2,2,0)@300 11:(2,2,1)@325 12:(2,2,2)@400 ; total 525 floats
// ============================================================================
__device__ inline double dfact(int n){ double r=1.0; for(int i=2;i<=n;i++) r*=(double)i; return r; }
struct dcplx { double x, y; };
__device__ inline dcplx cmul(dcplx a, dcplx b){ return {a.x*b.x-a.y*b.y, a.x*b.y+a.y*b.x}; }

__device__ dcplx Uent(int l, int r, int c){
  double re=0.0, im=0.0;
  double s = 1.0/sqrt(2.0);
  if (r==l && c==l) re = 1.0;
  else if (c>l){ int m=c-l; double sgn=(m&1)?-1.0:1.0;
    if (r==l-m) re = s; else if (r==l+m) re = sgn*s;
  } else if (c<l){ int m=l-c; double sgn=(m&1)?-1.0:1.0;
    if (r==l-m) im = s; else if (r==l+m) im = -sgn*s;
  }
  int lm=l&3; double pr,pi;
  if(lm==0){pr=1;pi=0;} else if(lm==1){pr=0;pi=-1;} else if(lm==2){pr=-1;pi=0;} else {pr=0;pi=1;}
  return { re*pr-im*pi, re*pi+im*pr };
}

__device__ double cg_complex_entry(int l1,int l2,int l3,int m1,int m2){
  int m3=m1+m2;
  if (m3<-l3 || m3>l3) return 0.0;
  double pref = sqrt((double)(2*l3+1)*dfact(l3+l1-l2)*dfact(l3-l1+l2)*dfact(l1+l2-l3)/dfact(l1+l2+l3+1));
  pref *= sqrt(dfact(l3+m3)*dfact(l3-m3)*dfact(l1-m1)*dfact(l1+m1)*dfact(l2-m2)*dfact(l2+m2));
  double s=0.0;
  for(int k=0;k<=l1+l2-l3;k++){
    int a2=l1-m1-k, a3=l2+m2-k, a4=l3-l2+m1+k, a5=l3-l1-m2+k;
    if(a2<0||a3<0||a4<0||a5<0) continue;
    double t=1.0/(dfact(k)*dfact(l1+l2-l3-k)*dfact(a2)*dfact(a3)*dfact(a4)*dfact(a5));
    s += (k&1)? -t : t;
  }
  return pref*s;
}

__global__ void cg_init_kernel(float* cg){
  __shared__ double sKr[525], sKi[525];
  __shared__ double sScale[13];
  __shared__ int    sSel[13];
  const int L1[13]={0,0,1,0,2,1,1,1,2,1,2,2,2};
  const int L2[13]={0,1,0,2,0,1,1,1,1,2,2,2,2};
  const int L3[13]={0,1,1,2,2,0,1,2,2,2,0,1,2};
  const int OFF[14]={0,1,10,19,44,69,78,105,150,225,300,325,400,525};
  const int tid = threadIdx.x;
  int combo=-1, l1=0,l2=0,l3=0;
  if (tid < 525){
    combo=12;
    for(int i=0;i<12;i++) if (tid < OFF[i+1]) { combo=i; break; }
    l1=L1[combo]; l2=L2[combo]; l3=L3[combo];
    int d2=2*l2+1, d3=2*l3+1;
    int e = tid - OFF[combo];
    int a = e/(d2*d3), b=(e/d3)%d2, cc=e%d3;
    double kr=0.0, ki=0.0;
    for(int m=0;m<2*l1+1;m++) for(int n=0;n<d2;n++){
      int m3 = (m-l1)+(n-l2);
      if (m3<-l3||m3>l3) continue;
      double cv = cg_complex_entry(l1,l2,l3,m-l1,n-l2);
      if (cv==0.0) continue;
      dcplx u1=Uent(l1,m,a), u2=Uent(l2,n,b), u3=Uent(l3,m3+l3,cc);
      u3.y = -u3.y;
      dcplx t = cmul(cmul(u1,u2),u3);
      kr += t.x*cv; ki += t.y*cv;
    }
    sKr[tid]=kr; sKi[tid]=ki;
  }
  __syncthreads();
  if (tid < 13){
    int sz = OFF[tid+1]-OFF[tid];
    double nr=0,ni=0;
    for(int i=0;i<sz;i++){ double r=sKr[OFF[tid]+i], im=sKi[OFF[tid]+i]; nr+=r*r; ni+=im*im; }
    int sel = (nr>=ni)? 0 : 1;
    sSel[tid]=sel;
    sScale[tid] = sqrt((double)(2*L3[tid]+1))/sqrt(sel? ni : nr);
  }
  __syncthreads();
  if (tid < 525){
    double v = sSel[combo]? sKi[tid] : sKr[tid];
    cg[tid] = (float)(v*sScale[combo]);
  }
}

// ============================================================================
// Weight prep: fp32 -> bf16 hi/lo planes. Linear weights transposed WT[o][k];
// TP weights [u][v].
// ============================================================================
__global__ void prep_kernel(const float* __restrict__ l2W0, const float* __restrict__ l2W1,
                            const float* __restrict__ l2W2, const float* __restrict__ LW0,
                            const float* __restrict__ LW1, const float* __restrict__ LW2,
                            const float* __restrict__ tpw, const float* __restrict__ tp4w,
                            unsigned short* __restrict__ wb){
  int i = blockIdx.x*256 + threadIdx.x;
  if (i >= W_TOT) return;
  float v;
  if (i < 8192){ int o=i>>7, k=i&127; v = l2W0[k*64+o]; }
  else if (i < 40960){ int j=i-8192; int o=j>>8, k=j&255; v = l2W1[k*128+o]; }
  else if (i < 49152){ int j=i-40960; int o=j>>7, k=j&127; v = l2W2[k*64+o]; }
  else if (i < 94208){ int j=i-49152; int li=j>>12, r=j&4095, o=r>>6, k=r&63; v = LW0[li*4096+k*64+o]; }
  else if (i < 274432){ int j=i-94208; int li=j>>14, r=j&16383, o=r>>7, k=r&127; v = LW1[li*16384+k*128+o]; }
  else if (i < 319488){ int j=i-274432; int li=j>>12, r=j&4095, o=r>>6, k=r&63; v = LW2[li*4096+k*64+o]; }
  else if (i < 491520){ v = tpw[i-319488]; }
  else { v = tp4w[i-491520]; }
  unsigned short h = f2b(v);
  wb[i] = h;
  wb[W_TOT + i] = f2b(v - b2f(h));
}

// pack 4 consecutive values into one b64 store per plane
__device__ inline void store4_hl(unsigned short* ph, unsigned short* pl, int idx,
                                 float v0, float v1, float v2, float v3){
  u16x4 vh, vl;
  float v[4] = {v0,v1,v2,v3};
  #pragma unroll
  for (int r=0;r<4;r++){
    unsigned short h = f2b(v[r]);
    vh[r] = h;
    vl[r] = f2b(v[r] - b2f(h));
  }
  *(u16x4*)(ph + idx) = vh;
  *(u16x4*)(pl + idx) = vl;
}

// ============================================================================
// MFMA linear HID0->HID0 (hi/lo), SWAPPED operands mfma(w,x): C row=feature
// (quad*4+r), col=sample (l16) -> each lane stores 4 CONTIGUOUS features of
// one sample via store4_hl (b64, bank-balanced). Operand addressing identical
// to the old form. Jobs: 0..3 l0 | 4..11 l1 | 12..15 l2.
// NW=12: waves 0-3 do {l0, l2}; waves 4-11 one l1.
// ============================================================================
__device__ void linL_mfma(const unsigned short* __restrict__ wb, int o0, int o1, int o2,
                          const float* __restrict__ b0,
                          const unsigned short* sh, const unsigned short* sl,
                          unsigned short* dh, unsigned short* dl, int wave, int lane)
{
  const float rs128 = 0.08838834764831845f;
  int l16 = lane & 15, quad = lane >> 4;
  int abase = l16 * SSTRIDE;        // sample = l16 (B operand / stores)
  for (int job = wave; job < 16; job += NW){
    if (job < 4){                 // l0: K=64, /8 + bias
      f32x4 a0 = {0,0,0,0}, a1 = {0,0,0,0};
      #pragma unroll
      for (int ks=0; ks<2; ks++){
        int so = abase + ks*32 + quad*8;
        bf16x8 xh = LDFRAG(sh+so), xl = LDFRAG(sl+so);
        int wo = o0 + (job*16 + l16)*64 + ks*32 + quad*8;
        bf16x8 wh = LDFRAG(wb+wo), wl = LDFRAG(wb+W_TOT+wo);
        a0 = mfma16(wh,xh,a0); a1 = mfma16(wl,xh,a1); a1 = mfma16(wh,xl,a1);
      }
      int fb = job*16 + quad*4;
      float4 b4 = *(const float4*)(b0 + fb);
      store4_hl(dh,dl, abase + fb,
                (a0[0]+a1[0])*0.125f + b4.x, (a0[1]+a1[1])*0.125f + b4.y,
                (a0[2]+a1[2])*0.125f + b4.z, (a0[3]+a1[3])*0.125f + b4.w);
    } else if (job < 12){         // l1: K=128 (l1|l1b), /sqrt(128)
      int nt = job-4;
      #pragma unroll
      for (int i=0;i<3;i++){
        f32x4 a0 = {0,0,0,0}, a1 = {0,0,0,0};
        #pragma unroll
        for (int ks=0; ks<4; ks++){
          int ka = ks*32 + quad*8;
          int so = abase + ((ka < 64) ? (64 + i*64 + ka) : (576 + i*64 + ka - 64));
          bf16x8 xh = LDFRAG(sh+so), xl = LDFRAG(sl+so);
          int wo = o1 + (nt*16 + l16)*128 + ka;
          bf16x8 wh = LDFRAG(wb+wo), wl = LDFRAG(wb+W_TOT+wo);
          a0 = mfma16(wh,xh,a0); a1 = mfma16(wl,xh,a1); a1 = mfma16(wh,xl,a1);
        }
        int colb = nt*16 + quad*4;
        int dof = (nt < 4) ? (64 + i*64 + colb) : (576 + i*64 + colb - 64);
        store4_hl(dh,dl, abase + dof,
                  (a0[0]+a1[0])*rs128, (a0[1]+a1[1])*rs128,
                  (a0[2]+a1[2])*rs128, (a0[3]+a1[3])*rs128);
      }
    } else {                      // l2: K=64, /8
      int nt = job-12;
      #pragma unroll
      for (int i=0;i<5;i++){
        f32x4 a0 = {0,0,0,0}, a1 = {0,0,0,0};
        #pragma unroll
        for (int ks=0; ks<2; ks++){
          int so = abase + 256 + i*64 + ks*32 + quad*8;
          bf16x8 xh = LDFRAG(sh+so), xl = LDFRAG(sl+so);
          int wo = o2 + (nt*16 + l16)*64 + ks*32 + quad*8;
          bf16x8 wh = LDFRAG(wb+wo), wl = LDFRAG(wb+W_TOT+wo);
          a0 = mfma16(wh,xh,a0); a1 = mfma16(wl,xh,a1); a1 = mfma16(wh,xl,a1);
        }
        store4_hl(dh,dl, abase + 256 + i*64 + nt*16 + quad*4,
                  (a0[0]+a1[0])*0.125f, (a0[1]+a1[1])*0.125f,
                  (a0[2]+a1[2])*0.125f, (a0[3]+a1[3])*0.125f);
      }
    }
  }
}

// lin2: HID1 -> HID0 (K=128/256/128), hi/lo, swapped operands + b64 stores.
__device__ void lin2_mfma(const unsigned short* __restrict__ wb,
                          const float* __restrict__ b0,
                          const unsigned short* h1h, const unsigned short* h1l,
                          unsigned short* dh, unsigned short* dl, int wave, int lane)
{
  const float rs128 = 0.08838834764831845f;
  int l16 = lane & 15, quad = lane >> 4;
  int abase = l16 * H1S;            // sample = l16 (B operand)
  int obase = l16 * SSTRIDE;        // output rows
  for (int job = wave; job < 16; job += NW){
    if (job < 4){                 // l0: K=128
      f32x4 a0 = {0,0,0,0}, a1 = {0,0,0,0};
      #pragma unroll
      for (int ks=0; ks<4; ks++){
        int so = abase + ks*32 + quad*8;
        bf16x8 xh = LDFRAG(h1h+so), xl = LDFRAG(h1l+so);
        int wo = OFF_L2W0 + (job*16 + l16)*128 + ks*32 + quad*8;
        bf16x8 wh = LDFRAG(wb+wo), wl = LDFRAG(wb+W_TOT+wo);
        a0 = mfma16(wh,xh,a0); a1 = mfma16(wl,xh,a1); a1 = mfma16(wh,xl,a1);
      }
      int fb = job*16 + quad*4;
      float4 b4 = *(const float4*)(b0 + fb);
      store4_hl(dh,dl, obase + fb,
                (a0[0]+a1[0])*rs128 + b4.x, (a0[1]+a1[1])*rs128 + b4.y,
                (a0[2]+a1[2])*rs128 + b4.z, (a0[3]+a1[3])*rs128 + b4.w);
    } else if (job < 12){         // l1: K=256, /16
      int nt = job-4;
      #pragma unroll
      for (int i=0;i<3;i++){
        f32x4 a0 = {0,0,0,0}, a1 = {0,0,0,0};
        #pragma unroll
        for (int ks=0; ks<8; ks++){
          int ka = ks*32 + quad*8;
          int so = abase + ((ka < 128) ? (128 + i*128 + ka) : (1152 + i*128 + ka - 128));
          bf16x8 xh = LDFRAG(h1h+so), xl = LDFRAG(h1l+so);
          int wo = OFF_L2W1 + (nt*16 + l16)*256 + ka;
          bf16x8 wh = LDFRAG(wb+wo), wl = LDFRAG(wb+W_TOT+wo);
          a0 = mfma16(wh,xh,a0); a1 = mfma16(wl,xh,a1); a1 = mfma16(wh,xl,a1);
        }
        int colb = nt*16 + quad*4;
        int dof = (nt < 4) ? (64 + i*64 + colb) : (576 + i*64 + colb - 64);
        store4_hl(dh,dl, obase + dof,
                  (a0[0]+a1[0])*0.0625f, (a0[1]+a1[1])*0.0625f,
                  (a0[2]+a1[2])*0.0625f, (a0[3]+a1[3])*0.0625f);
      }
    } else {                      // l2: K=128
      int nt = job-12;
      #pragma unroll
      for (int i=0;i<5;i++){
        f32x4 a0 = {0,0,0,0}, a1 = {0,0,0,0};
        #pragma unroll
        for (int ks=0; ks<4; ks++){
          int so = abase + 512 + i*128 + ks*32 + quad*8;
          bf16x8 xh = LDFRAG(h1h+so), xl = LDFRAG(h1l+so);
          int wo = OFF_L2W2 + (nt*16 + l16)*128 + ks*32 + quad*8;
          bf16x8 wh = LDFRAG(wb+wo), wl = LDFRAG(wb+W_TOT+wo);
          a0 = mfma16(wh,xh,a0); a1 = mfma16(wl,xh,a1); a1 = mfma16(wh,xl,a1);
        }
        store4_hl(dh,dl, obase + 256 + i*64 + nt*16 + quad*4,
                  (a0[0]+a1[0])*rs128, (a0[1]+a1[1])*rs128,
                  (a0[2]+a1[2])*rs128, (a0[3]+a1[3])*rs128);
      }
    }
  }
}

// ============================================================================
// Fused TP path: stage b-fragment in regs via MFMA, contract immediately.
// Wave's fixed mt picks the u-block; lane l -> sample n=l&15,
// u = mt*16 + quad*4 + r. PACKED contraction (f32x2, r-pairs {0,1},{2,3}).
// ============================================================================
template<int D1,int D2,int D3,int O1,int O2,int CGO>
__device__ __forceinline__ void fused_path(
    const unsigned short* __restrict__ wb, int wo,
    const unsigned short* s1h, const unsigned short* s1l,
    const unsigned short* s2h, const unsigned short* s2l,
    const float* __restrict__ cgp,
    f32x2 (&tk)[2][D3], int mt, int lane)
{
  int l16 = lane & 15, quad = lane >> 4;
  f32x2 x1v[D1][2];
  #pragma unroll
  for (int i=0;i<D1;i++){
    int o = l16*SSTRIDE + O1 + i*64 + mt*16 + quad*4;
    u16x4 xh4 = *(const u16x4*)(s1h + o);
    u16x4 xl4 = *(const u16x4*)(s1l + o);
    #pragma unroll
    for (int h=0;h<2;h++){
      f32x2 v;
      v[0] = b2f(xh4[2*h  ]) + b2f(xl4[2*h  ]);
      v[1] = b2f(xh4[2*h+1]) + b2f(xl4[2*h+1]);
      x1v[i][h] = v;
    }
  }
  #pragma unroll
  for (int j=0;j<D2;j++){
    f32x4 a0 = {0,0,0,0}, a1 = {0,0,0,0};
    #pragma unroll
    for (int ks=0; ks<2; ks++){
      int wofs = wo + (mt*16 + l16)*64 + ks*32 + quad*8;
      bf16x8 wh = LDFRAG(wb + wofs);
      bf16x8 wl = LDFRAG(wb + W_TOT + wofs);
      int sofs = l16*SSTRIDE + O2 + j*64 + ks*32 + quad*8;
      bf16x8 xh = LDFRAG(s2h + sofs);
      bf16x8 xl = LDFRAG(s2l + sofs);
      a0 = mfma16(wh,xh,a0); a1 = mfma16(wh,xl,a1); a1 = mfma16(wl,xh,a1);
    }
    f32x2 bu0, bu1;
    bu0[0] = a0[0]+a1[0]; bu0[1] = a0[1]+a1[1];
    bu1[0] = a0[2]+a1[2]; bu1[1] = a0[3]+a1[3];
    #pragma unroll
    for (int i=0;i<D1;i++){
      f32x2 pr0 = x1v[i][0]*bu0;
      f32x2 pr1 = x1v[i][1]*bu1;
      #pragma unroll
      for (int k=0;k<D3;k++){
        float c = cgp[CGO + (i*D2 + j)*D3 + k];
        f32x2 cc = {c, c};
        tk[0][k] += pr0*cc;
        tk[1][k] += pr1*cc;
      }
    }
  }
}

// FC variant: output summed over u; r-pairs folded into tk[k] (f32x2).
template<int D1,int D2,int D3,int O1,int O2,int CGO>
__device__ __forceinline__ void fused_path_fc(
    const unsigned short* __restrict__ wb, int wo,
    const unsigned short* s1h, const unsigned short* s1l,
    const unsigned short* s2h, const unsigned short* s2l,
    const float* __restrict__ cgp,
    f32x2 (&tk)[D3], int mt, int lane)
{
  int l16 = lane & 15, quad = lane >> 4;
  f32x2 x1v[D1][2];
  #pragma unroll
  for (int i=0;i<D1;i++){
    int o = l16*SSTRIDE + O1 + i*64 + mt*16 + quad*4;
    u16x4 xh4 = *(const u16x4*)(s1h + o);
    u16x4 xl4 = *(const u16x4*)(s1l + o);
    #pragma unroll
    for (int h=0;h<2;h++){
      f32x2 v;
      v[0] = b2f(xh4[2*h  ]) + b2f(xl4[2*h  ]);
      v[1] = b2f(xh4[2*h+1]) + b2f(xl4[2*h+1]);
      x1v[i][h] = v;
    }
  }
  #pragma unroll
  for (int j=0;j<D2;j++){
    f32x4 a0 = {0,0,0,0}, a1 = {0,0,0,0};
    #pragma unroll
    for (int ks=0; ks<2; ks++){
      int wofs = wo + (mt*16 + l16)*64 + ks*32 + quad*8;
      bf16x8 wh = LDFRAG(wb + wofs);
      bf16x8 wl = LDFRAG(wb + W_TOT + wofs);
      int sofs = l16*SSTRIDE + O2 + j*64 + ks*32 + quad*8;
      bf16x8 xh = LDFRAG(s2h + sofs);
      bf16x8 xl = LDFRAG(s2l + sofs);
      a0 = mfma16(wh,xh,a0); a1 = mfma16(wh,xl,a1); a1 = mfma16(wl,xh,a1);
    }
    f32x2 bu0, bu1;
    bu0[0] = a0[0]+a1[0]; bu0[1] = a0[1]+a1[1];
    bu1[0] = a0[2]+a1[2]; bu1[1] = a0[3]+a1[3];
    #pragma unroll
    for (int i=0;i<D1;i++){
      f32x2 pr = x1v[i][0]*bu0;
      pr += x1v[i][1]*bu1;
      #pragma unroll
      for (int k=0;k<D3;k++){
        float c = cgp[CGO + (i*D2 + j)*D3 + k];
        f32x2 cc = {c, c};
        tk[k] += pr*cc;
      }
    }
  }
}

// uvu TP, one barrier-free phase. 12 waves = 3 output-groups x 4 mt
// (disjoint LDS ranges, no merging): w0-3 l2, w4-7 l1, w8-11 l1b+l0.
// KFENCE every ~2 paths keeps live regs under the 85-reg cap.
__device__ void fused_tp_uvu(const unsigned short* __restrict__ wb, int two,
    const unsigned short* ah, const unsigned short* al,
    const unsigned short* bh, const unsigned short* bl,
    unsigned short* dh, unsigned short* dl,
    const float* __restrict__ cgp, int wave, int lane)
{
  const float f192 = 0.07216878364870323f;  // 1/sqrt(192)
  const float f256 = 0.0625f;               // 1/sqrt(256)
  int mt = wave & 3, grp = wave >> 2;
  int l16 = lane & 15, quad = lane >> 4;
  int u0 = mt*16 + quad*4;
  if (grp == 0){
    // out l2 @256 (fan 256): paths 2,8,9,13
    f32x2 tk2[2][5] = {};
    fused_path<1,5,5,  0,256, 19>(wb,two+ 2*4096, ah,al,bh,bl,cgp,tk2,mt,lane);
    fused_path<5,1,5,256,  0, 44>(wb,two+ 8*4096, ah,al,bh,bl,cgp,tk2,mt,lane);
    KFENCE();
    fused_path<5,3,5,256, 64,150>(wb,two+ 9*4096, ah,al,bh,bl,cgp,tk2,mt,lane);
    fused_path<5,3,5,256,576,150>(wb,two+13*4096, ah,al,bh,bl,cgp,tk2,mt,lane);
    #pragma unroll
    for (int k=0;k<5;k++)
      store4_hl(dh,dl, l16*SSTRIDE + 256 + k*64 + u0,
                tk2[0][k][0]*f256, tk2[0][k][1]*f256, tk2[1][k][0]*f256, tk2[1][k][1]*f256);
  } else if (grp == 1){
    // out l1 @64 (fan 256): paths 1,4,6,11
    f32x2 tkA[2][3] = {};
    fused_path<1,3,3,  0, 64,  1>(wb,two+ 1*4096, ah,al,bh,bl,cgp,tkA,mt,lane);
    fused_path<3,1,3, 64,  0, 10>(wb,two+ 4*4096, ah,al,bh,bl,cgp,tkA,mt,lane);
    KFENCE();
    fused_path<3,3,3, 64, 64, 78>(wb,two+ 6*4096, ah,al,bh,bl,cgp,tkA,mt,lane);
    fused_path<5,5,3,256,256,325>(wb,two+11*4096, ah,al,bh,bl,cgp,tkA,mt,lane);
    #pragma unroll
    for (int k=0;k<3;k++)
      store4_hl(dh,dl, l16*SSTRIDE +  64 + k*64 + u0,
                tkA[0][k][0]*f256, tkA[0][k][1]*f256, tkA[1][k][0]*f256, tkA[1][k][1]*f256);
  } else {
    // out l1b @576 (fan 192): paths 3,7,12, then l0 @0 (fan 192): 0,5,10
    {
      f32x2 tkB[2][3] = {};
      fused_path<1,3,3,  0,576,  1>(wb,two+ 3*4096, ah,al,bh,bl,cgp,tkB,mt,lane);
      fused_path<3,3,3, 64, 64, 78>(wb,two+ 7*4096, ah,al,bh,bl,cgp,tkB,mt,lane);
      KFENCE();
      fused_path<5,5,3,256,256,325>(wb,two+12*4096, ah,al,bh,bl,cgp,tkB,mt,lane);
      #pragma unroll
      for (int k=0;k<3;k++)
        store4_hl(dh,dl, l16*SSTRIDE + 576 + k*64 + u0,
                  tkB[0][k][0]*f192, tkB[0][k][1]*f192, tkB[1][k][0]*f192, tkB[1][k][1]*f192);
      KFENCE();
    }
    {
      f32x2 tk0[2][1] = {};
      fused_path<1,1,1,  0,  0,  0>(wb,two+ 0*4096, ah,al,bh,bl,cgp,tk0,mt,lane);
      fused_path<3,3,1, 64, 64, 69>(wb,two+ 5*4096, ah,al,bh,bl,cgp,tk0,mt,lane);
      KFENCE();
      fused_path<5,5,1,256,256,300>(wb,two+10*4096, ah,al,bh,bl,cgp,tk0,mt,lane);
      store4_hl(dh,dl, l16*SSTRIDE + u0,
                tk0[0][0][0]*f192, tk0[0][0][1]*f192, tk0[1][0][0]*f192, tk0[1][0][1]*f192);
    }
  }
}

// FC TP: 3 path-groups x 4 mt (atomicAdd makes any partition valid).
__device__ void fused_tp_fc(const unsigned short* __restrict__ wb,
    const unsigned short* ah, const unsigned short* al,
    const unsigned short* bh, const unsigned short* bl,
    float* s_out, const float* __restrict__ cgp, int wave, int lane)
{
  int mt = wave & 3, grp = wave >> 2;
  int l16 = lane & 15;
  f32x2 t0[1] = {};
  f32x2 t2[5] = {};
  if (grp == 0){
    fused_path_fc<5,5,5,256,256,400>(wb,OFF_TP4W+12*4096, ah,al,bh,bl,cgp,t2,mt,lane);
    KFENCE();
    fused_path_fc<3,5,5, 64,256,225>(wb,OFF_TP4W+ 8*4096, ah,al,bh,bl,cgp,t2,mt,lane);
    KFENCE();
    fused_path_fc<5,5,1,256,256,300>(wb,OFF_TP4W+ 3*4096, ah,al,bh,bl,cgp,t0,mt,lane);
  } else if (grp == 1){
    fused_path_fc<5,3,5,256, 64,150>(wb,OFF_TP4W+11*4096, ah,al,bh,bl,cgp,t2,mt,lane);
    fused_path_fc<5,3,5,256,576,150>(wb,OFF_TP4W+13*4096, ah,al,bh,bl,cgp,t2,mt,lane);
    KFENCE();
    fused_path_fc<3,3,5, 64, 64,105>(wb,OFF_TP4W+ 7*4096, ah,al,bh,bl,cgp,t2,mt,lane);
    fused_path_fc<3,3,5, 64,576,105>(wb,OFF_TP4W+ 9*4096, ah,al,bh,bl,cgp,t2,mt,lane);
    KFENCE();
    fused_path_fc<1,1,1,  0,  0,  0>(wb,OFF_TP4W+ 0*4096, ah,al,bh,bl,cgp,t0,mt,lane);
    fused_path_fc<3,3,1, 64, 64, 69>(wb,OFF_TP4W+ 1*4096, ah,al,bh,bl,cgp,t0,mt,lane);
  } else {
    fused_path_fc<1,5,5,  0,256, 19>(wb,OFF_TP4W+ 6*4096, ah,al,bh,bl,cgp,t2,mt,lane);
    fused_path_fc<5,1,5,256,  0, 44>(wb,OFF_TP4W+10*4096, ah,al,bh,bl,cgp,t2,mt,lane);
    KFENCE();
    fused_path_fc<3,3,5,576, 64,105>(wb,OFF_TP4W+14*4096, ah,al,bh,bl,cgp,t2,mt,lane);
    fused_path_fc<3,5,5,576,256,225>(wb,OFF_TP4W+15*4096, ah,al,bh,bl,cgp,t2,mt,lane);
    KFENCE();
    fused_path_fc<3,3,5,576,576,105>(wb,OFF_TP4W+16*4096, ah,al,bh,bl,cgp,t2,mt,lane);
    fused_path_fc<3,3,1, 64,576, 69>(wb,OFF_TP4W+ 2*4096, ah,al,bh,bl,cgp,t0,mt,lane);
    KFENCE();
    fused_path_fc<3,3,1,576, 64, 69>(wb,OFF_TP4W+ 4*4096, ah,al,bh,bl,cgp,t0,mt,lane);
    fused_path_fc<3,3,1,576,576, 69>(wb,OFF_TP4W+ 5*4096, ah,al,bh,bl,cgp,t0,mt,lane);
  }
  float v0 = t0[0][0] + t0[0][1];
  v0 += __shfl_xor(v0, 16, 64);
  v0 += __shfl_xor(v0, 32, 64);
  if (lane < 16) atomicAdd(&s_out[l16*6 + 0], v0);
  #pragma unroll
  for (int k=0;k<5;k++){
    float v = t2[k][0] + t2[k][1];
    v += __shfl_xor(v, 16, 64);
    v += __shfl_xor(v, 32, 64);
    if (lane < 16) atomicAdd(&s_out[l16*6 + 1 + k], v);
  }
}

// ============================================================================
// 15 barriers. NT=768 -> 3 waves/SIMD, VGPR cap 85 (R12 measured 84, no
// spill). R13 adds swapped-operand linears with b64 packed stores.
// ============================================================================
__global__ __launch_bounds__(NT) void deeprst_main(
    const float* __restrict__ x,
    const float* __restrict__ l1W0, const float* __restrict__ l1W1,
    const float* __restrict__ l1W2, const float* __restrict__ l1b0,
    const float* __restrict__ l2b0, const float* __restrict__ Lb0,
    const unsigned short* __restrict__ wb, const float* __restrict__ cgp,
    float* __restrict__ out)
{
  __shared__ unsigned short sth[3*BUF];   // 74496 B hi plane
  __shared__ unsigned short stl[3*BUF];   // 74496 B lo plane

  const int tid  = threadIdx.x;
  const int lane = tid & 63;
  const int wave = tid >> 6;
  const int n0   = blockIdx.x * TS;
  const float rs8 = 0.3535533905932738f;

  // ---- lin1 (scalar fp32 -> hi/lo), h1 in buffers 0+1 of both planes ----
  for (int idx=tid; idx<TS*128; idx+=NT){
    int n=idx>>7, o=idx&127;
    const float* xp = x + (n0+n)*80;
    float acc=0.f;
    #pragma unroll
    for (int v=0;v<16;v++) acc += xp[v]*l1W0[v*128+o];
    store_hl(sth,stl, n*H1S + o, acc*0.25f + l1b0[o]);
  }
  for (int idx=tid; idx<TS*768; idx+=NT){
    int o=idx&255, i=(idx>>8)%3, n=idx/768;
    const float* xp = x + (n0+n)*80 + 16;
    float acc=0.f;
    #pragma unroll
    for (int v=0;v<8;v++) acc += xp[v*3+i]*l1W1[v*256+o];
    int du = (o<128)? (128 + i*128 + o) : (1152 + i*128 + o-128);
    store_hl(sth,stl, n*H1S + du, acc*rs8);
  }
  for (int idx=tid; idx<TS*640; idx+=NT){
    int o=idx&127, i=(idx>>7)%5, n=idx/640;
    const float* xp = x + (n0+n)*80 + 40;
    float acc=0.f;
    #pragma unroll
    for (int v=0;v<8;v++) acc += xp[v*5+i]*l1W2[v*128+o];
    store_hl(sth,stl, n*H1S + 512 + i*128 + o, acc*rs8);
  }
  __syncthreads();

  // ---- lin2 (MFMA hi/lo): h1 -> buffer 2 ----
  lin2_mfma(wb, l2b0, sth, stl, sth+2*BUF, stl+2*BUF, wave, lane);
  __syncthreads();

  // ---- 3 rounds: split -> fused tp_uvu -> linear (3 barriers/round) ----
  int ih = 2, i0 = 0, i1 = 1;
  for (int r=0;r<3;r++){
    unsigned short *hh=sth+ih*BUF, *hl=stl+ih*BUF;
    unsigned short *ah=sth+i0*BUF, *al=stl+i0*BUF;
    unsigned short *bh=sth+i1*BUF, *bl=stl+i1*BUF;
    linL_mfma(wb, OFF_LW0+(3*r  )*4096, OFF_LW1+(3*r  )*16384, OFF_LW2+(3*r  )*4096,
              Lb0+(3*r  )*64, hh, hl, ah, al, wave, lane);
    linL_mfma(wb, OFF_LW0+(3*r+1)*4096, OFF_LW1+(3*r+1)*16384, OFF_LW2+(3*r+1)*4096,
              Lb0+(3*r+1)*64, hh, hl, bh, bl, wave, lane);
    __syncthreads();   // lin writes -> TP reads
    fused_tp_uvu(wb, OFF_TPW + r*14*4096, ah, al, bh, bl, hh, hl, cgp, wave, lane);
    __syncthreads();   // TP writes h -> linC reads h
    linL_mfma(wb, OFF_LW0+(3*r+2)*4096, OFF_LW1+(3*r+2)*16384, OFF_LW2+(3*r+2)*4096,
              Lb0+(3*r+2)*64, hh, hl, ah, al, wave, lane);
    __syncthreads();   // linC writes a -> next round reads
    int nh=i0; i0=i1; i1=ih; ih=nh;
  }

  // ---- split4 + fully-connected TP ----
  unsigned short *hh=sth+ih*BUF, *hl=stl+ih*BUF;
  unsigned short *ah=sth+i0*BUF, *al=stl+i0*BUF;
  unsigned short *bh=sth+i1*BUF, *bl=stl+i1*BUF;
  linL_mfma(wb, OFF_LW0+ 9*4096, OFF_LW1+ 9*16384, OFF_LW2+ 9*4096, Lb0+ 9*64, hh, hl, ah, al, wave, lane);
  linL_mfma(wb, OFF_LW0+10*4096, OFF_LW1+10*16384, OFF_LW2+10*4096, Lb0+10*64, hh, hl, bh, bl, wave, lane);
  __syncthreads();   // lin reads of h done -> safe to reuse h as s_out

  float* s_out = (float*)hh;   // h buffer dead after split4 linears
  if (tid < TS*6) s_out[tid] = 0.f;
  __syncthreads();   // zero visible before atomics

  fused_tp_fc(wb, ah, al, bh, bl, s_out, cgp, wave, lane);
  __syncthreads();   // atomics done -> read s_out

  if (tid < TS*6){
    int n=tid/6, k=tid%6;
    float sc = (k==0)? (1.0f/sqrtf(24576.0f)) : (1.0f/sqrtf(45056.0f));
    out[(n0+n)*6+k] = s_out[tid]*sc;
  }
}

// ============================================================================
extern "C" void kernel_launch(void* const* d_in, const int* in_sizes, int n_in,
                              void* d_out, int out_size, void* d_ws, size_t ws_size,
                              hipStream_t stream)
{
  (void)n_in; (void)out_size; (void)ws_size;
  const float* x    = (const float*)d_in[0];
  const float* l1W0 = (const float*)d_in[1];
  const float* l1W1 = (const float*)d_in[2];
  const float* l1W2 = (const float*)d_in[3];
  const float* l1b0 = (const float*)d_in[4];
  const float* l2W0 = (const float*)d_in[5];
  const float* l2W1 = (const float*)d_in[6];
  const float* l2W2 = (const float*)d_in[7];
  const float* l2b0 = (const float*)d_in[8];
  const float* LW0  = (const float*)d_in[9];
  const float* LW1  = (const float*)d_in[10];
  const float* LW2  = (const float*)d_in[11];
  const float* Lb0  = (const float*)d_in[12];
  const float* tpw  = (const float*)d_in[13];
  const float* tp4w = (const float*)d_in[14];

  float* cg = (float*)d_ws;                                    // 525 f32 @ ws+0
  unsigned short* wb = (unsigned short*)((char*)d_ws + 4096);  // hi + lo planes
  const int n = in_sizes[0]/80;

  cg_init_kernel<<<1, 576, 0, stream>>>(cg);
  prep_kernel<<<(W_TOT+255)/256, 256, 0, stream>>>(l2W0,l2W1,l2W2,LW0,LW1,LW2,tpw,tp4w,wb);
  deeprst_main<<<n/TS, NT, 0, stream>>>(x,l1W0,l1W1,l1W2,l1b0,l2b0,Lb0,wb,cg,(float*)d_out);
}

// Round 14
// 701.187 us; speedup vs baseline: 1.7738x; 1.0840x over previous
//
#include <hip/hip_runtime.h>
#include <math.h>

constexpr int TS = 16;     // samples per block
constexpr int NT = 768;    // threads per block (12 waves = 3 waves/SIMD)
constexpr int NW = NT/64;  // 12 waves
constexpr int SSTRIDE = 776;   // bf16 per sample, HID0 state (768 + 8 pad)
constexpr int H1S = 1544;      // bf16 per sample, HID1 transient (1536 + 8 pad)
constexpr int BUF = TS*SSTRIDE;
// HID0 per-sample layout: l0 @0 (64: [u]), l1 @64 (3x64: [i][u]),
// l2 @256 (5x64), l1b @576 (3x64)
// HID1 layout: l0 @0 (128), l1 @128 (3x128), l2 @512 (5x128), l1b @1152 (3x128)
//
// R13 (681us): swapped-operand linears (mfma(w,x)) + b64 packed stores cut
// LDS store instrs 4x -> -10%. BUT WRITE_SIZE 384B -> 295MB: the new store
// path (4 acc components + float4 bias + unrolled weight window all live)
// pushed peak pressure past the 85-reg cap at 3 waves/SIMD -> partial spill
// (~375 B/thread). R14: KFENCE between per-(job,i) units in the linears
// (same medicine as R8->R9) -- each unit's live set ~60 regs < 85.
// Everything else identical to R13.

typedef __attribute__((ext_vector_type(8))) short bf16x8;
typedef __attribute__((ext_vector_type(4))) float f32x4;
typedef __attribute__((ext_vector_type(2))) float f32x2;
typedef __attribute__((ext_vector_type(4))) unsigned short u16x4;

#define KFENCE() asm volatile("" ::: "memory")

__device__ inline f32x4 mfma16(bf16x8 a, bf16x8 b, f32x4 c){
  return __builtin_amdgcn_mfma_f32_16x16x32_bf16(a, b, c, 0, 0, 0);
}
__device__ inline unsigned short f2b(float f){
  union { float f; unsigned u; } v; v.f = f;
  return (unsigned short)((v.u + 0x7fffu + ((v.u >> 16) & 1u)) >> 16);
}
__device__ inline float b2f(unsigned short h){
  union { unsigned u; float f; } v; v.u = ((unsigned)h) << 16; return v.f;
}
__device__ inline void store_hl(unsigned short* ph, unsigned short* pl, int idx, float v){
  unsigned short h = f2b(v);
  ph[idx] = h;
  pl[idx] = f2b(v - b2f(h));
}
#define LDFRAG(p) (*(const bf16x8*)(p))

// ws bf16 weight offsets (elements, base = ws+4096B). lo plane at +W_TOT.
constexpr int OFF_L2W0 = 0;        // 64x128 (WT[o][k])
constexpr int OFF_L2W1 = 8192;     // 128x256
constexpr int OFF_L2W2 = 40960;    // 64x128
constexpr int OFF_LW0  = 49152;    // 11 x 64x64
constexpr int OFF_LW1  = 94208;    // 11 x 128x128
constexpr int OFF_LW2  = 274432;   // 11 x 64x64
constexpr int OFF_TPW  = 319488;   // 3x14 x 64x64 ([u][v])
constexpr int OFF_TP4W = 491520;   // 17 x 64x64
constexpr int W_TOT    = 561152;

// ============================================================================
// Clebsch-Gordan init (element-parallel fp64; verified R2/R3)
// offsets: 0:(0,0,0)@0 1:(0,1,1)@1 2:(1,0,1)@10 3:(0,2,2)@19 4:(2,0,2)@44
// 5:(1,1,0)@69 6:(1,1,1)@78 7:(1,1,2)@105 8:(2,1,2)@150 9:(1,2,2)@225
// 10:(2,2,0)@300 11:(2,2,1)@325 12:(2,2,2)@400 ; total 525 floats
// ============================================================================
__device__ inline double dfact(int n){ double r=1.0; for(int i=2;i<=n;i++) r*=(double)i; return r; }
struct dcplx { double x, y; };
__device__ inline dcplx cmul(dcplx a, dcplx b){ return {a.x*b.x-a.y*b.y, a.x*b.y+a.y*b.x}; }

__device__ dcplx Uent(int l, int r, int c){
  double re=0.0, im=0.0;
  double s = 1.0/sqrt(2.0);
  if (r==l && c==l) re = 1.0;
  else if (c>l){ int m=c-l; double sgn=(m&1)?-1.0:1.0;
    if (r==l-m) re = s; else if (r==l+m) re = sgn*s;
  } else if (c<l){ int m=l-c; double sgn=(m&1)?-1.0:1.0;
    if (r==l-m) im = s; else if (r==l+m) im = -sgn*s;
  }
  int lm=l&3; double pr,pi;
  if(lm==0){pr=1;pi=0;} else if(lm==1){pr=0;pi=-1;} else if(lm==2){pr=-1;pi=0;} else {pr=0;pi=1;}
  return { re*pr-im*pi, re*pi+im*pr };
}

__device__ double cg_complex_entry(int l1,int l2,int l3,int m1,int m2){
  int m3=m1+m2;
  if (m3<-l3 || m3>l3) return 0.0;
  double pref = sqrt((double)(2*l3+1)*dfact(l3+l1-l2)*dfact(l3-l1+l2)*dfact(l1+l2-l3)/dfact(l1+l2+l3+1));
  pref *= sqrt(dfact(l3+m3)*dfact(l3-m3)*dfact(l1-m1)*dfact(l1+m1)*dfact(l2-m2)*dfact(l2+m2));
  double s=0.0;
  for(int k=0;k<=l1+l2-l3;k++){
    int a2=l1-m1-k, a3=l2+m2-k, a4=l3-l2+m1+k, a5=l3-l1-m2+k;
    if(a2<0||a3<0||a4<0||a5<0) continue;
    double t=1.0/(dfact(k)*dfact(l1+l2-l3-k)*dfact(a2)*dfact(a3)*dfact(a4)*dfact(a5));
    s += (k&1)? -t : t;
  }
  return pref*s;
}

__global__ void cg_init_kernel(float* cg){
  __shared__ double sKr[525], sKi[525];
  __shared__ double sScale[13];
  __shared__ int    sSel[13];
  const int L1[13]={0,0,1,0,2,1,1,1,2,1,2,2,2};
  const int L2[13]={0,1,0,2,0,1,1,1,1,2,2,2,2};
  const int L3[13]={0,1,1,2,2,0,1,2,2,2,0,1,2};
  const int OFF[14]={0,1,10,19,44,69,78,105,150,225,300,325,400,525};
  const int tid = threadIdx.x;
  int combo=-1, l1=0,l2=0,l3=0;
  if (tid < 525){
    combo=12;
    for(int i=0;i<12;i++) if (tid < OFF[i+1]) { combo=i; break; }
    l1=L1[combo]; l2=L2[combo]; l3=L3[combo];
    int d2=2*l2+1, d3=2*l3+1;
    int e = tid - OFF[combo];
    int a = e/(d2*d3), b=(e/d3)%d2, cc=e%d3;
    double kr=0.0, ki=0.0;
    for(int m=0;m<2*l1+1;m++) for(int n=0;n<d2;n++){
      int m3 = (m-l1)+(n-l2);
      if (m3<-l3||m3>l3) continue;
      double cv = cg_complex_entry(l1,l2,l3,m-l1,n-l2);
      if (cv==0.0) continue;
      dcplx u1=Uent(l1,m,a), u2=Uent(l2,n,b), u3=Uent(l3,m3+l3,cc);
      u3.y = -u3.y;
      dcplx t = cmul(cmul(u1,u2),u3);
      kr += t.x*cv; ki += t.y*cv;
    }
    sKr[tid]=kr; sKi[tid]=ki;
  }
  __syncthreads();
  if (tid < 13){
    int sz = OFF[tid+1]-OFF[tid];
    double nr=0,ni=0;
    for(int i=0;i<sz;i++){ double r=sKr[OFF[tid]+i], im=sKi[OFF[tid]+i]; nr+=r*r; ni+=im*im; }
    int sel = (nr>=ni)? 0 : 1;
    sSel[tid]=sel;
    sScale[tid] = sqrt((double)(2*L3[tid]+1))/sqrt(sel? ni : nr);
  }
  __syncthreads();
  if (tid < 525){
    double v = sSel[combo]? sKi[tid] : sKr[tid];
    cg[tid] = (float)(v*sScale[combo]);
  }
}

// ============================================================================
// Weight prep: fp32 -> bf16 hi/lo planes. Linear weights transposed WT[o][k];
// TP weights [u][v].
// ============================================================================
__global__ void prep_kernel(const float* __restrict__ l2W0, const float* __restrict__ l2W1,
                            const float* __restrict__ l2W2, const float* __restrict__ LW0,
                            const float* __restrict__ LW1, const float* __restrict__ LW2,
                            const float* __restrict__ tpw, const float* __restrict__ tp4w,
                            unsigned short* __restrict__ wb){
  int i = blockIdx.x*256 + threadIdx.x;
  if (i >= W_TOT) return;
  float v;
  if (i < 8192){ int o=i>>7, k=i&127; v = l2W0[k*64+o]; }
  else if (i < 40960){ int j=i-8192; int o=j>>8, k=j&255; v = l2W1[k*128+o]; }
  else if (i < 49152){ int j=i-40960; int o=j>>7, k=j&127; v = l2W2[k*64+o]; }
  else if (i < 94208){ int j=i-49152; int li=j>>12, r=j&4095, o=r>>6, k=r&63; v = LW0[li*4096+k*64+o]; }
  else if (i < 274432){ int j=i-94208; int li=j>>14, r=j&16383, o=r>>7, k=r&127; v = LW1[li*16384+k*128+o]; }
  else if (i < 319488){ int j=i-274432; int li=j>>12, r=j&4095, o=r>>6, k=r&63; v = LW2[li*4096+k*64+o]; }
  else if (i < 491520){ v = tpw[i-319488]; }
  else { v = tp4w[i-491520]; }
  unsigned short h = f2b(v);
  wb[i] = h;
  wb[W_TOT + i] = f2b(v - b2f(h));
}

// pack 4 consecutive values into one b64 store per plane
__device__ inline void store4_hl(unsigned short* ph, unsigned short* pl, int idx,
                                 float v0, float v1, float v2, float v3){
  u16x4 vh, vl;
  float v[4] = {v0,v1,v2,v3};
  #pragma unroll
  for (int r=0;r<4;r++){
    unsigned short h = f2b(v[r]);
    vh[r] = h;
    vl[r] = f2b(v[r] - b2f(h));
  }
  *(u16x4*)(ph + idx) = vh;
  *(u16x4*)(pl + idx) = vl;
}

// ============================================================================
// MFMA linear HID0->HID0 (hi/lo), SWAPPED operands mfma(w,x): C row=feature
// (quad*4+r), col=sample (l16) -> each lane stores 4 CONTIGUOUS features of
// one sample via store4_hl (b64, bank-balanced). KFENCE between per-(job,i)
// units caps live pressure under the 85-reg cap (R13's 295MB spill fix).
// Jobs: 0..3 l0 | 4..11 l1 | 12..15 l2. NW=12: w0-3 {l0,l2}; w4-11 one l1.
// ============================================================================
__device__ void linL_mfma(const unsigned short* __restrict__ wb, int o0, int o1, int o2,
                          const float* __restrict__ b0,
                          const unsigned short* sh, const unsigned short* sl,
                          unsigned short* dh, unsigned short* dl, int wave, int lane)
{
  const float rs128 = 0.08838834764831845f;
  int l16 = lane & 15, quad = lane >> 4;
  int abase = l16 * SSTRIDE;        // sample = l16 (B operand / stores)
  for (int job = wave; job < 16; job += NW){
    if (job < 4){                 // l0: K=64, /8 + bias
      f32x4 a0 = {0,0,0,0}, a1 = {0,0,0,0};
      #pragma unroll
      for (int ks=0; ks<2; ks++){
        int so = abase + ks*32 + quad*8;
        bf16x8 xh = LDFRAG(sh+so), xl = LDFRAG(sl+so);
        int wo = o0 + (job*16 + l16)*64 + ks*32 + quad*8;
        bf16x8 wh = LDFRAG(wb+wo), wl = LDFRAG(wb+W_TOT+wo);
        a0 = mfma16(wh,xh,a0); a1 = mfma16(wl,xh,a1); a1 = mfma16(wh,xl,a1);
      }
      int fb = job*16 + quad*4;
      float4 b4 = *(const float4*)(b0 + fb);
      store4_hl(dh,dl, abase + fb,
                (a0[0]+a1[0])*0.125f + b4.x, (a0[1]+a1[1])*0.125f + b4.y,
                (a0[2]+a1[2])*0.125f + b4.z, (a0[3]+a1[3])*0.125f + b4.w);
      KFENCE();
    } else if (job < 12){         // l1: K=128 (l1|l1b), /sqrt(128)
      int nt = job-4;
      #pragma unroll
      for (int i=0;i<3;i++){
        f32x4 a0 = {0,0,0,0}, a1 = {0,0,0,0};
        #pragma unroll
        for (int ks=0; ks<4; ks++){
          int ka = ks*32 + quad*8;
          int so = abase + ((ka < 64) ? (64 + i*64 + ka) : (576 + i*64 + ka - 64));
          bf16x8 xh = LDFRAG(sh+so), xl = LDFRAG(sl+so);
          int wo = o1 + (nt*16 + l16)*128 + ka;
          bf16x8 wh = LDFRAG(wb+wo), wl = LDFRAG(wb+W_TOT+wo);
          a0 = mfma16(wh,xh,a0); a1 = mfma16(wl,xh,a1); a1 = mfma16(wh,xl,a1);
        }
        int colb = nt*16 + quad*4;
        int dof = (nt < 4) ? (64 + i*64 + colb) : (576 + i*64 + colb - 64);
        store4_hl(dh,dl, abase + dof,
                  (a0[0]+a1[0])*rs128, (a0[1]+a1[1])*rs128,
                  (a0[2]+a1[2])*rs128, (a0[3]+a1[3])*rs128);
        KFENCE();
      }
    } else {                      // l2: K=64, /8
      int nt = job-12;
      #pragma unroll
      for (int i=0;i<5;i++){
        f32x4 a0 = {0,0,0,0}, a1 = {0,0,0,0};
        #pragma unroll
        for (int ks=0; ks<2; ks++){
          int so = abase + 256 + i*64 + ks*32 + quad*8;
          bf16x8 xh = LDFRAG(sh+so), xl = LDFRAG(sl+so);
          int wo = o2 + (nt*16 + l16)*64 + ks*32 + quad*8;
          bf16x8 wh = LDFRAG(wb+wo), wl = LDFRAG(wb+W_TOT+wo);
          a0 = mfma16(wh,xh,a0); a1 = mfma16(wl,xh,a1); a1 = mfma16(wh,xl,a1);
        }
        store4_hl(dh,dl, abase + 256 + i*64 + nt*16 + quad*4,
                  (a0[0]+a1[0])*0.125f, (a0[1]+a1[1])*0.125f,
                  (a0[2]+a1[2])*0.125f, (a0[3]+a1[3])*0.125f);
        KFENCE();
      }
    }
  }
}

// lin2: HID1 -> HID0 (K=128/256/128), hi/lo, swapped operands + b64 stores.
__device__ void lin2_mfma(const unsigned short* __restrict__ wb,
                          const float* __restrict__ b0,
                          const unsigned short* h1h, const unsigned short* h1l,
                          unsigned short* dh, unsigned short* dl, int wave, int lane)
{
  const float rs128 = 0.08838834764831845f;
  int l16 = lane & 15, quad = lane >> 4;
  int abase = l16 * H1S;            // sample = l16 (B operand)
  int obase = l16 * SSTRIDE;        // output rows
  for (int job = wave; job < 16; job += NW){
    if (job < 4){                 // l0: K=128
      f32x4 a0 = {0,0,0,0}, a1 = {0,0,0,0};
      #pragma unroll
      for (int ks=0; ks<4; ks++){
        int so = abase + ks*32 + quad*8;
        bf16x8 xh = LDFRAG(h1h+so), xl = LDFRAG(h1l+so);
        int wo = OFF_L2W0 + (job*16 + l16)*128 + ks*32 + quad*8;
        bf16x8 wh = LDFRAG(wb+wo), wl = LDFRAG(wb+W_TOT+wo);
        a0 = mfma16(wh,xh,a0); a1 = mfma16(wl,xh,a1); a1 = mfma16(wh,xl,a1);
      }
      int fb = job*16 + quad*4;
      float4 b4 = *(const float4*)(b0 + fb);
      store4_hl(dh,dl, obase + fb,
                (a0[0]+a1[0])*rs128 + b4.x, (a0[1]+a1[1])*rs128 + b4.y,
                (a0[2]+a1[2])*rs128 + b4.z, (a0[3]+a1[3])*rs128 + b4.w);
      KFENCE();
    } else if (job < 12){         // l1: K=256, /16
      int nt = job-4;
      #pragma unroll
      for (int i=0;i<3;i++){
        f32x4 a0 = {0,0,0,0}, a1 = {0,0,0,0};
        #pragma unroll
        for (int ks=0; ks<8; ks++){
          int ka = ks*32 + quad*8;
          int so = abase + ((ka < 128) ? (128 + i*128 + ka) : (1152 + i*128 + ka - 128));
          bf16x8 xh = LDFRAG(h1h+so), xl = LDFRAG(h1l+so);
          int wo = OFF_L2W1 + (nt*16 + l16)*256 + ka;
          bf16x8 wh = LDFRAG(wb+wo), wl = LDFRAG(wb+W_TOT+wo);
          a0 = mfma16(wh,xh,a0); a1 = mfma16(wl,xh,a1); a1 = mfma16(wh,xl,a1);
        }
        int colb = nt*16 + quad*4;
        int dof = (nt < 4) ? (64 + i*64 + colb) : (576 + i*64 + colb - 64);
        store4_hl(dh,dl, obase + dof,
                  (a0[0]+a1[0])*0.0625f, (a0[1]+a1[1])*0.0625f,
                  (a0[2]+a1[2])*0.0625f, (a0[3]+a1[3])*0.0625f);
        KFENCE();
      }
    } else {                      // l2: K=128
      int nt = job-12;
      #pragma unroll
      for (int i=0;i<5;i++){
        f32x4 a0 = {0,0,0,0}, a1 = {0,0,0,0};
        #pragma unroll
        for (int ks=0; ks<4; ks++){
          int so = abase + 512 + i*128 + ks*32 + quad*8;
          bf16x8 xh = LDFRAG(h1h+so), xl = LDFRAG(h1l+so);
          int wo = OFF_L2W2 + (nt*16 + l16)*128 + ks*32 + quad*8;
          bf16x8 wh = LDFRAG(wb+wo), wl = LDFRAG(wb+W_TOT+wo);
          a0 = mfma16(wh,xh,a0); a1 = mfma16(wl,xh,a1); a1 = mfma16(wh,xl,a1);
        }
        store4_hl(dh,dl, obase + 256 + i*64 + nt*16 + quad*4,
                  (a0[0]+a1[0])*rs128, (a0[1]+a1[1])*rs128,
                  (a0[2]+a1[2])*rs128, (a0[3]+a1[3])*rs128);
        KFENCE();
      }
    }
  }
}

// ============================================================================
// Fused TP path: stage b-fragment in regs via MFMA, contract immediately.
// Wave's fixed mt picks the u-block; lane l -> sample n=l&15,
// u = mt*16 + quad*4 + r. PACKED contraction (f32x2, r-pairs {0,1},{2,3}).
// ============================================================================
template<int D1,int D2,int D3,int O1,int O2,int CGO>
__device__ __forceinline__ void fused_path(
    const unsigned short* __restrict__ wb, int wo,
    const unsigned short* s1h, const unsigned short* s1l,
    const unsigned short* s2h, const unsigned short* s2l,
    const float* __restrict__ cgp,
    f32x2 (&tk)[2][D3], int mt, int lane)
{
  int l16 = lane & 15, quad = lane >> 4;
  f32x2 x1v[D1][2];
  #pragma unroll
  for (int i=0;i<D1;i++){
    int o = l16*SSTRIDE + O1 + i*64 + mt*16 + quad*4;
    u16x4 xh4 = *(const u16x4*)(s1h + o);
    u16x4 xl4 = *(const u16x4*)(s1l + o);
    #pragma unroll
    for (int h=0;h<2;h++){
      f32x2 v;
      v[0] = b2f(xh4[2*h  ]) + b2f(xl4[2*h  ]);
      v[1] = b2f(xh4[2*h+1]) + b2f(xl4[2*h+1]);
      x1v[i][h] = v;
    }
  }
  #pragma unroll
  for (int j=0;j<D2;j++){
    f32x4 a0 = {0,0,0,0}, a1 = {0,0,0,0};
    #pragma unroll
    for (int ks=0; ks<2; ks++){
      int wofs = wo + (mt*16 + l16)*64 + ks*32 + quad*8;
      bf16x8 wh = LDFRAG(wb + wofs);
      bf16x8 wl = LDFRAG(wb + W_TOT + wofs);
      int sofs = l16*SSTRIDE + O2 + j*64 + ks*32 + quad*8;
      bf16x8 xh = LDFRAG(s2h + sofs);
      bf16x8 xl = LDFRAG(s2l + sofs);
      a0 = mfma16(wh,xh,a0); a1 = mfma16(wh,xl,a1); a1 = mfma16(wl,xh,a1);
    }
    f32x2 bu0, bu1;
    bu0[0] = a0[0]+a1[0]; bu0[1] = a0[1]+a1[1];
    bu1[0] = a0[2]+a1[2]; bu1[1] = a0[3]+a1[3];
    #pragma unroll
    for (int i=0;i<D1;i++){
      f32x2 pr0 = x1v[i][0]*bu0;
      f32x2 pr1 = x1v[i][1]*bu1;
      #pragma unroll
      for (int k=0;k<D3;k++){
        float c = cgp[CGO + (i*D2 + j)*D3 + k];
        f32x2 cc = {c, c};
        tk[0][k] += pr0*cc;
        tk[1][k] += pr1*cc;
      }
    }
  }
}

// FC variant: output summed over u; r-pairs folded into tk[k] (f32x2).
template<int D1,int D2,int D3,int O1,int O2,int CGO>
__device__ __forceinline__ void fused_path_fc(
    const unsigned short* __restrict__ wb, int wo,
    const unsigned short* s1h, const unsigned short* s1l,
    const unsigned short* s2h, const unsigned short* s2l,
    const float* __restrict__ cgp,
    f32x2 (&tk)[D3], int mt, int lane)
{
  int l16 = lane & 15, quad = lane >> 4;
  f32x2 x1v[D1][2];
  #pragma unroll
  for (int i=0;i<D1;i++){
    int o = l16*SSTRIDE + O1 + i*64 + mt*16 + quad*4;
    u16x4 xh4 = *(const u16x4*)(s1h + o);
    u16x4 xl4 = *(const u16x4*)(s1l + o);
    #pragma unroll
    for (int h=0;h<2;h++){
      f32x2 v;
      v[0] = b2f(xh4[2*h  ]) + b2f(xl4[2*h  ]);
      v[1] = b2f(xh4[2*h+1]) + b2f(xl4[2*h+1]);
      x1v[i][h] = v;
    }
  }
  #pragma unroll
  for (int j=0;j<D2;j++){
    f32x4 a0 = {0,0,0,0}, a1 = {0,0,0,0};
    #pragma unroll
    for (int ks=0; ks<2; ks++){
      int wofs = wo + (mt*16 + l16)*64 + ks*32 + quad*8;
      bf16x8 wh = LDFRAG(wb + wofs);
      bf16x8 wl = LDFRAG(wb + W_TOT + wofs);
      int sofs = l16*SSTRIDE + O2 + j*64 + ks*32 + quad*8;
      bf16x8 xh = LDFRAG(s2h + sofs);
      bf16x8 xl = LDFRAG(s2l + sofs);
      a0 = mfma16(wh,xh,a0); a1 = mfma16(wh,xl,a1); a1 = mfma16(wl,xh,a1);
    }
    f32x2 bu0, bu1;
    bu0[0] = a0[0]+a1[0]; bu0[1] = a0[1]+a1[1];
    bu1[0] = a0[2]+a1[2]; bu1[1] = a0[3]+a1[3];
    #pragma unroll
    for (int i=0;i<D1;i++){
      f32x2 pr = x1v[i][0]*bu0;
      pr += x1v[i][1]*bu1;
      #pragma unroll
      for (int k=0;k<D3;k++){
        float c = cgp[CGO + (i*D2 + j)*D3 + k];
        f32x2 cc = {c, c};
        tk[k] += pr*cc;
      }
    }
  }
}

// uvu TP, one barrier-free phase. 12 waves = 3 output-groups x 4 mt
// (disjoint LDS ranges, no merging): w0-3 l2, w4-7 l1, w8-11 l1b+l0.
// KFENCE every ~2 paths keeps live regs under the 85-reg cap.
__device__ void fused_tp_uvu(const unsigned short* __restrict__ wb, int two,
    const unsigned short* ah, const unsigned short* al,
    const unsigned short* bh, const unsigned short* bl,
    unsigned short* dh, unsigned short* dl,
    const float* __restrict__ cgp, int wave, int lane)
{
  const float f192 = 0.07216878364870323f;  // 1/sqrt(192)
  const float f256 = 0.0625f;               // 1/sqrt(256)
  int mt = wave & 3, grp = wave >> 2;
  int l16 = lane & 15, quad = lane >> 4;
  int u0 = mt*16 + quad*4;
  if (grp == 0){
    // out l2 @256 (fan 256): paths 2,8,9,13
    f32x2 tk2[2][5] = {};
    fused_path<1,5,5,  0,256, 19>(wb,two+ 2*4096, ah,al,bh,bl,cgp,tk2,mt,lane);
    fused_path<5,1,5,256,  0, 44>(wb,two+ 8*4096, ah,al,bh,bl,cgp,tk2,mt,lane);
    KFENCE();
    fused_path<5,3,5,256, 64,150>(wb,two+ 9*4096, ah,al,bh,bl,cgp,tk2,mt,lane);
    fused_path<5,3,5,256,576,150>(wb,two+13*4096, ah,al,bh,bl,cgp,tk2,mt,lane);
    #pragma unroll
    for (int k=0;k<5;k++)
      store4_hl(dh,dl, l16*SSTRIDE + 256 + k*64 + u0,
                tk2[0][k][0]*f256, tk2[0][k][1]*f256, tk2[1][k][0]*f256, tk2[1][k][1]*f256);
  } else if (grp == 1){
    // out l1 @64 (fan 256): paths 1,4,6,11
    f32x2 tkA[2][3] = {};
    fused_path<1,3,3,  0, 64,  1>(wb,two+ 1*4096, ah,al,bh,bl,cgp,tkA,mt,lane);
    fused_path<3,1,3, 64,  0, 10>(wb,two+ 4*4096, ah,al,bh,bl,cgp,tkA,mt,lane);
    KFENCE();
    fused_path<3,3,3, 64, 64, 78>(wb,two+ 6*4096, ah,al,bh,bl,cgp,tkA,mt,lane);
    fused_path<5,5,3,256,256,325>(wb,two+11*4096, ah,al,bh,bl,cgp,tkA,mt,lane);
    #pragma unroll
    for (int k=0;k<3;k++)
      store4_hl(dh,dl, l16*SSTRIDE +  64 + k*64 + u0,
                tkA[0][k][0]*f256, tkA[0][k][1]*f256, tkA[1][k][0]*f256, tkA[1][k][1]*f256);
  } else {
    // out l1b @576 (fan 192): paths 3,7,12, then l0 @0 (fan 192): 0,5,10
    {
      f32x2 tkB[2][3] = {};
      fused_path<1,3,3,  0,576,  1>(wb,two+ 3*4096, ah,al,bh,bl,cgp,tkB,mt,lane);
      fused_path<3,3,3, 64, 64, 78>(wb,two+ 7*4096, ah,al,bh,bl,cgp,tkB,mt,lane);
      KFENCE();
      fused_path<5,5,3,256,256,325>(wb,two+12*4096, ah,al,bh,bl,cgp,tkB,mt,lane);
      #pragma unroll
      for (int k=0;k<3;k++)
        store4_hl(dh,dl, l16*SSTRIDE + 576 + k*64 + u0,
                  tkB[0][k][0]*f192, tkB[0][k][1]*f192, tkB[1][k][0]*f192, tkB[1][k][1]*f192);
      KFENCE();
    }
    {
      f32x2 tk0[2][1] = {};
      fused_path<1,1,1,  0,  0,  0>(wb,two+ 0*4096, ah,al,bh,bl,cgp,tk0,mt,lane);
      fused_path<3,3,1, 64, 64, 69>(wb,two+ 5*4096, ah,al,bh,bl,cgp,tk0,mt,lane);
      KFENCE();
      fused_path<5,5,1,256,256,300>(wb,two+10*4096, ah,al,bh,bl,cgp,tk0,mt,lane);
      store4_hl(dh,dl, l16*SSTRIDE + u0,
                tk0[0][0][0]*f192, tk0[0][0][1]*f192, tk0[1][0][0]*f192, tk0[1][0][1]*f192);
    }
  }
}

// FC TP: 3 path-groups x 4 mt (atomicAdd makes any partition valid).
__device__ void fused_tp_fc(const unsigned short* __restrict__ wb,
    const unsigned short* ah, const unsigned short* al,
    const unsigned short* bh, const unsigned short* bl,
    float* s_out, const float* __restrict__ cgp, int wave, int lane)
{
  int mt = wave & 3, grp = wave >> 2;
  int l16 = lane & 15;
  f32x2 t0[1] = {};
  f32x2 t2[5] = {};
  if (grp == 0){
    fused_path_fc<5,5,5,256,256,400>(wb,OFF_TP4W+12*4096, ah,al,bh,bl,cgp,t2,mt,lane);
    KFENCE();
    fused_path_fc<3,5,5, 64,256,225>(wb,OFF_TP4W+ 8*4096, ah,al,bh,bl,cgp,t2,mt,lane);
    KFENCE();
    fused_path_fc<5,5,1,256,256,300>(wb,OFF_TP4W+ 3*4096, ah,al,bh,bl,cgp,t0,mt,lane);
  } else if (grp == 1){
    fused_path_fc<5,3,5,256, 64,150>(wb,OFF_TP4W+11*4096, ah,al,bh,bl,cgp,t2,mt,lane);
    fused_path_fc<5,3,5,256,576,150>(wb,OFF_TP4W+13*4096, ah,al,bh,bl,cgp,t2,mt,lane);
    KFENCE();
    fused_path_fc<3,3,5, 64, 64,105>(wb,OFF_TP4W+ 7*4096, ah,al,bh,bl,cgp,t2,mt,lane);
    fused_path_fc<3,3,5, 64,576,105>(wb,OFF_TP4W+ 9*4096, ah,al,bh,bl,cgp,t2,mt,lane);
    KFENCE();
    fused_path_fc<1,1,1,  0,  0,  0>(wb,OFF_TP4W+ 0*4096, ah,al,bh,bl,cgp,t0,mt,lane);
    fused_path_fc<3,3,1, 64, 64, 69>(wb,OFF_TP4W+ 1*4096, ah,al,bh,bl,cgp,t0,mt,lane);
  } else {
    fused_path_fc<1,5,5,  0,256, 19>(wb,OFF_TP4W+ 6*4096, ah,al,bh,bl,cgp,t2,mt,lane);
    fused_path_fc<5,1,5,256,  0, 44>(wb,OFF_TP4W+10*4096, ah,al,bh,bl,cgp,t2,mt,lane);
    KFENCE();
    fused_path_fc<3,3,5,576, 64,105>(wb,OFF_TP4W+14*4096, ah,al,bh,bl,cgp,t2,mt,lane);
    fused_path_fc<3,5,5,576,256,225>(wb,OFF_TP4W+15*4096, ah,al,bh,bl,cgp,t2,mt,lane);
    KFENCE();
    fused_path_fc<3,3,5,576,576,105>(wb,OFF_TP4W+16*4096, ah,al,bh,bl,cgp,t2,mt,lane);
    fused_path_fc<3,3,1, 64,576, 69>(wb,OFF_TP4W+ 2*4096, ah,al,bh,bl,cgp,t0,mt,lane);
    KFENCE();
    fused_path_fc<3,3,1,576, 64, 69>(wb,OFF_TP4W+ 4*4096, ah,al,bh,bl,cgp,t0,mt,lane);
    fused_path_fc<3,3,1,576,576, 69>(wb,OFF_TP4W+ 5*4096, ah,al,bh,bl,cgp,t0,mt,lane);
  }
  float v0 = t0[0][0] + t0[0][1];
  v0 += __shfl_xor(v0, 16, 64);
  v0 += __shfl_xor(v0, 32, 64);
  if (lane < 16) atomicAdd(&s_out[l16*6 + 0], v0);
  #pragma unroll
  for (int k=0;k<5;k++){
    float v = t2[k][0] + t2[k][1];
    v += __shfl_xor(v, 16, 64);
    v += __shfl_xor(v, 32, 64);
    if (lane < 16) atomicAdd(&s_out[l16*6 + 1 + k], v);
  }
}

// ============================================================================
// 15 barriers. NT=768 -> 3 waves/SIMD, VGPR cap 85. R14: KFENCE per linear
// unit kills the R13 spill (WRITE 295MB -> expected <5MB).
// ============================================================================
__global__ __launch_bounds__(NT) void deeprst_main(
    const float* __restrict__ x,
    const float* __restrict__ l1W0, const float* __restrict__ l1W1,
    const float* __restrict__ l1W2, const float* __restrict__ l1b0,
    const float* __restrict__ l2b0, const float* __restrict__ Lb0,
    const unsigned short* __restrict__ wb, const float* __restrict__ cgp,
    float* __restrict__ out)
{
  __shared__ unsigned short sth[3*BUF];   // 74496 B hi plane
  __shared__ unsigned short stl[3*BUF];   // 74496 B lo plane

  const int tid  = threadIdx.x;
  const int lane = tid & 63;
  const int wave = tid >> 6;
  const int n0   = blockIdx.x * TS;
  const float rs8 = 0.3535533905932738f;

  // ---- lin1 (scalar fp32 -> hi/lo), h1 in buffers 0+1 of both planes ----
  for (int idx=tid; idx<TS*128; idx+=NT){
    int n=idx>>7, o=idx&127;
    const float* xp = x + (n0+n)*80;
    float acc=0.f;
    #pragma unroll
    for (int v=0;v<16;v++) acc += xp[v]*l1W0[v*128+o];
    store_hl(sth,stl, n*H1S + o, acc*0.25f + l1b0[o]);
  }
  for (int idx=tid; idx<TS*768; idx+=NT){
    int o=idx&255, i=(idx>>8)%3, n=idx/768;
    const float* xp = x + (n0+n)*80 + 16;
    float acc=0.f;
    #pragma unroll
    for (int v=0;v<8;v++) acc += xp[v*3+i]*l1W1[v*256+o];
    int du = (o<128)? (128 + i*128 + o) : (1152 + i*128 + o-128);
    store_hl(sth,stl, n*H1S + du, acc*rs8);
  }
  for (int idx=tid; idx<TS*640; idx+=NT){
    int o=idx&127, i=(idx>>7)%5, n=idx/640;
    const float* xp = x + (n0+n)*80 + 40;
    float acc=0.f;
    #pragma unroll
    for (int v=0;v<8;v++) acc += xp[v*5+i]*l1W2[v*128+o];
    store_hl(sth,stl, n*H1S + 512 + i*128 + o, acc*rs8);
  }
  __syncthreads();

  // ---- lin2 (MFMA hi/lo): h1 -> buffer 2 ----
  lin2_mfma(wb, l2b0, sth, stl, sth+2*BUF, stl+2*BUF, wave, lane);
  __syncthreads();

  // ---- 3 rounds: split -> fused tp_uvu -> linear (3 barriers/round) ----
  int ih = 2, i0 = 0, i1 = 1;
  for (int r=0;r<3;r++){
    unsigned short *hh=sth+ih*BUF, *hl=stl+ih*BUF;
    unsigned short *ah=sth+i0*BUF, *al=stl+i0*BUF;
    unsigned short *bh=sth+i1*BUF, *bl=stl+i1*BUF;
    linL_mfma(wb, OFF_LW0+(3*r  )*4096, OFF_LW1+(3*r  )*16384, OFF_LW2+(3*r  )*4096,
              Lb0+(3*r  )*64, hh, hl, ah, al, wave, lane);
    linL_mfma(wb, OFF_LW0+(3*r+1)*4096, OFF_LW1+(3*r+1)*16384, OFF_LW2+(3*r+1)*4096,
              Lb0+(3*r+1)*64, hh, hl, bh, bl, wave, lane);
    __syncthreads();   // lin writes -> TP reads
    fused_tp_uvu(wb, OFF_TPW + r*14*4096, ah, al, bh, bl, hh, hl, cgp, wave, lane);
    __syncthreads();   // TP writes h -> linC reads h
    linL_mfma(wb, OFF_LW0+(3*r+2)*4096, OFF_LW1+(3*r+2)*16384, OFF_LW2+(3*r+2)*4096,
              Lb0+(3*r+2)*64, hh, hl, ah, al, wave, lane);
    __syncthreads();   // linC writes a -> next round reads
    int nh=i0; i0=i1; i1=ih; ih=nh;
  }

  // ---- split4 + fully-connected TP ----
  unsigned short *hh=sth+ih*BUF, *hl=stl+ih*BUF;
  unsigned short *ah=sth+i0*BUF, *al=stl+i0*BUF;
  unsigned short *bh=sth+i1*BUF, *bl=stl+i1*BUF;
  linL_mfma(wb, OFF_LW0+ 9*4096, OFF_LW1+ 9*16384, OFF_LW2+ 9*4096, Lb0+ 9*64, hh, hl, ah, al, wave, lane);
  linL_mfma(wb, OFF_LW0+10*4096, OFF_LW1+10*16384, OFF_LW2+10*4096, Lb0+10*64, hh, hl, bh, bl, wave, lane);
  __syncthreads();   // lin reads of h done -> safe to reuse h as s_out

  float* s_out = (float*)hh;   // h buffer dead after split4 linears
  if (tid < TS*6) s_out[tid] = 0.f;
  __syncthreads();   // zero visible before atomics

  fused_tp_fc(wb, ah, al, bh, bl, s_out, cgp, wave, lane);
  __syncthreads();   // atomics done -> read s_out

  if (tid < TS*6){
    int n=tid/6, k=tid%6;
    float sc = (k==0)? (1.0f/sqrtf(24576.0f)) : (1.0f/sqrtf(45056.0f));
    out[(n0+n)*6+k] = s_out[tid]*sc;
  }
}

// ============================================================================
extern "C" void kernel_launch(void* const* d_in, const int* in_sizes, int n_in,
                              void* d_out, int out_size, void* d_ws, size_t ws_size,
                              hipStream_t stream)
{
  (void)n_in; (void)out_size; (void)ws_size;
  const float* x    = (const float*)d_in[0];
  const float* l1W0 = (const float*)d_in[1];
  const float* l1W1 = (const float*)d_in[2];
  const float* l1W2 = (const float*)d_in[3];
  const float* l1b0 = (const float*)d_in[4];
  const float* l2W0 = (const float*)d_in[5];
  const float* l2W1 = (const float*)d_in[6];
  const float* l2W2 = (const float*)d_in[7];
  const float* l2b0 = (const float*)d_in[8];
  const float* LW0  = (const float*)d_in[9];
  const float* LW1  = (const float*)d_in[10];
  const float* LW2  = (const float*)d_in[11];
  const float* Lb0  = (const float*)d_in[12];
  const float* tpw  = (const float*)d_in[13];
  const float* tp4w = (const float*)d_in[14];

  float* cg = (float*)d_ws;                                    // 525 f32 @ ws+0
  unsigned short* wb = (unsigned short*)((char*)d_ws + 4096);  // hi + lo planes
  const int n = in_sizes[0]/80;

  cg_init_kernel<<<1, 576, 0, stream>>>(cg);
  prep_kernel<<<(W_TOT+255)/256, 256, 0, stream>>>(l2W0,l2W1,l2W2,LW0,LW1,LW2,tpw,tp4w,wb);
  deeprst_main<<<n/TS, NT, 0, stream>>>(x,l1W0,l1W1,l1W2,l1b0,l2b0,Lb0,wb,cg,(float*)d_out);
}

// Round 15
// 692.824 us; speedup vs baseline: 1.7952x; 1.0121x over previous
//
#include <hip/hip_runtime.h>
#include <math.h>

constexpr int TS = 16;     // samples per block
constexpr int NT = 768;    // threads per block (12 waves = 3 waves/SIMD)
constexpr int NW = NT/64;  // 12 waves
constexpr int SSTRIDE = 776;   // bf16 per sample, HID0 state (768 + 8 pad)
constexpr int H1S = 1544;      // bf16 per sample, HID1 transient (1536 + 8 pad)
constexpr int BUF = TS*SSTRIDE;
// HID0 per-sample layout: l0 @0 (64: [u]), l1 @64 (3x64: [i][u]),
// l2 @256 (5x64), l1b @576 (3x64)
// HID1 layout: l0 @0 (128), l1 @128 (3x128), l2 @512 (5x128), l1b @1152 (3x128)
//
// R14 (636us): spill dead (WRITE 3.4KB), VGPR 84, occ 35%. Counters:
// MFMA 11.4 + VALU 26.8 = 38% issue; each wave stalls ~87%, dominated by
// L2-latency (~200cy) weight loads feeding MFMA chains, serialized by the
// 1-unit KFENCEs in the linears. R15: widen linear KFENCE windows to 2 units
// (same medicine dose as the TP's 2-path windows, which fit the 85-reg cap
// at VGPR=84): scheduler can hoist unit k+1's weight loads under unit k's
// MFMA tail. l1: windows {i0,i1},{i2}; l2: {0,1},{2,3},{4}; l0 unchanged.
// WRITE_SIZE is the spill canary (>=50MB -> window overflowed, revert).

typedef __attribute__((ext_vector_type(8))) short bf16x8;
typedef __attribute__((ext_vector_type(4))) float f32x4;
typedef __attribute__((ext_vector_type(2))) float f32x2;
typedef __attribute__((ext_vector_type(4))) unsigned short u16x4;

#define KFENCE() asm volatile("" ::: "memory")

__device__ inline f32x4 mfma16(bf16x8 a, bf16x8 b, f32x4 c){
  return __builtin_amdgcn_mfma_f32_16x16x32_bf16(a, b, c, 0, 0, 0);
}
__device__ inline unsigned short f2b(float f){
  union { float f; unsigned u; } v; v.f = f;
  return (unsigned short)((v.u + 0x7fffu + ((v.u >> 16) & 1u)) >> 16);
}
__device__ inline float b2f(unsigned short h){
  union { unsigned u; float f; } v; v.u = ((unsigned)h) << 16; return v.f;
}
__device__ inline void store_hl(unsigned short* ph, unsigned short* pl, int idx, float v){
  unsigned short h = f2b(v);
  ph[idx] = h;
  pl[idx] = f2b(v - b2f(h));
}
#define LDFRAG(p) (*(const bf16x8*)(p))

// ws bf16 weight offsets (elements, base = ws+4096B). lo plane at +W_TOT.
constexpr int OFF_L2W0 = 0;        // 64x128 (WT[o][k])
constexpr int OFF_L2W1 = 8192;     // 128x256
constexpr int OFF_L2W2 = 40960;    // 64x128
constexpr int OFF_LW0  = 49152;    // 11 x 64x64
constexpr int OFF_LW1  = 94208;    // 11 x 128x128
constexpr int OFF_LW2  = 274432;   // 11 x 64x64
constexpr int OFF_TPW  = 319488;   // 3x14 x 64x64 ([u][v])
constexpr int OFF_TP4W = 491520;   // 17 x 64x64
constexpr int W_TOT    = 561152;

// ============================================================================
// Clebsch-Gordan init (element-parallel fp64; verified R2/R3)
// offsets: 0:(0,0,0)@0 1:(0,1,1)@1 2:(1,0,1)@10 3:(0,2,2)@19 4:(2,0,2)@44
// 5:(1,1,0)@69 6:(1,1,1)@78 7:(1,1,2)@105 8:(2,1,2)@150 9:(1,2,2)@225
// 10:(2,2,0)@300 11:(2,2,1)@325 12:(2,2,2)@400 ; total 525 floats
// ============================================================================
__device__ inline double dfact(int n){ double r=1.0; for(int i=2;i<=n;i++) r*=(double)i; return r; }
struct dcplx { double x, y; };
__device__ inline dcplx cmul(dcplx a, dcplx b){ return {a.x*b.x-a.y*b.y, a.x*b.y+a.y*b.x}; }

__device__ dcplx Uent(int l, int r, int c){
  double re=0.0, im=0.0;
  double s = 1.0/sqrt(2.0);
  if (r==l && c==l) re = 1.0;
  else if (c>l){ int m=c-l; double sgn=(m&1)?-1.0:1.0;
    if (r==l-m) re = s; else if (r==l+m) re = sgn*s;
  } else if (c<l){ int m=l-c; double sgn=(m&1)?-1.0:1.0;
    if (r==l-m) im = s; else if (r==l+m) im = -sgn*s;
  }
  int lm=l&3; double pr,pi;
  if(lm==0){pr=1;pi=0;} else if(lm==1){pr=0;pi=-1;} else if(lm==2){pr=-1;pi=0;} else {pr=0;pi=1;}
  return { re*pr-im*pi, re*pi+im*pr };
}

__device__ double cg_complex_entry(int l1,int l2,int l3,int m1,int m2){
  int m3=m1+m2;
  if (m3<-l3 || m3>l3) return 0.0;
  double pref = sqrt((double)(2*l3+1)*dfact(l3+l1-l2)*dfact(l3-l1+l2)*dfact(l1+l2-l3)/dfact(l1+l2+l3+1));
  pref *= sqrt(dfact(l3+m3)*dfact(l3-m3)*dfact(l1-m1)*dfact(l1+m1)*dfact(l2-m2)*dfact(l2+m2));
  double s=0.0;
  for(int k=0;k<=l1+l2-l3;k++){
    int a2=l1-m1-k, a3=l2+m2-k, a4=l3-l2+m1+k, a5=l3-l1-m2+k;
    if(a2<0||a3<0||a4<0||a5<0) continue;
    double t=1.0/(dfact(k)*dfact(l1+l2-l3-k)*dfact(a2)*dfact(a3)*dfact(a4)*dfact(a5));
    s += (k&1)? -t : t;
  }
  return pref*s;
}

__global__ void cg_init_kernel(float* cg){
  __shared__ double sKr[525], sKi[525];
  __shared__ double sScale[13];
  __shared__ int    sSel[13];
  const int L1[13]={0,0,1,0,2,1,1,1,2,1,2,2,2};
  const int L2[13]={0,1,0,2,0,1,1,1,1,2,2,2,2};
  const int L3[13]={0,1,1,2,2,0,1,2,2,2,0,1,2};
  const int OFF[14]={0,1,10,19,44,69,78,105,150,225,300,325,400,525};
  const int tid = threadIdx.x;
  int combo=-1, l1=0,l2=0,l3=0;
  if (tid < 525){
    combo=12;
    for(int i=0;i<12;i++) if (tid < OFF[i+1]) { combo=i; break; }
    l1=L1[combo]; l2=L2[combo]; l3=L3[combo];
    int d2=2*l2+1, d3=2*l3+1;
    int e = tid - OFF[combo];
    int a = e/(d2*d3), b=(e/d3)%d2, cc=e%d3;
    double kr=0.0, ki=0.0;
    for(int m=0;m<2*l1+1;m++) for(int n=0;n<d2;n++){
      int m3 = (m-l1)+(n-l2);
      if (m3<-l3||m3>l3) continue;
      double cv = cg_complex_entry(l1,l2,l3,m-l1,n-l2);
      if (cv==0.0) continue;
      dcplx u1=Uent(l1,m,a), u2=Uent(l2,n,b), u3=Uent(l3,m3+l3,cc);
      u3.y = -u3.y;
      dcplx t = cmul(cmul(u1,u2),u3);
      kr += t.x*cv; ki += t.y*cv;
    }
    sKr[tid]=kr; sKi[tid]=ki;
  }
  __syncthreads();
  if (tid < 13){
    int sz = OFF[tid+1]-OFF[tid];
    double nr=0,ni=0;
    for(int i=0;i<sz;i++){ double r=sKr[OFF[tid]+i], im=sKi[OFF[tid]+i]; nr+=r*r; ni+=im*im; }
    int sel = (nr>=ni)? 0 : 1;
    sSel[tid]=sel;
    sScale[tid] = sqrt((double)(2*L3[tid]+1))/sqrt(sel? ni : nr);
  }
  __syncthreads();
  if (tid < 525){
    double v = sSel[combo]? sKi[tid] : sKr[tid];
    cg[tid] = (float)(v*sScale[combo]);
  }
}

// ============================================================================
// Weight prep: fp32 -> bf16 hi/lo planes. Linear weights transposed WT[o][k];
// TP weights [u][v].
// ============================================================================
__global__ void prep_kernel(const float* __restrict__ l2W0, const float* __restrict__ l2W1,
                            const float* __restrict__ l2W2, const float* __restrict__ LW0,
                            const float* __restrict__ LW1, const float* __restrict__ LW2,
                            const float* __restrict__ tpw, const float* __restrict__ tp4w,
                            unsigned short* __restrict__ wb){
  int i = blockIdx.x*256 + threadIdx.x;
  if (i >= W_TOT) return;
  float v;
  if (i < 8192){ int o=i>>7, k=i&127; v = l2W0[k*64+o]; }
  else if (i < 40960){ int j=i-8192; int o=j>>8, k=j&255; v = l2W1[k*128+o]; }
  else if (i < 49152){ int j=i-40960; int o=j>>7, k=j&127; v = l2W2[k*64+o]; }
  else if (i < 94208){ int j=i-49152; int li=j>>12, r=j&4095, o=r>>6, k=r&63; v = LW0[li*4096+k*64+o]; }
  else if (i < 274432){ int j=i-94208; int li=j>>14, r=j&16383, o=r>>7, k=r&127; v = LW1[li*16384+k*128+o]; }
  else if (i < 319488){ int j=i-274432; int li=j>>12, r=j&4095, o=r>>6, k=r&63; v = LW2[li*4096+k*64+o]; }
  else if (i < 491520){ v = tpw[i-319488]; }
  else { v = tp4w[i-491520]; }
  unsigned short h = f2b(v);
  wb[i] = h;
  wb[W_TOT + i] = f2b(v - b2f(h));
}

// pack 4 consecutive values into one b64 store per plane
__device__ inline void store4_hl(unsigned short* ph, unsigned short* pl, int idx,
                                 float v0, float v1, float v2, float v3){
  u16x4 vh, vl;
  float v[4] = {v0,v1,v2,v3};
  #pragma unroll
  for (int r=0;r<4;r++){
    unsigned short h = f2b(v[r]);
    vh[r] = h;
    vl[r] = f2b(v[r] - b2f(h));
  }
  *(u16x4*)(ph + idx) = vh;
  *(u16x4*)(pl + idx) = vl;
}

// ============================================================================
// MFMA linear HID0->HID0 (hi/lo), SWAPPED operands mfma(w,x): C row=feature
// (quad*4+r), col=sample (l16); store4_hl b64 stores. KFENCE windows of TWO
// units (R15): unit k+1's weight loads overlap unit k's MFMA tail while
// keeping live pressure under the 85-reg cap.
// Jobs: 0..3 l0 | 4..11 l1 | 12..15 l2. NW=12: w0-3 {l0,l2}; w4-11 one l1.
// ============================================================================
__device__ void linL_mfma(const unsigned short* __restrict__ wb, int o0, int o1, int o2,
                          const float* __restrict__ b0,
                          const unsigned short* sh, const unsigned short* sl,
                          unsigned short* dh, unsigned short* dl, int wave, int lane)
{
  const float rs128 = 0.08838834764831845f;
  int l16 = lane & 15, quad = lane >> 4;
  int abase = l16 * SSTRIDE;        // sample = l16 (B operand / stores)
  for (int job = wave; job < 16; job += NW){
    if (job < 4){                 // l0: K=64, /8 + bias
      f32x4 a0 = {0,0,0,0}, a1 = {0,0,0,0};
      #pragma unroll
      for (int ks=0; ks<2; ks++){
        int so = abase + ks*32 + quad*8;
        bf16x8 xh = LDFRAG(sh+so), xl = LDFRAG(sl+so);
        int wo = o0 + (job*16 + l16)*64 + ks*32 + quad*8;
        bf16x8 wh = LDFRAG(wb+wo), wl = LDFRAG(wb+W_TOT+wo);
        a0 = mfma16(wh,xh,a0); a1 = mfma16(wl,xh,a1); a1 = mfma16(wh,xl,a1);
      }
      int fb = job*16 + quad*4;
      float4 b4 = *(const float4*)(b0 + fb);
      store4_hl(dh,dl, abase + fb,
                (a0[0]+a1[0])*0.125f + b4.x, (a0[1]+a1[1])*0.125f + b4.y,
                (a0[2]+a1[2])*0.125f + b4.z, (a0[3]+a1[3])*0.125f + b4.w);
      KFENCE();
    } else if (job < 12){         // l1: K=128 (l1|l1b), /sqrt(128)
      int nt = job-4;
      #pragma unroll
      for (int i=0;i<3;i++){
        f32x4 a0 = {0,0,0,0}, a1 = {0,0,0,0};
        #pragma unroll
        for (int ks=0; ks<4; ks++){
          int ka = ks*32 + quad*8;
          int so = abase + ((ka < 64) ? (64 + i*64 + ka) : (576 + i*64 + ka - 64));
          bf16x8 xh = LDFRAG(sh+so), xl = LDFRAG(sl+so);
          int wo = o1 + (nt*16 + l16)*128 + ka;
          bf16x8 wh = LDFRAG(wb+wo), wl = LDFRAG(wb+W_TOT+wo);
          a0 = mfma16(wh,xh,a0); a1 = mfma16(wl,xh,a1); a1 = mfma16(wh,xl,a1);
        }
        int colb = nt*16 + quad*4;
        int dof = (nt < 4) ? (64 + i*64 + colb) : (576 + i*64 + colb - 64);
        store4_hl(dh,dl, abase + dof,
                  (a0[0]+a1[0])*rs128, (a0[1]+a1[1])*rs128,
                  (a0[2]+a1[2])*rs128, (a0[3]+a1[3])*rs128);
        if (i == 1 || i == 2) KFENCE();   // windows {0,1},{2}
      }
    } else {                      // l2: K=64, /8
      int nt = job-12;
      #pragma unroll
      for (int i=0;i<5;i++){
        f32x4 a0 = {0,0,0,0}, a1 = {0,0,0,0};
        #pragma unroll
        for (int ks=0; ks<2; ks++){
          int so = abase + 256 + i*64 + ks*32 + quad*8;
          bf16x8 xh = LDFRAG(sh+so), xl = LDFRAG(sl+so);
          int wo = o2 + (nt*16 + l16)*64 + ks*32 + quad*8;
          bf16x8 wh = LDFRAG(wb+wo), wl = LDFRAG(wb+W_TOT+wo);
          a0 = mfma16(wh,xh,a0); a1 = mfma16(wl,xh,a1); a1 = mfma16(wh,xl,a1);
        }
        store4_hl(dh,dl, abase + 256 + i*64 + nt*16 + quad*4,
                  (a0[0]+a1[0])*0.125f, (a0[1]+a1[1])*0.125f,
                  (a0[2]+a1[2])*0.125f, (a0[3]+a1[3])*0.125f);
        if (i == 1 || i == 3 || i == 4) KFENCE();   // windows {0,1},{2,3},{4}
      }
    }
  }
}

// lin2: HID1 -> HID0 (K=128/256/128), hi/lo, swapped operands + b64 stores.
__device__ void lin2_mfma(const unsigned short* __restrict__ wb,
                          const float* __restrict__ b0,
                          const unsigned short* h1h, const unsigned short* h1l,
                          unsigned short* dh, unsigned short* dl, int wave, int lane)
{
  const float rs128 = 0.08838834764831845f;
  int l16 = lane & 15, quad = lane >> 4;
  int abase = l16 * H1S;            // sample = l16 (B operand)
  int obase = l16 * SSTRIDE;        // output rows
  for (int job = wave; job < 16; job += NW){
    if (job < 4){                 // l0: K=128
      f32x4 a0 = {0,0,0,0}, a1 = {0,0,0,0};
      #pragma unroll
      for (int ks=0; ks<4; ks++){
        int so = abase + ks*32 + quad*8;
        bf16x8 xh = LDFRAG(h1h+so), xl = LDFRAG(h1l+so);
        int wo = OFF_L2W0 + (job*16 + l16)*128 + ks*32 + quad*8;
        bf16x8 wh = LDFRAG(wb+wo), wl = LDFRAG(wb+W_TOT+wo);
        a0 = mfma16(wh,xh,a0); a1 = mfma16(wl,xh,a1); a1 = mfma16(wh,xl,a1);
      }
      int fb = job*16 + quad*4;
      float4 b4 = *(const float4*)(b0 + fb);
      store4_hl(dh,dl, obase + fb,
                (a0[0]+a1[0])*rs128 + b4.x, (a0[1]+a1[1])*rs128 + b4.y,
                (a0[2]+a1[2])*rs128 + b4.z, (a0[3]+a1[3])*rs128 + b4.w);
      KFENCE();
    } else if (job < 12){         // l1: K=256, /16
      int nt = job-4;
      #pragma unroll
      for (int i=0;i<3;i++){
        f32x4 a0 = {0,0,0,0}, a1 = {0,0,0,0};
        #pragma unroll
        for (int ks=0; ks<8; ks++){
          int ka = ks*32 + quad*8;
          int so = abase + ((ka < 128) ? (128 + i*128 + ka) : (1152 + i*128 + ka - 128));
          bf16x8 xh = LDFRAG(h1h+so), xl = LDFRAG(h1l+so);
          int wo = OFF_L2W1 + (nt*16 + l16)*256 + ka;
          bf16x8 wh = LDFRAG(wb+wo), wl = LDFRAG(wb+W_TOT+wo);
          a0 = mfma16(wh,xh,a0); a1 = mfma16(wl,xh,a1); a1 = mfma16(wh,xl,a1);
        }
        int colb = nt*16 + quad*4;
        int dof = (nt < 4) ? (64 + i*64 + colb) : (576 + i*64 + colb - 64);
        store4_hl(dh,dl, obase + dof,
                  (a0[0]+a1[0])*0.0625f, (a0[1]+a1[1])*0.0625f,
                  (a0[2]+a1[2])*0.0625f, (a0[3]+a1[3])*0.0625f);
        if (i == 1 || i == 2) KFENCE();   // windows {0,1},{2} (K=256: 1-unit live ~70, 2-unit window relies on scheduler moderation; canary = WRITE_SIZE)
      }
    } else {                      // l2: K=128
      int nt = job-12;
      #pragma unroll
      for (int i=0;i<5;i++){
        f32x4 a0 = {0,0,0,0}, a1 = {0,0,0,0};
        #pragma unroll
        for (int ks=0; ks<4; ks++){
          int so = abase + 512 + i*128 + ks*32 + quad*8;
          bf16x8 xh = LDFRAG(h1h+so), xl = LDFRAG(h1l+so);
          int wo = OFF_L2W2 + (nt*16 + l16)*128 + ks*32 + quad*8;
          bf16x8 wh = LDFRAG(wb+wo), wl = LDFRAG(wb+W_TOT+wo);
          a0 = mfma16(wh,xh,a0); a1 = mfma16(wl,xh,a1); a1 = mfma16(wh,xl,a1);
        }
        store4_hl(dh,dl, obase + 256 + i*64 + nt*16 + quad*4,
                  (a0[0]+a1[0])*rs128, (a0[1]+a1[1])*rs128,
                  (a0[2]+a1[2])*rs128, (a0[3]+a1[3])*rs128);
        if (i == 1 || i == 3 || i == 4) KFENCE();   // windows {0,1},{2,3},{4}
      }
    }
  }
}

// ============================================================================
// Fused TP path: stage b-fragment in regs via MFMA, contract immediately.
// Wave's fixed mt picks the u-block; lane l -> sample n=l&15,
// u = mt*16 + quad*4 + r. PACKED contraction (f32x2, r-pairs {0,1},{2,3}).
// ============================================================================
template<int D1,int D2,int D3,int O1,int O2,int CGO>
__device__ __forceinline__ void fused_path(
    const unsigned short* __restrict__ wb, int wo,
    const unsigned short* s1h, const unsigned short* s1l,
    const unsigned short* s2h, const unsigned short* s2l,
    const float* __restrict__ cgp,
    f32x2 (&tk)[2][D3], int mt, int lane)
{
  int l16 = lane & 15, quad = lane >> 4;
  f32x2 x1v[D1][2];
  #pragma unroll
  for (int i=0;i<D1;i++){
    int o = l16*SSTRIDE + O1 + i*64 + mt*16 + quad*4;
    u16x4 xh4 = *(const u16x4*)(s1h + o);
    u16x4 xl4 = *(const u16x4*)(s1l + o);
    #pragma unroll
    for (int h=0;h<2;h++){
      f32x2 v;
      v[0] = b2f(xh4[2*h  ]) + b2f(xl4[2*h  ]);
      v[1] = b2f(xh4[2*h+1]) + b2f(xl4[2*h+1]);
      x1v[i][h] = v;
    }
  }
  #pragma unroll
  for (int j=0;j<D2;j++){
    f32x4 a0 = {0,0,0,0}, a1 = {0,0,0,0};
    #pragma unroll
    for (int ks=0; ks<2; ks++){
      int wofs = wo + (mt*16 + l16)*64 + ks*32 + quad*8;
      bf16x8 wh = LDFRAG(wb + wofs);
      bf16x8 wl = LDFRAG(wb + W_TOT + wofs);
      int sofs = l16*SSTRIDE + O2 + j*64 + ks*32 + quad*8;
      bf16x8 xh = LDFRAG(s2h + sofs);
      bf16x8 xl = LDFRAG(s2l + sofs);
      a0 = mfma16(wh,xh,a0); a1 = mfma16(wh,xl,a1); a1 = mfma16(wl,xh,a1);
    }
    f32x2 bu0, bu1;
    bu0[0] = a0[0]+a1[0]; bu0[1] = a0[1]+a1[1];
    bu1[0] = a0[2]+a1[2]; bu1[1] = a0[3]+a1[3];
    #pragma unroll
    for (int i=0;i<D1;i++){
      f32x2 pr0 = x1v[i][0]*bu0;
      f32x2 pr1 = x1v[i][1]*bu1;
      #pragma unroll
      for (int k=0;k<D3;k++){
        float c = cgp[CGO + (i*D2 + j)*D3 + k];
        f32x2 cc = {c, c};
        tk[0][k] += pr0*cc;
        tk[1][k] += pr1*cc;
      }
    }
  }
}

// FC variant: output summed over u; r-pairs folded into tk[k] (f32x2).
template<int D1,int D2,int D3,int O1,int O2,int CGO>
__device__ __forceinline__ void fused_path_fc(
    const unsigned short* __restrict__ wb, int wo,
    const unsigned short* s1h, const unsigned short* s1l,
    const unsigned short* s2h, const unsigned short* s2l,
    const float* __restrict__ cgp,
    f32x2 (&tk)[D3], int mt, int lane)
{
  int l16 = lane & 15, quad = lane >> 4;
  f32x2 x1v[D1][2];
  #pragma unroll
  for (int i=0;i<D1;i++){
    int o = l16*SSTRIDE + O1 + i*64 + mt*16 + quad*4;
    u16x4 xh4 = *(const u16x4*)(s1h + o);
    u16x4 xl4 = *(const u16x4*)(s1l + o);
    #pragma unroll
    for (int h=0;h<2;h++){
      f32x2 v;
      v[0] = b2f(xh4[2*h  ]) + b2f(xl4[2*h  ]);
      v[1] = b2f(xh4[2*h+1]) + b2f(xl4[2*h+1]);
      x1v[i][h] = v;
    }
  }
  #pragma unroll
  for (int j=0;j<D2;j++){
    f32x4 a0 = {0,0,0,0}, a1 = {0,0,0,0};
    #pragma unroll
    for (int ks=0; ks<2; ks++){
      int wofs = wo + (mt*16 + l16)*64 + ks*32 + quad*8;
      bf16x8 wh = LDFRAG(wb + wofs);
      bf16x8 wl = LDFRAG(wb + W_TOT + wofs);
      int sofs = l16*SSTRIDE + O2 + j*64 + ks*32 + quad*8;
      bf16x8 xh = LDFRAG(s2h + sofs);
      bf16x8 xl = LDFRAG(s2l + sofs);
      a0 = mfma16(wh,xh,a0); a1 = mfma16(wh,xl,a1); a1 = mfma16(wl,xh,a1);
    }
    f32x2 bu0, bu1;
    bu0[0] = a0[0]+a1[0]; bu0[1] = a0[1]+a1[1];
    bu1[0] = a0[2]+a1[2]; bu1[1] = a0[3]+a1[3];
    #pragma unroll
    for (int i=0;i<D1;i++){
      f32x2 pr = x1v[i][0]*bu0;
      pr += x1v[i][1]*bu1;
      #pragma unroll
      for (int k=0;k<D3;k++){
        float c = cgp[CGO + (i*D2 + j)*D3 + k];
        f32x2 cc = {c, c};
        tk[k] += pr*cc;
      }
    }
  }
}

// uvu TP, one barrier-free phase. 12 waves = 3 output-groups x 4 mt
// (disjoint LDS ranges, no merging): w0-3 l2, w4-7 l1, w8-11 l1b+l0.
// KFENCE every ~2 paths keeps live regs under the 85-reg cap.
__device__ void fused_tp_uvu(const unsigned short* __restrict__ wb, int two,
    const unsigned short* ah, const unsigned short* al,
    const unsigned short* bh, const unsigned short* bl,
    unsigned short* dh, unsigned short* dl,
    const float* __restrict__ cgp, int wave, int lane)
{
  const float f192 = 0.07216878364870323f;  // 1/sqrt(192)
  const float f256 = 0.0625f;               // 1/sqrt(256)
  int mt = wave & 3, grp = wave >> 2;
  int l16 = lane & 15, quad = lane >> 4;
  int u0 = mt*16 + quad*4;
  if (grp == 0){
    // out l2 @256 (fan 256): paths 2,8,9,13
    f32x2 tk2[2][5] = {};
    fused_path<1,5,5,  0,256, 19>(wb,two+ 2*4096, ah,al,bh,bl,cgp,tk2,mt,lane);
    fused_path<5,1,5,256,  0, 44>(wb,two+ 8*4096, ah,al,bh,bl,cgp,tk2,mt,lane);
    KFENCE();
    fused_path<5,3,5,256, 64,150>(wb,two+ 9*4096, ah,al,bh,bl,cgp,tk2,mt,lane);
    fused_path<5,3,5,256,576,150>(wb,two+13*4096, ah,al,bh,bl,cgp,tk2,mt,lane);
    #pragma unroll
    for (int k=0;k<5;k++)
      store4_hl(dh,dl, l16*SSTRIDE + 256 + k*64 + u0,
                tk2[0][k][0]*f256, tk2[0][k][1]*f256, tk2[1][k][0]*f256, tk2[1][k][1]*f256);
  } else if (grp == 1){
    // out l1 @64 (fan 256): paths 1,4,6,11
    f32x2 tkA[2][3] = {};
    fused_path<1,3,3,  0, 64,  1>(wb,two+ 1*4096, ah,al,bh,bl,cgp,tkA,mt,lane);
    fused_path<3,1,3, 64,  0, 10>(wb,two+ 4*4096, ah,al,bh,bl,cgp,tkA,mt,lane);
    KFENCE();
    fused_path<3,3,3, 64, 64, 78>(wb,two+ 6*4096, ah,al,bh,bl,cgp,tkA,mt,lane);
    fused_path<5,5,3,256,256,325>(wb,two+11*4096, ah,al,bh,bl,cgp,tkA,mt,lane);
    #pragma unroll
    for (int k=0;k<3;k++)
      store4_hl(dh,dl, l16*SSTRIDE +  64 + k*64 + u0,
                tkA[0][k][0]*f256, tkA[0][k][1]*f256, tkA[1][k][0]*f256, tkA[1][k][1]*f256);
  } else {
    // out l1b @576 (fan 192): paths 3,7,12, then l0 @0 (fan 192): 0,5,10
    {
      f32x2 tkB[2][3] = {};
      fused_path<1,3,3,  0,576,  1>(wb,two+ 3*4096, ah,al,bh,bl,cgp,tkB,mt,lane);
      fused_path<3,3,3, 64, 64, 78>(wb,two+ 7*4096, ah,al,bh,bl,cgp,tkB,mt,lane);
      KFENCE();
      fused_path<5,5,3,256,256,325>(wb,two+12*4096, ah,al,bh,bl,cgp,tkB,mt,lane);
      #pragma unroll
      for (int k=0;k<3;k++)
        store4_hl(dh,dl, l16*SSTRIDE + 576 + k*64 + u0,
                  tkB[0][k][0]*f192, tkB[0][k][1]*f192, tkB[1][k][0]*f192, tkB[1][k][1]*f192);
      KFENCE();
    }
    {
      f32x2 tk0[2][1] = {};
      fused_path<1,1,1,  0,  0,  0>(wb,two+ 0*4096, ah,al,bh,bl,cgp,tk0,mt,lane);
      fused_path<3,3,1, 64, 64, 69>(wb,two+ 5*4096, ah,al,bh,bl,cgp,tk0,mt,lane);
      KFENCE();
      fused_path<5,5,1,256,256,300>(wb,two+10*4096, ah,al,bh,bl,cgp,tk0,mt,lane);
      store4_hl(dh,dl, l16*SSTRIDE + u0,
                tk0[0][0][0]*f192, tk0[0][0][1]*f192, tk0[1][0][0]*f192, tk0[1][0][1]*f192);
    }
  }
}

// FC TP: 3 path-groups x 4 mt (atomicAdd makes any partition valid).
__device__ void fused_tp_fc(const unsigned short* __restrict__ wb,
    const unsigned short* ah, const unsigned short* al,
    const unsigned short* bh, const unsigned short* bl,
    float* s_out, const float* __restrict__ cgp, int wave, int lane)
{
  int mt = wave & 3, grp = wave >> 2;
  int l16 = lane & 15;
  f32x2 t0[1] = {};
  f32x2 t2[5] = {};
  if (grp == 0){
    fused_path_fc<5,5,5,256,256,400>(wb,OFF_TP4W+12*4096, ah,al,bh,bl,cgp,t2,mt,lane);
    KFENCE();
    fused_path_fc<3,5,5, 64,256,225>(wb,OFF_TP4W+ 8*4096, ah,al,bh,bl,cgp,t2,mt,lane);
    KFENCE();
    fused_path_fc<5,5,1,256,256,300>(wb,OFF_TP4W+ 3*4096, ah,al,bh,bl,cgp,t0,mt,lane);
  } else if (grp == 1){
    fused_path_fc<5,3,5,256, 64,150>(wb,OFF_TP4W+11*4096, ah,al,bh,bl,cgp,t2,mt,lane);
    fused_path_fc<5,3,5,256,576,150>(wb,OFF_TP4W+13*4096, ah,al,bh,bl,cgp,t2,mt,lane);
    KFENCE();
    fused_path_fc<3,3,5, 64, 64,105>(wb,OFF_TP4W+ 7*4096, ah,al,bh,bl,cgp,t2,mt,lane);
    fused_path_fc<3,3,5, 64,576,105>(wb,OFF_TP4W+ 9*4096, ah,al,bh,bl,cgp,t2,mt,lane);
    KFENCE();
    fused_path_fc<1,1,1,  0,  0,  0>(wb,OFF_TP4W+ 0*4096, ah,al,bh,bl,cgp,t0,mt,lane);
    fused_path_fc<3,3,1, 64, 64, 69>(wb,OFF_TP4W+ 1*4096, ah,al,bh,bl,cgp,t0,mt,lane);
  } else {
    fused_path_fc<1,5,5,  0,256, 19>(wb,OFF_TP4W+ 6*4096, ah,al,bh,bl,cgp,t2,mt,lane);
    fused_path_fc<5,1,5,256,  0, 44>(wb,OFF_TP4W+10*4096, ah,al,bh,bl,cgp,t2,mt,lane);
    KFENCE();
    fused_path_fc<3,3,5,576, 64,105>(wb,OFF_TP4W+14*4096, ah,al,bh,bl,cgp,t2,mt,lane);
    fused_path_fc<3,5,5,576,256,225>(wb,OFF_TP4W+15*4096, ah,al,bh,bl,cgp,t2,mt,lane);
    KFENCE();
    fused_path_fc<3,3,5,576,576,105>(wb,OFF_TP4W+16*4096, ah,al,bh,bl,cgp,t2,mt,lane);
    fused_path_fc<3,3,1, 64,576, 69>(wb,OFF_TP4W+ 2*4096, ah,al,bh,bl,cgp,t0,mt,lane);
    KFENCE();
    fused_path_fc<3,3,1,576, 64, 69>(wb,OFF_TP4W+ 4*4096, ah,al,bh,bl,cgp,t0,mt,lane);
    fused_path_fc<3,3,1,576,576, 69>(wb,OFF_TP4W+ 5*4096, ah,al,bh,bl,cgp,t0,mt,lane);
  }
  float v0 = t0[0][0] + t0[0][1];
  v0 += __shfl_xor(v0, 16, 64);
  v0 += __shfl_xor(v0, 32, 64);
  if (lane < 16) atomicAdd(&s_out[l16*6 + 0], v0);
  #pragma unroll
  for (int k=0;k<5;k++){
    float v = t2[k][0] + t2[k][1];
    v += __shfl_xor(v, 16, 64);
    v += __shfl_xor(v, 32, 64);
    if (lane < 16) atomicAdd(&s_out[l16*6 + 1 + k], v);
  }
}

// ============================================================================
// 15 barriers. NT=768 -> 3 waves/SIMD, VGPR cap 85. R15: 2-unit linear
// KFENCE windows (load-latency overlap); WRITE_SIZE is the spill canary.
// ============================================================================
__global__ __launch_bounds__(NT) void deeprst_main(
    const float* __restrict__ x,
    const float* __restrict__ l1W0, const float* __restrict__ l1W1,
    const float* __restrict__ l1W2, const float* __restrict__ l1b0,
    const float* __restrict__ l2b0, const float* __restrict__ Lb0,
    const unsigned short* __restrict__ wb, const float* __restrict__ cgp,
    float* __restrict__ out)
{
  __shared__ unsigned short sth[3*BUF];   // 74496 B hi plane
  __shared__ unsigned short stl[3*BUF];   // 74496 B lo plane

  const int tid  = threadIdx.x;
  const int lane = tid & 63;
  const int wave = tid >> 6;
  const int n0   = blockIdx.x * TS;
  const float rs8 = 0.3535533905932738f;

  // ---- lin1 (scalar fp32 -> hi/lo), h1 in buffers 0+1 of both planes ----
  for (int idx=tid; idx<TS*128; idx+=NT){
    int n=idx>>7, o=idx&127;
    const float* xp = x + (n0+n)*80;
    float acc=0.f;
    #pragma unroll
    for (int v=0;v<16;v++) acc += xp[v]*l1W0[v*128+o];
    store_hl(sth,stl, n*H1S + o, acc*0.25f + l1b0[o]);
  }
  for (int idx=tid; idx<TS*768; idx+=NT){
    int o=idx&255, i=(idx>>8)%3, n=idx/768;
    const float* xp = x + (n0+n)*80 + 16;
    float acc=0.f;
    #pragma unroll
    for (int v=0;v<8;v++) acc += xp[v*3+i]*l1W1[v*256+o];
    int du = (o<128)? (128 + i*128 + o) : (1152 + i*128 + o-128);
    store_hl(sth,stl, n*H1S + du, acc*rs8);
  }
  for (int idx=tid; idx<TS*640; idx+=NT){
    int o=idx&127, i=(idx>>7)%5, n=idx/640;
    const float* xp = x + (n0+n)*80 + 40;
    float acc=0.f;
    #pragma unroll
    for (int v=0;v<8;v++) acc += xp[v*5+i]*l1W2[v*128+o];
    store_hl(sth,stl, n*H1S + 512 + i*128 + o, acc*rs8);
  }
  __syncthreads();

  // ---- lin2 (MFMA hi/lo): h1 -> buffer 2 ----
  lin2_mfma(wb, l2b0, sth, stl, sth+2*BUF, stl+2*BUF, wave, lane);
  __syncthreads();

  // ---- 3 rounds: split -> fused tp_uvu -> linear (3 barriers/round) ----
  int ih = 2, i0 = 0, i1 = 1;
  for (int r=0;r<3;r++){
    unsigned short *hh=sth+ih*BUF, *hl=stl+ih*BUF;
    unsigned short *ah=sth+i0*BUF, *al=stl+i0*BUF;
    unsigned short *bh=sth+i1*BUF, *bl=stl+i1*BUF;
    linL_mfma(wb, OFF_LW0+(3*r  )*4096, OFF_LW1+(3*r  )*16384, OFF_LW2+(3*r  )*4096,
              Lb0+(3*r  )*64, hh, hl, ah, al, wave, lane);
    linL_mfma(wb, OFF_LW0+(3*r+1)*4096, OFF_LW1+(3*r+1)*16384, OFF_LW2+(3*r+1)*4096,
              Lb0+(3*r+1)*64, hh, hl, bh, bl, wave, lane);
    __syncthreads();   // lin writes -> TP reads
    fused_tp_uvu(wb, OFF_TPW + r*14*4096, ah, al, bh, bl, hh, hl, cgp, wave, lane);
    __syncthreads();   // TP writes h -> linC reads h
    linL_mfma(wb, OFF_LW0+(3*r+2)*4096, OFF_LW1+(3*r+2)*16384, OFF_LW2+(3*r+2)*4096,
              Lb0+(3*r+2)*64, hh, hl, ah, al, wave, lane);
    __syncthreads();   // linC writes a -> next round reads
    int nh=i0; i0=i1; i1=ih; ih=nh;
  }

  // ---- split4 + fully-connected TP ----
  unsigned short *hh=sth+ih*BUF, *hl=stl+ih*BUF;
  unsigned short *ah=sth+i0*BUF, *al=stl+i0*BUF;
  unsigned short *bh=sth+i1*BUF, *bl=stl+i1*BUF;
  linL_mfma(wb, OFF_LW0+ 9*4096, OFF_LW1+ 9*16384, OFF_LW2+ 9*4096, Lb0+ 9*64, hh, hl, ah, al, wave, lane);
  linL_mfma(wb, OFF_LW0+10*4096, OFF_LW1+10*16384, OFF_LW2+10*4096, Lb0+10*64, hh, hl, bh, bl, wave, lane);
  __syncthreads();   // lin reads of h done -> safe to reuse h as s_out

  float* s_out = (float*)hh;   // h buffer dead after split4 linears
  if (tid < TS*6) s_out[tid] = 0.f;
  __syncthreads();   // zero visible before atomics

  fused_tp_fc(wb, ah, al, bh, bl, s_out, cgp, wave, lane);
  __syncthreads();   // atomics done -> read s_out

  if (tid < TS*6){
    int n=tid/6, k=tid%6;
    float sc = (k==0)? (1.0f/sqrtf(24576.0f)) : (1.0f/sqrtf(45056.0f));
    out[(n0+n)*6+k] = s_out[tid]*sc;
  }
}

// ============================================================================
extern "C" void kernel_launch(void* const* d_in, const int* in_sizes, int n_in,
                              void* d_out, int out_size, void* d_ws, size_t ws_size,
                              hipStream_t stream)
{
  (void)n_in; (void)out_size; (void)ws_size;
  const float* x    = (const float*)d_in[0];
  const float* l1W0 = (const float*)d_in[1];
  const float* l1W1 = (const float*)d_in[2];
  const float* l1W2 = (const float*)d_in[3];
  const float* l1b0 = (const float*)d_in[4];
  const float* l2W0 = (const float*)d_in[5];
  const float* l2W1 = (const float*)d_in[6];
  const float* l2W2 = (const float*)d_in[7];
  const float* l2b0 = (const float*)d_in[8];
  const float* LW0  = (const float*)d_in[9];
  const float* LW1  = (const float*)d_in[10];
  const float* LW2  = (const float*)d_in[11];
  const float* Lb0  = (const float*)d_in[12];
  const float* tpw  = (const float*)d_in[13];
  const float* tp4w = (const float*)d_in[14];

  float* cg = (float*)d_ws;                                    // 525 f32 @ ws+0
  unsigned short* wb = (unsigned short*)((char*)d_ws + 4096);  // hi + lo planes
  const int n = in_sizes[0]/80;

  cg_init_kernel<<<1, 576, 0, stream>>>(cg);
  prep_kernel<<<(W_TOT+255)/256, 256, 0, stream>>>(l2W0,l2W1,l2W2,LW0,LW1,LW2,tpw,tp4w,wb);
  deeprst_main<<<n/TS, NT, 0, stream>>>(x,l1W0,l1W1,l1W2,l1b0,l2b0,Lb0,wb,cg,(float*)d_out);
}